// Round 1
// baseline (5568.021 us; speedup 1.0000x reference)
//
#include <hip/hip_runtime.h>
#include <hip/hip_bf16.h>

using u16 = unsigned short;
using u32 = unsigned int;
using u64 = unsigned long long;

#define HSIZE (1u<<21)
#define HMASK (HSIZE-1u)
#define HEMPTY 0xFFFFFFFFFFFFFFFFull

__device__ __forceinline__ float bf2f(u32 u){ union{u32 i; float f;} v; v.i = u<<16; return v.f; }
__device__ __forceinline__ u32 f2bf(float f){ union{float f; u32 i;} v; v.f=f; u32 i=v.i; return (i + 0x7FFFu + ((i>>16)&1u)) >> 16; }
__device__ __forceinline__ u32 pack2(float a, float b){ return f2bf(a) | (f2bf(b)<<16); }

// ---------------- reverse-edge hash ----------------
__global__ __launch_bounds__(256) void k_hash_insert(
    const int* __restrict__ row, const int* __restrict__ col,
    u64* __restrict__ tab, int E, int N)
{
  int e = blockIdx.x*256 + threadIdx.x;
  if (e >= E) return;
  u32 key = (u32)row[e] * (u32)N + (u32)col[e];
  u64 entry = ((u64)key << 32) | (u32)e;
  u32 h = (key * 2654435761u) & HMASK;
  while (true) {
    u64 old = atomicCAS(&tab[h], HEMPTY, entry);
    if (old == HEMPTY) break;
    h = (h + 1u) & HMASK;
  }
}

__global__ __launch_bounds__(256) void k_hash_lookup(
    const int* __restrict__ row, const int* __restrict__ col,
    const u64* __restrict__ tab, int* __restrict__ rev, int E, int N)
{
  int e = blockIdx.x*256 + threadIdx.x;
  if (e >= E) return;
  u32 rkey = (u32)col[e] * (u32)N + (u32)row[e];
  u32 h = (rkey * 2654435761u) & HMASK;
  int r = -1;
  while (true) {
    u64 entry = tab[h];
    if (entry == HEMPTY) break;
    if ((u32)(entry >> 32) == rkey) { r = (int)(entry & 0xFFFFFFFFull); break; }
    h = (h + 1u) & HMASK;
  }
  rev[e] = r;
}

// ---------------- edge init: eh = edge_attr @ We + be ----------------
__global__ __launch_bounds__(256) void k_edge_init(
    const float* __restrict__ ea, const float* __restrict__ We,
    const float* __restrict__ be, u16* __restrict__ eh, int E)
{
  int e = blockIdx.x*256 + threadIdx.x;
  if (e >= E) return;
  const float* a = ea + (size_t)e*6;
  float2 a0 = *(const float2*)(a);
  float2 a1 = *(const float2*)(a+2);
  float2 a2 = *(const float2*)(a+4);
  float av[6] = {a0.x,a0.y,a1.x,a1.y,a2.x,a2.y};
  float acc[64];
  #pragma unroll
  for (int j=0;j<64;j++) acc[j] = be[j];
  #pragma unroll
  for (int k=0;k<6;k++){
    const float* w = We + k*64;
    #pragma unroll
    for (int j=0;j<64;j++) acc[j] += av[k]*w[j];
  }
  uint4* dst = (uint4*)(eh + ((size_t)e<<6));
  #pragma unroll
  for (int q=0;q<8;q++){
    uint4 u;
    u.x = pack2(acc[q*8+0], acc[q*8+1]);
    u.y = pack2(acc[q*8+2], acc[q*8+3]);
    u.z = pack2(acc[q*8+4], acc[q*8+5]);
    u.w = pack2(acc[q*8+6], acc[q*8+7]);
    dst[q] = u;
  }
}

// ---------------- scatter-add (bf16 vals -> f32 out) ----------------
__global__ __launch_bounds__(256) void k_scat_bf16(
    const u16* __restrict__ vals, const int* __restrict__ idx,
    float* __restrict__ out, int E)
{
  int t = blockIdx.x*256 + threadIdx.x;
  if (t >= E*16) return;
  int e = t >> 4, q = t & 15;
  int n = idx[e];
  uint2 u = *(const uint2*)(vals + ((size_t)e<<6) + q*4);
  float* o = out + ((size_t)n<<6) + q*4;
  atomicAdd(o+0, bf2f(u.x));
  atomicAdd(o+1, bf2f(u.x>>16));
  atomicAdd(o+2, bf2f(u.y));
  atomicAdd(o+3, bf2f(u.y>>16));
}

// ---------------- scatter-add (f32 vals -> f32 out), 64-wide rows ----------------
__global__ __launch_bounds__(256) void k_scat_f32(
    const float* __restrict__ vals, const int* __restrict__ idx,
    float* __restrict__ out, int Nv)
{
  int t = blockIdx.x*256 + threadIdx.x;
  if (t >= Nv*16) return;
  int i = t >> 4, q = t & 15;
  int g = idx[i];
  float4 v = *(const float4*)(vals + ((size_t)i<<6) + q*4);
  float* o = out + ((size_t)g<<6) + q*4;
  atomicAdd(o+0, v.x); atomicAdd(o+1, v.y);
  atomicAdd(o+2, v.z); atomicAdd(o+3, v.w);
}

// ---------------- edge update ----------------
// messages[e] = relu([x[row[e]], seg[col[e]] - eh[rev[e]]] @ Wm + bm)
template<int XDIM>
__global__ __launch_bounds__(256) void k_edge(
    const float* __restrict__ xin, const u16* __restrict__ eh,
    const float* __restrict__ seg,
    const int* __restrict__ row, const int* __restrict__ col, const int* __restrict__ rev,
    const float* __restrict__ Wm, const float* __restrict__ bm,
    u16* __restrict__ msg, int E)
{
  int e = blockIdx.x*256 + threadIdx.x;
  if (e >= E) return;
  int r = row[e], c = col[e], rv = rev[e];
  float acc[64];
  #pragma unroll
  for (int j=0;j<64;j++) acc[j] = bm[j];
  const float* xr = xin + (size_t)r*XDIM;
  #pragma unroll 1
  for (int k=0;k+2<=XDIM;k+=2){
    float2 a = *(const float2*)(xr + k);
    const float* w = Wm + (size_t)k*64;
    #pragma unroll
    for (int j=0;j<64;j++) acc[j] += a.x*w[j];
    #pragma unroll
    for (int j=0;j<64;j++) acc[j] += a.y*w[64+j];
  }
  const float* sr = seg + ((size_t)c<<6);
  const float* w2 = Wm + (size_t)XDIM*64;
  bool hasrev = (rv >= 0);
  const u16* er = hasrev ? (eh + ((size_t)rv<<6)) : eh;
  #pragma unroll 1
  for (int k=0;k<64;k+=8){
    float4 s0 = *(const float4*)(sr + k);
    float4 s1 = *(const float4*)(sr + k + 4);
    float av[8] = {s0.x,s0.y,s0.z,s0.w,s1.x,s1.y,s1.z,s1.w};
    if (hasrev) {
      uint4 u = *(const uint4*)(er + k);
      av[0] -= bf2f(u.x); av[1] -= bf2f(u.x>>16);
      av[2] -= bf2f(u.y); av[3] -= bf2f(u.y>>16);
      av[4] -= bf2f(u.z); av[5] -= bf2f(u.z>>16);
      av[6] -= bf2f(u.w); av[7] -= bf2f(u.w>>16);
    }
    #pragma unroll
    for (int t=0;t<8;t++){
      const float* w = w2 + (size_t)(k+t)*64;
      #pragma unroll
      for (int j=0;j<64;j++) acc[j] += av[t]*w[j];
    }
  }
  uint4* dst = (uint4*)(msg + ((size_t)e<<6));
  #pragma unroll
  for (int q=0;q<8;q++){
    uint4 u;
    u.x = pack2(fmaxf(acc[q*8+0],0.f), fmaxf(acc[q*8+1],0.f));
    u.y = pack2(fmaxf(acc[q*8+2],0.f), fmaxf(acc[q*8+3],0.f));
    u.z = pack2(fmaxf(acc[q*8+4],0.f), fmaxf(acc[q*8+5],0.f));
    u.w = pack2(fmaxf(acc[q*8+6],0.f), fmaxf(acc[q*8+7],0.f));
    dst[q] = u;
  }
}

// ---------------- node update ----------------
// x_out[n] = relu([x[n], node_msg[n]] @ Wn + bn)
template<int XDIM>
__global__ __launch_bounds__(256) void k_node(
    const float* __restrict__ xin, const float* __restrict__ nmsg,
    const float* __restrict__ Wn, const float* __restrict__ bn,
    float* __restrict__ xout, int N)
{
  int n = blockIdx.x*256 + threadIdx.x;
  if (n >= N) return;
  float acc[64];
  #pragma unroll
  for (int j=0;j<64;j++) acc[j] = bn[j];
  const float* xr = xin + (size_t)n*XDIM;
  #pragma unroll 1
  for (int k=0;k+2<=XDIM;k+=2){
    float2 a = *(const float2*)(xr + k);
    const float* w = Wn + (size_t)k*64;
    #pragma unroll
    for (int j=0;j<64;j++) acc[j] += a.x*w[j];
    #pragma unroll
    for (int j=0;j<64;j++) acc[j] += a.y*w[64+j];
  }
  const float* mr = nmsg + ((size_t)n<<6);
  const float* w2 = Wn + (size_t)XDIM*64;
  #pragma unroll 1
  for (int k=0;k<64;k+=4){
    float4 a = *(const float4*)(mr + k);
    float av[4] = {a.x,a.y,a.z,a.w};
    #pragma unroll
    for (int t=0;t<4;t++){
      const float* w = w2 + (size_t)(k+t)*64;
      #pragma unroll
      for (int j=0;j<64;j++) acc[j] += av[t]*w[j];
    }
  }
  float4* dst = (float4*)(xout + ((size_t)n<<6));
  #pragma unroll
  for (int q=0;q<16;q++){
    dst[q] = make_float4(fmaxf(acc[q*4+0],0.f), fmaxf(acc[q*4+1],0.f),
                         fmaxf(acc[q*4+2],0.f), fmaxf(acc[q*4+3],0.f));
  }
}

// ---------------- MLP head ----------------
__global__ __launch_bounds__(256) void k_xg(
    const float* __restrict__ pooled, const float* __restrict__ Wxd,
    const float* __restrict__ bxd, float* __restrict__ xg, int B)
{
  int t = blockIdx.x*256 + threadIdx.x;
  if (t >= B*128) return;
  int r = t >> 7, j = t & 127;
  float acc = bxd[j];
  const float* p = pooled + ((size_t)r<<6);
  #pragma unroll
  for (int k=0;k<64;k++) acc += p[k]*Wxd[k*128+j];
  xg[t] = fmaxf(acc, 0.f);
}

__global__ __launch_bounds__(256) void k_h1(
    const float* __restrict__ xg, const float* __restrict__ xt,
    const float* __restrict__ W1, const float* __restrict__ b1,
    float* __restrict__ h1, int B)
{
  int t = blockIdx.x*256 + threadIdx.x;
  if (t >= B*1024) return;
  int r = t >> 10, j = t & 1023;
  float acc = b1[j];
  const float* g = xg + (size_t)r*128;
  const float* s = xt + (size_t)r*128;
  #pragma unroll 4
  for (int k=0;k<128;k++) acc += g[k]*W1[(size_t)k*1024+j];
  #pragma unroll 4
  for (int k=0;k<128;k++) acc += s[k]*W1[(size_t)(128+k)*1024+j];
  h1[t] = fmaxf(acc, 0.f);
}

__global__ __launch_bounds__(256) void k_h2(
    const float* __restrict__ h1, const float* __restrict__ W2,
    const float* __restrict__ b2, float* __restrict__ h2, int B)
{
  int t = blockIdx.x*256 + threadIdx.x;
  if (t >= B*256) return;
  int r = t >> 8, j = t & 255;
  float acc = b2[j];
  const float* h = h1 + (size_t)r*1024;
  #pragma unroll 4
  for (int k=0;k<1024;k++) acc += h[k]*W2[(size_t)k*256+j];
  h2[t] = fmaxf(acc, 0.f);
}

__global__ __launch_bounds__(256) void k_out(
    const float* __restrict__ h2, const float* __restrict__ Wo,
    const float* __restrict__ bo, float* __restrict__ out, int B)
{
  int t = blockIdx.x*256 + threadIdx.x;
  if (t >= B) return;
  float acc = bo[0];
  const float* h = h2 + (size_t)t*256;
  #pragma unroll 4
  for (int k=0;k<256;k++) acc += h[k]*Wo[k];
  out[t] = acc;
}

extern "C" void kernel_launch(void* const* d_in, const int* in_sizes, int n_in,
                              void* d_out, int out_size, void* d_ws, size_t ws_size,
                              hipStream_t stream)
{
  const float* x    = (const float*)d_in[0];
  const float* ea   = (const float*)d_in[1];
  const float* xt   = (const float*)d_in[2];
  const int*   eidx = (const int*)d_in[3];
  const int*   batch= (const int*)d_in[4];
  const float* We   = (const float*)d_in[6];
  const float* be   = (const float*)d_in[7];
  const float* Wm[3]= {(const float*)d_in[8],  (const float*)d_in[12], (const float*)d_in[16]};
  const float* bm[3]= {(const float*)d_in[9],  (const float*)d_in[13], (const float*)d_in[17]};
  const float* Wn[3]= {(const float*)d_in[10], (const float*)d_in[14], (const float*)d_in[18]};
  const float* bn[3]= {(const float*)d_in[11], (const float*)d_in[15], (const float*)d_in[19]};
  const float* Wxd  = (const float*)d_in[20];
  const float* bxd  = (const float*)d_in[21];
  const float* W1   = (const float*)d_in[22];
  const float* b1   = (const float*)d_in[23];
  const float* W2   = (const float*)d_in[24];
  const float* b2   = (const float*)d_in[25];
  const float* Wo   = (const float*)d_in[26];
  const float* bo   = (const float*)d_in[27];

  const int N = in_sizes[0] / 78;
  const int E = in_sizes[1] / 6;
  const int B = in_sizes[2] / 128;
  const int* row = eidx;
  const int* col = eidx + E;

  char* p = (char*)d_ws;
  size_t off = 0;
  auto alloc = [&](size_t b)->void* {
    void* r = p + off;
    off = (off + b + 255) & ~(size_t)255;
    return r;
  };
  int*   rev   = (int*)  alloc((size_t)E * 4);
  u16*   ehA   = (u16*)  alloc((size_t)E * 128);
  u16*   ehB   = (u16*)  alloc((size_t)E * 128);
  float* seg   = (float*)alloc((size_t)N * 256);
  float* nmsg  = (float*)alloc((size_t)N * 256);
  float* xa    = (float*)alloc((size_t)N * 256);
  float* xb    = (float*)alloc((size_t)N * 256);
  float* pooled= (float*)alloc((size_t)B * 256);
  float* xg    = (float*)alloc((size_t)B * 512);
  float* h1    = (float*)alloc((size_t)B * 4096);
  float* h2    = (float*)alloc((size_t)B * 1024);
  u64*   tab   = (u64*)ehB;   // hash table aliases ehB (dead before first ehB write)

  dim3 blk(256);
  int gE   = (E + 255) / 256;
  int gE16 = (E*16 + 255) / 256;
  int gN   = (N + 255) / 256;
  int gN16 = (N*16 + 255) / 256;

  hipMemsetAsync(tab, 0xFF, (size_t)HSIZE * 8, stream);
  k_hash_insert<<<gE, blk, 0, stream>>>(row, col, tab, E, N);
  k_hash_lookup<<<gE, blk, 0, stream>>>(row, col, tab, rev, E, N);
  k_edge_init<<<gE, blk, 0, stream>>>(ea, We, be, ehA, E);

  const u16* ehin = ehA;
  u16* ehout = ehB;
  const float* xin = x;
  for (int L = 0; L < 3; ++L) {
    float* xout = (L % 2 == 0) ? xa : xb;
    hipMemsetAsync(seg, 0, (size_t)N * 256, stream);
    k_scat_bf16<<<gE16, blk, 0, stream>>>(ehin, row, seg, E);
    if (L == 0) k_edge<78><<<gE, blk, 0, stream>>>(xin, ehin, seg, row, col, rev, Wm[L], bm[L], ehout, E);
    else        k_edge<64><<<gE, blk, 0, stream>>>(xin, ehin, seg, row, col, rev, Wm[L], bm[L], ehout, E);
    hipMemsetAsync(nmsg, 0, (size_t)N * 256, stream);
    k_scat_bf16<<<gE16, blk, 0, stream>>>(ehout, col, nmsg, E);
    if (L == 0) k_node<78><<<gN, blk, 0, stream>>>(xin, nmsg, Wn[L], bn[L], xout, N);
    else        k_node<64><<<gN, blk, 0, stream>>>(xin, nmsg, Wn[L], bn[L], xout, N);
    const u16* tmp = ehin; ehin = ehout; ehout = (u16*)tmp;
    xin = xout;
  }

  hipMemsetAsync(pooled, 0, (size_t)B * 256, stream);
  k_scat_f32<<<gN16, blk, 0, stream>>>(xa, batch, pooled, N);
  k_xg <<<(B*128 + 255)/256, blk, 0, stream>>>(pooled, Wxd, bxd, xg, B);
  k_h1 <<<(B*1024 + 255)/256, blk, 0, stream>>>(xg, xt, W1, b1, h1, B);
  k_h2 <<<(B*256 + 255)/256, blk, 0, stream>>>(h1, W2, b2, h2, B);
  k_out<<<(B + 255)/256, blk, 0, stream>>>(h2, Wo, bo, (float*)d_out, B);
}

// Round 2
// 2105.454 us; speedup vs baseline: 2.6446x; 2.6446x over previous
//
#include <hip/hip_runtime.h>
#include <hip/hip_bf16.h>

using u16 = unsigned short;
using u32 = unsigned int;
using u64 = unsigned long long;

#define HSIZE (1u<<21)
#define HMASK (HSIZE-1u)
#define HEMPTY 0xFFFFFFFFFFFFFFFFull

__device__ __forceinline__ float bf2f(u32 u){ union{u32 i; float f;} v; v.i = u<<16; return v.f; }
__device__ __forceinline__ u32 f2bf(float f){ union{float f; u32 i;} v; v.f=f; u32 i=v.i; return (i + 0x7FFFu + ((i>>16)&1u)) >> 16; }
__device__ __forceinline__ u32 pack2(float a, float b){ return f2bf(a) | (f2bf(b)<<16); }

// ---------------- reverse-edge hash ----------------
__global__ __launch_bounds__(256) void k_hash_insert(
    const int* __restrict__ row, const int* __restrict__ col,
    u64* __restrict__ tab, int E, int N)
{
  int e = blockIdx.x*256 + threadIdx.x;
  if (e >= E) return;
  u32 key = (u32)row[e] * (u32)N + (u32)col[e];
  u64 entry = ((u64)key << 32) | (u32)e;
  u32 h = (key * 2654435761u) & HMASK;
  while (true) {
    u64 old = atomicCAS(&tab[h], HEMPTY, entry);
    if (old == HEMPTY) break;
    h = (h + 1u) & HMASK;
  }
}

__global__ __launch_bounds__(256) void k_hash_lookup(
    const int* __restrict__ row, const int* __restrict__ col,
    const u64* __restrict__ tab, int* __restrict__ rev, int E, int N)
{
  int e = blockIdx.x*256 + threadIdx.x;
  if (e >= E) return;
  u32 rkey = (u32)col[e] * (u32)N + (u32)row[e];
  u32 h = (rkey * 2654435761u) & HMASK;
  int r = -1;
  while (true) {
    u64 entry = tab[h];
    if (entry == HEMPTY) break;
    if ((u32)(entry >> 32) == rkey) { r = (int)(entry & 0xFFFFFFFFull); break; }
    h = (h + 1u) & HMASK;
  }
  rev[e] = r;
}

// ---------------- CSR build ----------------
__global__ __launch_bounds__(256) void k_deg(
    const int* __restrict__ row, int* __restrict__ cnt, int E)
{
  int e = blockIdx.x*256 + threadIdx.x;
  if (e >= E) return;
  atomicAdd(&cnt[row[e]], 1);
}

// single-block exclusive scan over N counters -> off[0..N], nxt copy
__global__ __launch_bounds__(256) void k_scan(
    const int* __restrict__ cnt, int* __restrict__ off, int* __restrict__ nxt, int N)
{
  __shared__ int part[257];
  int tid = threadIdx.x;
  int chunk = (N + 255) >> 8;
  int lo = tid * chunk, hi = min(lo + chunk, N);
  if (lo > N) lo = N;
  if (hi < lo) hi = lo;
  int s = 0;
  for (int i = lo; i < hi; i++) s += cnt[i];
  part[tid + 1] = s;
  if (tid == 0) part[0] = 0;
  __syncthreads();
  if (tid == 0) { for (int i = 1; i <= 256; i++) part[i] += part[i - 1]; }
  __syncthreads();
  int run = part[tid];
  for (int i = lo; i < hi; i++) { off[i] = run; nxt[i] = run; run += cnt[i]; }
  if (tid == 255) off[N] = part[256];
}

// fill row-CSR edge list; elc[slot] = rev[e] gives the list of edges with col==n
// (valid because every edge in this dataset has a reverse: col[rev[e]] == row[e])
__global__ __launch_bounds__(256) void k_fill(
    const int* __restrict__ row, const int* __restrict__ rev,
    int* __restrict__ nxt, int* __restrict__ elr, int* __restrict__ elc, int E)
{
  int e = blockIdx.x*256 + threadIdx.x;
  if (e >= E) return;
  int r = row[e];
  int pos = atomicAdd(&nxt[r], 1);
  elr[pos] = e;
  elc[pos] = rev[e];
}

// ---------------- segment-sum via gather: one wave per node, lane = channel ----------------
__global__ __launch_bounds__(256) void k_gather64(
    const u16* __restrict__ vals, const int* __restrict__ elist,
    const int* __restrict__ off, float* __restrict__ out, int N)
{
  int w = (blockIdx.x << 2) + (threadIdx.x >> 6);
  if (w >= N) return;
  int lane = threadIdx.x & 63;
  int lo = off[w], hi = off[w + 1];
  float s = 0.f;
  for (int i = lo; i < hi; i++) {
    int e = elist[i];
    s += bf2f((u32)vals[((size_t)e << 6) + lane]);
  }
  out[((size_t)w << 6) + lane] = s;
}

// ---------------- edge init: eh = edge_attr @ We + be ----------------
__global__ __launch_bounds__(256) void k_edge_init(
    const float* __restrict__ ea, const float* __restrict__ We,
    const float* __restrict__ be, u16* __restrict__ eh, int E)
{
  int e = blockIdx.x*256 + threadIdx.x;
  if (e >= E) return;
  const float* a = ea + (size_t)e*6;
  float2 a0 = *(const float2*)(a);
  float2 a1 = *(const float2*)(a+2);
  float2 a2 = *(const float2*)(a+4);
  float av[6] = {a0.x,a0.y,a1.x,a1.y,a2.x,a2.y};
  float acc[64];
  #pragma unroll
  for (int j=0;j<64;j++) acc[j] = be[j];
  #pragma unroll
  for (int k=0;k<6;k++){
    const float* w = We + k*64;
    #pragma unroll
    for (int j=0;j<64;j++) acc[j] += av[k]*w[j];
  }
  uint4* dst = (uint4*)(eh + ((size_t)e<<6));
  #pragma unroll
  for (int q=0;q<8;q++){
    uint4 u;
    u.x = pack2(acc[q*8+0], acc[q*8+1]);
    u.y = pack2(acc[q*8+2], acc[q*8+3]);
    u.z = pack2(acc[q*8+4], acc[q*8+5]);
    u.w = pack2(acc[q*8+6], acc[q*8+7]);
    dst[q] = u;
  }
}

// ---------------- edge update ----------------
// messages[e] = relu([x[row[e]], seg[col[e]] - eh[rev[e]]] @ Wm + bm)
template<int XDIM>
__global__ __launch_bounds__(256) void k_edge(
    const float* __restrict__ xin, const u16* __restrict__ eh,
    const float* __restrict__ seg,
    const int* __restrict__ row, const int* __restrict__ col, const int* __restrict__ rev,
    const float* __restrict__ Wm, const float* __restrict__ bm,
    u16* __restrict__ msg, int E)
{
  int e = blockIdx.x*256 + threadIdx.x;
  if (e >= E) return;
  int r = row[e], c = col[e], rv = rev[e];
  float acc[64];
  #pragma unroll
  for (int j=0;j<64;j++) acc[j] = bm[j];
  const float* xr = xin + (size_t)r*XDIM;
  #pragma unroll 1
  for (int k=0;k+2<=XDIM;k+=2){
    float2 a = *(const float2*)(xr + k);
    const float* w = Wm + (size_t)k*64;
    #pragma unroll
    for (int j=0;j<64;j++) acc[j] += a.x*w[j];
    #pragma unroll
    for (int j=0;j<64;j++) acc[j] += a.y*w[64+j];
  }
  const float* sr = seg + ((size_t)c<<6);
  const float* w2 = Wm + (size_t)XDIM*64;
  bool hasrev = (rv >= 0);
  const u16* er = hasrev ? (eh + ((size_t)rv<<6)) : eh;
  #pragma unroll 1
  for (int k=0;k<64;k+=8){
    float4 s0 = *(const float4*)(sr + k);
    float4 s1 = *(const float4*)(sr + k + 4);
    float av[8] = {s0.x,s0.y,s0.z,s0.w,s1.x,s1.y,s1.z,s1.w};
    if (hasrev) {
      uint4 u = *(const uint4*)(er + k);
      av[0] -= bf2f(u.x); av[1] -= bf2f(u.x>>16);
      av[2] -= bf2f(u.y); av[3] -= bf2f(u.y>>16);
      av[4] -= bf2f(u.z); av[5] -= bf2f(u.z>>16);
      av[6] -= bf2f(u.w); av[7] -= bf2f(u.w>>16);
    }
    #pragma unroll
    for (int t=0;t<8;t++){
      const float* w = w2 + (size_t)(k+t)*64;
      #pragma unroll
      for (int j=0;j<64;j++) acc[j] += av[t]*w[j];
    }
  }
  uint4* dst = (uint4*)(msg + ((size_t)e<<6));
  #pragma unroll
  for (int q=0;q<8;q++){
    uint4 u;
    u.x = pack2(fmaxf(acc[q*8+0],0.f), fmaxf(acc[q*8+1],0.f));
    u.y = pack2(fmaxf(acc[q*8+2],0.f), fmaxf(acc[q*8+3],0.f));
    u.z = pack2(fmaxf(acc[q*8+4],0.f), fmaxf(acc[q*8+5],0.f));
    u.w = pack2(fmaxf(acc[q*8+6],0.f), fmaxf(acc[q*8+7],0.f));
    dst[q] = u;
  }
}

// ---------------- node update ----------------
// x_out[n] = relu([x[n], node_msg[n]] @ Wn + bn)
template<int XDIM>
__global__ __launch_bounds__(256) void k_node(
    const float* __restrict__ xin, const float* __restrict__ nmsg,
    const float* __restrict__ Wn, const float* __restrict__ bn,
    float* __restrict__ xout, int N)
{
  int n = blockIdx.x*256 + threadIdx.x;
  if (n >= N) return;
  float acc[64];
  #pragma unroll
  for (int j=0;j<64;j++) acc[j] = bn[j];
  const float* xr = xin + (size_t)n*XDIM;
  #pragma unroll 1
  for (int k=0;k+2<=XDIM;k+=2){
    float2 a = *(const float2*)(xr + k);
    const float* w = Wn + (size_t)k*64;
    #pragma unroll
    for (int j=0;j<64;j++) acc[j] += a.x*w[j];
    #pragma unroll
    for (int j=0;j<64;j++) acc[j] += a.y*w[64+j];
  }
  const float* mr = nmsg + ((size_t)n<<6);
  const float* w2 = Wn + (size_t)XDIM*64;
  #pragma unroll 1
  for (int k=0;k<64;k+=4){
    float4 a = *(const float4*)(mr + k);
    float av[4] = {a.x,a.y,a.z,a.w};
    #pragma unroll
    for (int t=0;t<4;t++){
      const float* w = w2 + (size_t)(k+t)*64;
      #pragma unroll
      for (int j=0;j<64;j++) acc[j] += av[t]*w[j];
    }
  }
  float4* dst = (float4*)(xout + ((size_t)n<<6));
  #pragma unroll
  for (int q=0;q<16;q++){
    dst[q] = make_float4(fmaxf(acc[q*4+0],0.f), fmaxf(acc[q*4+1],0.f),
                         fmaxf(acc[q*4+2],0.f), fmaxf(acc[q*4+3],0.f));
  }
}

// ---------------- pooling (batch is sorted) ----------------
__global__ __launch_bounds__(256) void k_goff(
    const int* __restrict__ batch, int* __restrict__ goff, int N, int B)
{
  int n = blockIdx.x*256 + threadIdx.x;
  if (n >= N) return;
  int bcur = batch[n];
  int bprev = (n == 0) ? -1 : batch[n-1];
  for (int g = bprev + 1; g <= bcur; ++g) goff[g] = n;
  if (n == N-1) { for (int g = bcur + 1; g <= B; ++g) goff[g] = N; }
}

__global__ __launch_bounds__(256) void k_pool(
    const float* __restrict__ xin, const int* __restrict__ goff,
    float* __restrict__ pooled, int B)
{
  int g = (blockIdx.x << 2) + (threadIdx.x >> 6);
  if (g >= B) return;
  int lane = threadIdx.x & 63;
  int lo = goff[g], hi = goff[g + 1];
  float s = 0.f;
  for (int n = lo; n < hi; n++) s += xin[((size_t)n << 6) + lane];
  pooled[((size_t)g << 6) + lane] = s;
}

// ---------------- MLP head ----------------
__global__ __launch_bounds__(256) void k_xg(
    const float* __restrict__ pooled, const float* __restrict__ Wxd,
    const float* __restrict__ bxd, float* __restrict__ xg, int B)
{
  int t = blockIdx.x*256 + threadIdx.x;
  if (t >= B*128) return;
  int r = t >> 7, j = t & 127;
  float acc = bxd[j];
  const float* p = pooled + ((size_t)r<<6);
  #pragma unroll
  for (int k=0;k<64;k++) acc += p[k]*Wxd[k*128+j];
  xg[t] = fmaxf(acc, 0.f);
}

__global__ __launch_bounds__(256) void k_h1(
    const float* __restrict__ xg, const float* __restrict__ xt,
    const float* __restrict__ W1, const float* __restrict__ b1,
    float* __restrict__ h1, int B)
{
  int t = blockIdx.x*256 + threadIdx.x;
  if (t >= B*1024) return;
  int r = t >> 10, j = t & 1023;
  float acc = b1[j];
  const float* g = xg + (size_t)r*128;
  const float* s = xt + (size_t)r*128;
  #pragma unroll 4
  for (int k=0;k<128;k++) acc += g[k]*W1[(size_t)k*1024+j];
  #pragma unroll 4
  for (int k=0;k<128;k++) acc += s[k]*W1[(size_t)(128+k)*1024+j];
  h1[t] = fmaxf(acc, 0.f);
}

__global__ __launch_bounds__(256) void k_h2(
    const float* __restrict__ h1, const float* __restrict__ W2,
    const float* __restrict__ b2, float* __restrict__ h2, int B)
{
  int t = blockIdx.x*256 + threadIdx.x;
  if (t >= B*256) return;
  int r = t >> 8, j = t & 255;
  float acc = b2[j];
  const float* h = h1 + (size_t)r*1024;
  #pragma unroll 4
  for (int k=0;k<1024;k++) acc += h[k]*W2[(size_t)k*256+j];
  h2[t] = fmaxf(acc, 0.f);
}

__global__ __launch_bounds__(256) void k_out(
    const float* __restrict__ h2, const float* __restrict__ Wo,
    const float* __restrict__ bo, float* __restrict__ out, int B)
{
  int t = blockIdx.x*256 + threadIdx.x;
  if (t >= B) return;
  float acc = bo[0];
  const float* h = h2 + (size_t)t*256;
  #pragma unroll 4
  for (int k=0;k<256;k++) acc += h[k]*Wo[k];
  out[t] = acc;
}

extern "C" void kernel_launch(void* const* d_in, const int* in_sizes, int n_in,
                              void* d_out, int out_size, void* d_ws, size_t ws_size,
                              hipStream_t stream)
{
  const float* x    = (const float*)d_in[0];
  const float* ea   = (const float*)d_in[1];
  const float* xt   = (const float*)d_in[2];
  const int*   eidx = (const int*)d_in[3];
  const int*   batch= (const int*)d_in[4];
  const float* We   = (const float*)d_in[6];
  const float* be   = (const float*)d_in[7];
  const float* Wm[3]= {(const float*)d_in[8],  (const float*)d_in[12], (const float*)d_in[16]};
  const float* bm[3]= {(const float*)d_in[9],  (const float*)d_in[13], (const float*)d_in[17]};
  const float* Wn[3]= {(const float*)d_in[10], (const float*)d_in[14], (const float*)d_in[18]};
  const float* bn[3]= {(const float*)d_in[11], (const float*)d_in[15], (const float*)d_in[19]};
  const float* Wxd  = (const float*)d_in[20];
  const float* bxd  = (const float*)d_in[21];
  const float* W1   = (const float*)d_in[22];
  const float* b1   = (const float*)d_in[23];
  const float* W2   = (const float*)d_in[24];
  const float* b2   = (const float*)d_in[25];
  const float* Wo   = (const float*)d_in[26];
  const float* bo   = (const float*)d_in[27];

  const int N = in_sizes[0] / 78;
  const int E = in_sizes[1] / 6;
  const int B = in_sizes[2] / 128;
  const int* row = eidx;
  const int* col = eidx + E;

  char* p = (char*)d_ws;
  size_t off = 0;
  auto alloc = [&](size_t b)->void* {
    void* r = p + off;
    off = (off + b + 255) & ~(size_t)255;
    return r;
  };
  int*   rev   = (int*)  alloc((size_t)E * 4);
  u16*   ehA   = (u16*)  alloc((size_t)E * 128);
  u16*   ehB   = (u16*)  alloc((size_t)E * 128);
  float* seg   = (float*)alloc((size_t)N * 256);
  float* nmsg  = (float*)alloc((size_t)N * 256);
  float* xa    = (float*)alloc((size_t)N * 256);
  float* xb    = (float*)alloc((size_t)N * 256);
  int*   cnt   = (int*)  alloc((size_t)N * 4);
  int*   offs  = (int*)  alloc((size_t)(N+1) * 4);
  int*   nxt   = (int*)  alloc((size_t)N * 4);
  int*   elr   = (int*)  alloc((size_t)E * 4);
  int*   elc   = (int*)  alloc((size_t)E * 4);
  int*   goff  = (int*)  alloc((size_t)(B+1) * 4);
  float* pooled= (float*)alloc((size_t)B * 256);
  float* xg    = (float*)alloc((size_t)B * 512);
  float* h1    = (float*)alloc((size_t)B * 4096);
  float* h2    = (float*)alloc((size_t)B * 1024);
  u64*   tab   = (u64*)ehB;   // hash table aliases ehB (dead before first ehB write)

  dim3 blk(256);
  int gE  = (E + 255) / 256;
  int gN  = (N + 255) / 256;
  int gNw = (N + 3) / 4;   // wave-per-node kernels
  int gBw = (B + 3) / 4;   // wave-per-graph kernels

  hipMemsetAsync(tab, 0xFF, (size_t)HSIZE * 8, stream);
  hipMemsetAsync(cnt, 0, (size_t)N * 4, stream);
  k_hash_insert<<<gE, blk, 0, stream>>>(row, col, tab, E, N);
  k_hash_lookup<<<gE, blk, 0, stream>>>(row, col, tab, rev, E, N);
  k_deg <<<gE, blk, 0, stream>>>(row, cnt, E);
  k_scan<<<1,  blk, 0, stream>>>(cnt, offs, nxt, N);
  k_fill<<<gE, blk, 0, stream>>>(row, rev, nxt, elr, elc, E);
  k_edge_init<<<gE, blk, 0, stream>>>(ea, We, be, ehA, E);
  k_goff<<<gN, blk, 0, stream>>>(batch, goff, N, B);

  const u16* ehin = ehA;
  u16* ehout = ehB;
  const float* xin = x;
  for (int L = 0; L < 3; ++L) {
    float* xout = (L % 2 == 0) ? xa : xb;
    k_gather64<<<gNw, blk, 0, stream>>>(ehin, elr, offs, seg, N);
    if (L == 0) k_edge<78><<<gE, blk, 0, stream>>>(xin, ehin, seg, row, col, rev, Wm[L], bm[L], ehout, E);
    else        k_edge<64><<<gE, blk, 0, stream>>>(xin, ehin, seg, row, col, rev, Wm[L], bm[L], ehout, E);
    k_gather64<<<gNw, blk, 0, stream>>>(ehout, elc, offs, nmsg, N);
    if (L == 0) k_node<78><<<gN, blk, 0, stream>>>(xin, nmsg, Wn[L], bn[L], xout, N);
    else        k_node<64><<<gN, blk, 0, stream>>>(xin, nmsg, Wn[L], bn[L], xout, N);
    const u16* tmp = ehin; ehin = ehout; ehout = (u16*)tmp;
    xin = xout;
  }

  k_pool<<<gBw, blk, 0, stream>>>(xa, goff, pooled, B);
  k_xg <<<(B*128 + 255)/256, blk, 0, stream>>>(pooled, Wxd, bxd, xg, B);
  k_h1 <<<(B*1024 + 255)/256, blk, 0, stream>>>(xg, xt, W1, b1, h1, B);
  k_h2 <<<(B*256 + 255)/256, blk, 0, stream>>>(h1, W2, b2, h2, B);
  k_out<<<(B + 255)/256, blk, 0, stream>>>(h2, Wo, bo, (float*)d_out, B);
}

// Round 4
// 1796.920 us; speedup vs baseline: 3.0986x; 1.1717x over previous
//
#include <hip/hip_runtime.h>
#include <hip/hip_bf16.h>

using u16 = unsigned short;
using u32 = unsigned int;
using u64 = unsigned long long;

typedef short short8 __attribute__((ext_vector_type(8)));
typedef float f32x4 __attribute__((ext_vector_type(4)));

#define HSIZE (1u<<21)
#define HMASK (HSIZE-1u)
#define HEMPTY 0xFFFFFFFFFFFFFFFFull

__device__ __forceinline__ float bf2f(u32 u){ union{u32 i; float f;} v; v.i = u<<16; return v.f; }
__device__ __forceinline__ u32 f2bf(float f){ union{float f; u32 i;} v; v.f=f; u32 i=v.i; return (i + 0x7FFFu + ((i>>16)&1u)) >> 16; }
__device__ __forceinline__ u32 pack2(float a, float b){ return f2bf(a) | (f2bf(b)<<16); }

__device__ __forceinline__ void store16bf(u16* d, const float* a){
  uint4 u0, u1;
  u0.x = pack2(a[0],a[1]);   u0.y = pack2(a[2],a[3]);
  u0.z = pack2(a[4],a[5]);   u0.w = pack2(a[6],a[7]);
  u1.x = pack2(a[8],a[9]);   u1.y = pack2(a[10],a[11]);
  u1.z = pack2(a[12],a[13]); u1.w = pack2(a[14],a[15]);
  *(uint4*)(d)   = u0;
  *(uint4*)(d+8) = u1;
}

// ---------------- reverse-edge hash ----------------
__global__ __launch_bounds__(256) void k_hash_insert(
    const int* __restrict__ row, const int* __restrict__ col,
    u64* __restrict__ tab, int E, int N)
{
  int e = blockIdx.x*256 + threadIdx.x;
  if (e >= E) return;
  u32 key = (u32)row[e] * (u32)N + (u32)col[e];
  u64 entry = ((u64)key << 32) | (u32)e;
  u32 h = (key * 2654435761u) & HMASK;
  while (true) {
    u64 old = atomicCAS(&tab[h], HEMPTY, entry);
    if (old == HEMPTY) break;
    h = (h + 1u) & HMASK;
  }
}

__global__ __launch_bounds__(256) void k_hash_lookup(
    const int* __restrict__ row, const int* __restrict__ col,
    const u64* __restrict__ tab, int* __restrict__ rev, int E, int N)
{
  int e = blockIdx.x*256 + threadIdx.x;
  if (e >= E) return;
  u32 rkey = (u32)col[e] * (u32)N + (u32)row[e];
  u32 h = (rkey * 2654435761u) & HMASK;
  int r = -1;
  while (true) {
    u64 entry = tab[h];
    if (entry == HEMPTY) break;
    if ((u32)(entry >> 32) == rkey) { r = (int)(entry & 0xFFFFFFFFull); break; }
    h = (h + 1u) & HMASK;
  }
  rev[e] = r;
}

// ---------------- CSR build ----------------
__global__ __launch_bounds__(256) void k_deg(
    const int* __restrict__ row, int* __restrict__ cnt, int E)
{
  int e = blockIdx.x*256 + threadIdx.x;
  if (e >= E) return;
  atomicAdd(&cnt[row[e]], 1);
}

__global__ __launch_bounds__(256) void k_scan(
    const int* __restrict__ cnt, int* __restrict__ off, int* __restrict__ nxt, int N)
{
  __shared__ int part[257];
  int tid = threadIdx.x;
  int chunk = (N + 255) >> 8;
  int lo = tid * chunk, hi = min(lo + chunk, N);
  if (lo > N) lo = N;
  if (hi < lo) hi = lo;
  int s = 0;
  for (int i = lo; i < hi; i++) s += cnt[i];
  part[tid + 1] = s;
  if (tid == 0) part[0] = 0;
  __syncthreads();
  if (tid == 0) { for (int i = 1; i <= 256; i++) part[i] += part[i - 1]; }
  __syncthreads();
  int run = part[tid];
  for (int i = lo; i < hi; i++) { off[i] = run; nxt[i] = run; run += cnt[i]; }
  if (tid == 255) off[N] = part[256];
}

// fill: perm[slot] = edge id, iperm[edge] = slot
__global__ __launch_bounds__(256) void k_fill(
    const int* __restrict__ row, int* __restrict__ nxt,
    int* __restrict__ perm, int* __restrict__ iperm, int E)
{
  int e = blockIdx.x*256 + threadIdx.x;
  if (e >= E) return;
  int pos = atomicAdd(&nxt[row[e]], 1);
  perm[pos] = e;
  iperm[e] = pos;
}

// permuted per-slot arrays
__global__ __launch_bounds__(256) void k_permarr(
    const int* __restrict__ perm, const int* __restrict__ iperm,
    const int* __restrict__ row, const int* __restrict__ rev,
    int* __restrict__ rowp, int* __restrict__ revp, int E)
{
  int i = blockIdx.x*256 + threadIdx.x;
  if (i >= E) return;
  int e = perm[i];
  rowp[i] = row[e];
  int r = rev[e];
  revp[i] = (r >= 0) ? iperm[r] : i;
}

// ---------------- edge init into slot order: eh_p[i] = ea[perm[i]] @ We + be ----------------
__global__ __launch_bounds__(256) void k_edge_init(
    const float* __restrict__ ea, const int* __restrict__ perm,
    const float* __restrict__ We, const float* __restrict__ be,
    u16* __restrict__ eh, int E)
{
  int tid = blockIdx.x*256 + threadIdx.x;
  int i = tid >> 2;
  if (i >= E) return;
  int t = tid & 3;
  int e = perm[i];
  const float* a = ea + (size_t)e*6;
  float acc[16];
  #pragma unroll
  for (int j=0;j<16;j++) acc[j] = be[t*16+j];
  #pragma unroll
  for (int k=0;k<6;k++){
    float av = a[k];
    const float* w = We + k*64 + t*16;
    #pragma unroll
    for (int j=0;j<16;j++) acc[j] += av*w[j];
  }
  store16bf(eh + ((size_t)i<<6) + t*16, acc);
}

// ---------------- seg[n] = sum of contiguous eh_p slots (streaming), bf16 out ----------------
__global__ __launch_bounds__(256) void k_seg(
    const u16* __restrict__ eh, const int* __restrict__ off,
    u16* __restrict__ segb, int N)
{
  int w = (blockIdx.x << 2) + (threadIdx.x >> 6);
  if (w >= N) return;
  int lane = threadIdx.x & 63;
  int lo = off[w], hi = off[w+1];
  float s = 0.f;
  for (int i = lo; i < hi; i++) s += bf2f((u32)eh[((size_t)i<<6) + lane]);
  segb[((size_t)w<<6) + lane] = (u16)f2bf(s);
}

// ---------------- node projections: px = x@Wtop + bm ; ps = seg@Wbot  (bf16 out) ----------------
template<int XDIM>
__global__ __launch_bounds__(256) void k_nodeproj(
    const float* __restrict__ xin, const u16* __restrict__ segb,
    const float* __restrict__ Wm, const float* __restrict__ bm,
    u16* __restrict__ pxb, u16* __restrict__ psb, int N)
{
  int tid = blockIdx.x*256 + threadIdx.x;
  int n = tid >> 2;
  if (n >= N) return;
  int t = tid & 3;
  float apx[16];
  #pragma unroll
  for (int j=0;j<16;j++) apx[j] = bm[t*16+j];
  const float* xr = xin + (size_t)n*XDIM;
  #pragma unroll 2
  for (int k=0;k<XDIM;k++){
    float a = xr[k];
    const float* w = Wm + (size_t)k*64 + t*16;
    #pragma unroll
    for (int j=0;j<16;j++) apx[j] += a*w[j];
  }
  float aps[16];
  #pragma unroll
  for (int j=0;j<16;j++) aps[j] = 0.f;
  const u16* sr = segb + ((size_t)n<<6);
  const float* w2 = Wm + (size_t)XDIM*64 + t*16;
  #pragma unroll 2
  for (int k=0;k<64;k++){
    float a = bf2f((u32)sr[k]);
    const float* w = w2 + (size_t)k*64;
    #pragma unroll
    for (int j=0;j<16;j++) aps[j] += a*w[j];
  }
  store16bf(pxb + ((size_t)n<<6) + t*16, apx);
  store16bf(psb + ((size_t)n<<6) + t*16, aps);
}

// ---------------- pack Wbot (64x64 f32) into MFMA B-fragment layout (bf16) ----------------
// frag id f = nt*2+kk. lane holds 8 values: B[k][n], n = nt*16 + (lane&15),
// k = (lane>>4)*8 + j + 32*kk
__global__ __launch_bounds__(256) void k_prepw(
    const float* __restrict__ Wbot, u16* __restrict__ wbuf)
{
  int tid = threadIdx.x;
  for (int fl = tid*2; fl < tid*2+2; fl++){
    int f = fl >> 6, lane = fl & 63;
    int nt = f >> 1, kk = f & 1;
    int n = (nt<<4) + (lane & 15);
    int kb = ((lane>>4)<<3) + (kk<<5);
    u16* d = wbuf + fl*8;
    #pragma unroll
    for (int j=0;j<8;j++) d[j] = (u16)f2bf(Wbot[(size_t)(kb+j)*64 + n]);
  }
}

// ---------------- MFMA projection + scatter:  valbuf[revp[i]] = ps[rowp[i]] - eh[i]@Wbot ----------------
__global__ __launch_bounds__(256) void k_scatmfma(
    const u16* __restrict__ eh, const u16* __restrict__ wbuf,
    const u16* __restrict__ psb, const int* __restrict__ rowp,
    const int* __restrict__ revp, u16* __restrict__ valbuf, int E)
{
  int lane = threadIdx.x & 63;
  int wid = (blockIdx.x << 2) + (threadIdx.x >> 6);
  int base = wid << 4;
  if (base >= E) return;
  short8 bf[4][2];
  #pragma unroll
  for (int nt=0;nt<4;nt++)
    #pragma unroll
    for (int kk=0;kk<2;kk++)
      bf[nt][kk] = *(const short8*)(wbuf + ((((nt<<1)|kk)<<6) + lane)*8);
  int sa = base + (lane & 15);
  if (sa > E-1) sa = E-1;
  const short8* ap = (const short8*)(eh + ((size_t)sa<<6) + ((lane>>4)<<3));
  short8 a0 = ap[0];
  short8 a1 = ap[4];           // +32 elements: k in [32,64)
  f32x4 acc[4];
  #pragma unroll
  for (int nt=0;nt<4;nt++){
    f32x4 z = {0.f,0.f,0.f,0.f};
    acc[nt] = z;
    acc[nt] = __builtin_amdgcn_mfma_f32_16x16x32_bf16(a0, bf[nt][0], acc[nt], 0,0,0);
    acc[nt] = __builtin_amdgcn_mfma_f32_16x16x32_bf16(a1, bf[nt][1], acc[nt], 0,0,0);
  }
  int mbase = (lane>>4)<<2;
  int nlo = lane & 15;
  #pragma unroll
  for (int r=0;r<4;r++){
    int slot = base + mbase + r;
    if (slot >= E) continue;
    int rp = rowp[slot];
    int rv = revp[slot];
    const u16* pr = psb + ((size_t)rp<<6) + nlo;
    u16* ob = valbuf + ((size_t)rv<<6) + nlo;
    #pragma unroll
    for (int nt=0;nt<4;nt++){
      float v = bf2f((u32)pr[nt<<4]) - acc[nt][r];
      ob[nt<<4] = (u16)f2bf(v);
    }
  }
}

// ---------------- combine (in-place): val[i] = relu(px[rowp[i]] + val[i]) ----------------
__global__ __launch_bounds__(256) void k_combine(
    const int* __restrict__ rowp, const u16* __restrict__ pxb,
    u16* __restrict__ val, int E)
{
  int tid = blockIdx.x*256 + threadIdx.x;
  int slot = tid >> 2;
  if (slot >= E) return;
  int t = tid & 3;
  int rp = rowp[slot];
  const u16* p = pxb + ((size_t)rp<<6) + t*16;
  u16* v = val + ((size_t)slot<<6) + t*16;
  uint4 v0 = *(const uint4*)(v);
  uint4 v1 = *(const uint4*)(v+8);
  uint4 p0 = *(const uint4*)(p);
  uint4 p1 = *(const uint4*)(p+8);
  auto comb2 = [](u32 pv, u32 vv)->u32 {
    float a0 = fmaxf(bf2f(pv)     + bf2f(vv),     0.f);
    float a1 = fmaxf(bf2f(pv>>16) + bf2f(vv>>16), 0.f);
    return pack2(a0, a1);
  };
  uint4 o0, o1;
  o0.x = comb2(p0.x, v0.x); o0.y = comb2(p0.y, v0.y);
  o0.z = comb2(p0.z, v0.z); o0.w = comb2(p0.w, v0.w);
  o1.x = comb2(p1.x, v1.x); o1.y = comb2(p1.y, v1.y);
  o1.z = comb2(p1.z, v1.z); o1.w = comb2(p1.w, v1.w);
  *(uint4*)(v)   = o0;
  *(uint4*)(v+8) = o1;
}

// ---------------- nmsg[n] = sum over j in range(n) of msg[revp[j]]  (bf16 out) ----------------
__global__ __launch_bounds__(256) void k_gnmsg(
    const u16* __restrict__ msg, const int* __restrict__ revp,
    const int* __restrict__ off, u16* __restrict__ nmsgb, int N)
{
  int w = (blockIdx.x << 2) + (threadIdx.x >> 6);
  if (w >= N) return;
  int lane = threadIdx.x & 63;
  int lo = off[w], hi = off[w+1];
  float s = 0.f;
  for (int j = lo; j < hi; j++) {
    int i = revp[j];
    s += bf2f((u32)msg[((size_t)i<<6) + lane]);
  }
  nmsgb[((size_t)w<<6) + lane] = (u16)f2bf(s);
}

// ---------------- node update: xout = relu([xin, nmsg]@Wn + bn) ----------------
template<int XDIM>
__global__ __launch_bounds__(256) void k_node(
    const float* __restrict__ xin, const u16* __restrict__ nmsgb,
    const float* __restrict__ Wn, const float* __restrict__ bn,
    float* __restrict__ xout, int N)
{
  int tid = blockIdx.x*256 + threadIdx.x;
  int n = tid >> 2;
  if (n >= N) return;
  int t = tid & 3;
  float acc[16];
  #pragma unroll
  for (int j=0;j<16;j++) acc[j] = bn[t*16+j];
  const float* xr = xin + (size_t)n*XDIM;
  #pragma unroll 2
  for (int k=0;k<XDIM;k++){
    float a = xr[k];
    const float* w = Wn + (size_t)k*64 + t*16;
    #pragma unroll
    for (int j=0;j<16;j++) acc[j] += a*w[j];
  }
  const u16* mr = nmsgb + ((size_t)n<<6);
  const float* w2 = Wn + (size_t)XDIM*64 + t*16;
  #pragma unroll 2
  for (int k=0;k<64;k++){
    float a = bf2f((u32)mr[k]);
    const float* w = w2 + (size_t)k*64;
    #pragma unroll
    for (int j=0;j<16;j++) acc[j] += a*w[j];
  }
  float* d = xout + ((size_t)n<<6) + t*16;
  #pragma unroll
  for (int j=0;j<16;j++) d[j] = fmaxf(acc[j], 0.f);
}

// ---------------- pooling (batch is sorted) ----------------
__global__ __launch_bounds__(256) void k_goff(
    const int* __restrict__ batch, int* __restrict__ goff, int N, int B)
{
  int n = blockIdx.x*256 + threadIdx.x;
  if (n >= N) return;
  int bcur = batch[n];
  int bprev = (n == 0) ? -1 : batch[n-1];
  for (int g = bprev + 1; g <= bcur; ++g) goff[g] = n;
  if (n == N-1) { for (int g = bcur + 1; g <= B; ++g) goff[g] = N; }
}

__global__ __launch_bounds__(256) void k_pool(
    const float* __restrict__ xin, const int* __restrict__ goff,
    float* __restrict__ pooled, int B)
{
  int g = (blockIdx.x << 2) + (threadIdx.x >> 6);
  if (g >= B) return;
  int lane = threadIdx.x & 63;
  int lo = goff[g], hi = goff[g + 1];
  float s = 0.f;
  for (int n = lo; n < hi; n++) s += xin[((size_t)n << 6) + lane];
  pooled[((size_t)g << 6) + lane] = s;
}

// ---------------- MLP head ----------------
__global__ __launch_bounds__(256) void k_xg(
    const float* __restrict__ pooled, const float* __restrict__ Wxd,
    const float* __restrict__ bxd, float* __restrict__ xg, int B)
{
  int t = blockIdx.x*256 + threadIdx.x;
  if (t >= B*128) return;
  int r = t >> 7, j = t & 127;
  float acc = bxd[j];
  const float* p = pooled + ((size_t)r<<6);
  #pragma unroll
  for (int k=0;k<64;k++) acc += p[k]*Wxd[k*128+j];
  xg[t] = fmaxf(acc, 0.f);
}

__global__ __launch_bounds__(256) void k_h1(
    const float* __restrict__ xg, const float* __restrict__ xt,
    const float* __restrict__ W1, const float* __restrict__ b1,
    float* __restrict__ h1, int B)
{
  int t = blockIdx.x*256 + threadIdx.x;
  if (t >= B*1024) return;
  int r = t >> 10, j = t & 1023;
  float acc = b1[j];
  const float* g = xg + (size_t)r*128;
  const float* s = xt + (size_t)r*128;
  #pragma unroll 4
  for (int k=0;k<128;k++) acc += g[k]*W1[(size_t)k*1024+j];
  #pragma unroll 4
  for (int k=0;k<128;k++) acc += s[k]*W1[(size_t)(128+k)*1024+j];
  h1[t] = fmaxf(acc, 0.f);
}

__global__ __launch_bounds__(256) void k_h2(
    const float* __restrict__ h1, const float* __restrict__ W2,
    const float* __restrict__ b2, float* __restrict__ h2, int B)
{
  int t = blockIdx.x*256 + threadIdx.x;
  if (t >= B*256) return;
  int r = t >> 8, j = t & 255;
  float acc = b2[j];
  const float* h = h1 + (size_t)r*1024;
  #pragma unroll 4
  for (int k=0;k<1024;k++) acc += h[k]*W2[(size_t)k*256+j];
  h2[t] = fmaxf(acc, 0.f);
}

__global__ __launch_bounds__(256) void k_out(
    const float* __restrict__ h2, const float* __restrict__ Wo,
    const float* __restrict__ bo, float* __restrict__ out, int B)
{
  int t = blockIdx.x*256 + threadIdx.x;
  if (t >= B) return;
  float acc = bo[0];
  const float* h = h2 + (size_t)t*256;
  #pragma unroll 4
  for (int k=0;k<256;k++) acc += h[k]*Wo[k];
  out[t] = acc;
}

extern "C" void kernel_launch(void* const* d_in, const int* in_sizes, int n_in,
                              void* d_out, int out_size, void* d_ws, size_t ws_size,
                              hipStream_t stream)
{
  const float* x    = (const float*)d_in[0];
  const float* ea   = (const float*)d_in[1];
  const float* xt   = (const float*)d_in[2];
  const int*   eidx = (const int*)d_in[3];
  const int*   batch= (const int*)d_in[4];
  const float* We   = (const float*)d_in[6];
  const float* be   = (const float*)d_in[7];
  const float* Wm[3]= {(const float*)d_in[8],  (const float*)d_in[12], (const float*)d_in[16]};
  const float* bm[3]= {(const float*)d_in[9],  (const float*)d_in[13], (const float*)d_in[17]};
  const float* Wn[3]= {(const float*)d_in[10], (const float*)d_in[14], (const float*)d_in[18]};
  const float* bn[3]= {(const float*)d_in[11], (const float*)d_in[15], (const float*)d_in[19]};
  const float* Wxd  = (const float*)d_in[20];
  const float* bxd  = (const float*)d_in[21];
  const float* W1   = (const float*)d_in[22];
  const float* b1   = (const float*)d_in[23];
  const float* W2   = (const float*)d_in[24];
  const float* b2   = (const float*)d_in[25];
  const float* Wo   = (const float*)d_in[26];
  const float* bo   = (const float*)d_in[27];

  const int N = in_sizes[0] / 78;
  const int E = in_sizes[1] / 6;
  const int B = in_sizes[2] / 128;
  const int* row = eidx;
  const int* col = eidx + E;

  char* p = (char*)d_ws;
  size_t off = 0;
  auto alloc = [&](size_t b)->void* {
    void* r = p + off;
    off = (off + b + 255) & ~(size_t)255;
    return r;
  };
  // persistent buffers (~250 MB total)
  u16*   ehA   = (u16*)  alloc((size_t)E * 128);
  u16*   ehB   = (u16*)  alloc((size_t)E * 128);
  int*   rowp  = (int*)  alloc((size_t)E * 4);
  int*   revp  = (int*)  alloc((size_t)E * 4);
  int*   offs  = (int*)  alloc((size_t)(N+1) * 4);
  u16*   segb  = (u16*)  alloc((size_t)N * 128);   // seg, then reused as nmsg
  u16*   pxb   = (u16*)  alloc((size_t)N * 128);
  u16*   psb   = (u16*)  alloc((size_t)N * 128);
  float* xa    = (float*)alloc((size_t)N * 256);
  float* xb    = (float*)alloc((size_t)N * 256);
  int*   goff  = (int*)  alloc((size_t)(B+1) * 4);
  float* pooled= (float*)alloc((size_t)B * 256);
  float* xg    = (float*)alloc((size_t)B * 512);
  float* h1    = (float*)alloc((size_t)B * 4096);
  float* h2    = (float*)alloc((size_t)B * 1024);
  u16*   wbuf  = (u16*)  alloc((size_t)4096 * 2);

  // setup transients aliased into ehB (all dead before ehB's first write in k_scatmfma L0)
  char* ehBc = (char*)ehB;
  u64* tab   = (u64*)ehBc;                                    // 16 MB
  int* rev   = (int*)(ehBc + (size_t)HSIZE*8);                // 3.2 MB
  int* perm  = rev + E;                                       // 3.2 MB
  int* iperm = perm + E;                                      // 3.2 MB
  int* cnt   = iperm + E;                                     // 0.16 MB
  int* nxt   = cnt + N;                                       // 0.16 MB

  dim3 blk(256);
  int gE   = (E + 255) / 256;
  int gE4  = ((size_t)E*4 + 255) / 256;
  int gEm  = (E + 63) / 64;      // mfma: 16 slots/wave, 4 waves/block
  int gN   = (N + 255) / 256;
  int gN4  = ((size_t)N*4 + 255) / 256;
  int gNw  = (N + 3) / 4;
  int gBw  = (B + 3) / 4;

  hipMemsetAsync(tab, 0xFF, (size_t)HSIZE * 8, stream);
  hipMemsetAsync(cnt, 0, (size_t)N * 4, stream);
  k_hash_insert<<<gE, blk, 0, stream>>>(row, col, tab, E, N);
  k_hash_lookup<<<gE, blk, 0, stream>>>(row, col, tab, rev, E, N);
  k_deg <<<gE, blk, 0, stream>>>(row, cnt, E);
  k_scan<<<1,  blk, 0, stream>>>(cnt, offs, nxt, N);
  k_fill<<<gE, blk, 0, stream>>>(row, nxt, perm, iperm, E);
  k_permarr<<<gE, blk, 0, stream>>>(perm, iperm, row, rev, rowp, revp, E);
  k_edge_init<<<gE4, blk, 0, stream>>>(ea, perm, We, be, ehA, E);
  k_goff<<<gN, blk, 0, stream>>>(batch, goff, N, B);

  const u16* ehin = ehA;
  u16* ehout = ehB;
  const float* xin = x;
  for (int L = 0; L < 3; ++L) {
    const int XD = (L == 0) ? 78 : 64;
    float* xout = (L % 2 == 0) ? xa : xb;
    k_seg<<<gNw, blk, 0, stream>>>(ehin, offs, segb, N);
    if (L == 0) k_nodeproj<78><<<gN4, blk, 0, stream>>>(xin, segb, Wm[L], bm[L], pxb, psb, N);
    else        k_nodeproj<64><<<gN4, blk, 0, stream>>>(xin, segb, Wm[L], bm[L], pxb, psb, N);
    k_prepw<<<1, blk, 0, stream>>>(Wm[L] + (size_t)XD*64, wbuf);
    k_scatmfma<<<gEm, blk, 0, stream>>>(ehin, wbuf, psb, rowp, revp, ehout, E);
    k_combine<<<gE4, blk, 0, stream>>>(rowp, pxb, ehout, E);
    k_gnmsg<<<gNw, blk, 0, stream>>>(ehout, revp, offs, segb, N);
    if (L == 0) k_node<78><<<gN4, blk, 0, stream>>>(xin, segb, Wn[L], bn[L], xout, N);
    else        k_node<64><<<gN4, blk, 0, stream>>>(xin, segb, Wn[L], bn[L], xout, N);
    u16* tmp = (u16*)ehin; ehin = ehout; ehout = tmp;
    xin = xout;
  }

  k_pool<<<gBw, blk, 0, stream>>>(xa, goff, pooled, B);
  k_xg <<<(B*128 + 255)/256, blk, 0, stream>>>(pooled, Wxd, bxd, xg, B);
  k_h1 <<<(B*1024 + 255)/256, blk, 0, stream>>>(xg, xt, W1, b1, h1, B);
  k_h2 <<<(B*256 + 255)/256, blk, 0, stream>>>(h1, W2, b2, h2, B);
  k_out<<<(B + 255)/256, blk, 0, stream>>>(h2, Wo, bo, (float*)d_out, B);
}

// Round 5
// 1178.471 us; speedup vs baseline: 4.7248x; 1.5248x over previous
//
#include <hip/hip_runtime.h>
#include <hip/hip_bf16.h>

using u16 = unsigned short;
using u32 = unsigned int;
using u64 = unsigned long long;

typedef short short8 __attribute__((ext_vector_type(8)));
typedef float f32x4 __attribute__((ext_vector_type(4)));

#define HSIZE (1u<<21)
#define HMASK (HSIZE-1u)
#define HEMPTY 0xFFFFFFFFFFFFFFFFull

// wpack section offsets (u16 units) within one layer's 20480-u16 slab
#define WP_TOP   0
#define WP_BOT   6144
#define WP_NTOP  10240
#define WP_NBOT  16384
#define WP_LAYER 20480

__device__ __forceinline__ float bf2f(u32 u){ union{u32 i; float f;} v; v.i = u<<16; return v.f; }
__device__ __forceinline__ u32 f2bf(float f){ union{float f; u32 i;} v; v.f=f; u32 i=v.i; return (i + 0x7FFFu + ((i>>16)&1u)) >> 16; }
__device__ __forceinline__ u32 pack2(float a, float b){ return f2bf(a) | (f2bf(b)<<16); }

__device__ __forceinline__ void store16bf(u16* d, const float* a){
  uint4 u0, u1;
  u0.x = pack2(a[0],a[1]);   u0.y = pack2(a[2],a[3]);
  u0.z = pack2(a[4],a[5]);   u0.w = pack2(a[6],a[7]);
  u1.x = pack2(a[8],a[9]);   u1.y = pack2(a[10],a[11]);
  u1.z = pack2(a[12],a[13]); u1.w = pack2(a[14],a[15]);
  *(uint4*)(d)   = u0;
  *(uint4*)(d+8) = u1;
}

// ---------------- reverse-edge hash ----------------
__global__ __launch_bounds__(256) void k_hash_insert(
    const int* __restrict__ row, const int* __restrict__ col,
    u64* __restrict__ tab, int E, int N)
{
  int e = blockIdx.x*256 + threadIdx.x;
  if (e >= E) return;
  u32 key = (u32)row[e] * (u32)N + (u32)col[e];
  u64 entry = ((u64)key << 32) | (u32)e;
  u32 h = (key * 2654435761u) & HMASK;
  while (true) {
    u64 old = atomicCAS(&tab[h], HEMPTY, entry);
    if (old == HEMPTY) break;
    h = (h + 1u) & HMASK;
  }
}

__global__ __launch_bounds__(256) void k_hash_lookup(
    const int* __restrict__ row, const int* __restrict__ col,
    const u64* __restrict__ tab, int* __restrict__ rev, int E, int N)
{
  int e = blockIdx.x*256 + threadIdx.x;
  if (e >= E) return;
  u32 rkey = (u32)col[e] * (u32)N + (u32)row[e];
  u32 h = (rkey * 2654435761u) & HMASK;
  int r = -1;
  while (true) {
    u64 entry = tab[h];
    if (entry == HEMPTY) break;
    if ((u32)(entry >> 32) == rkey) { r = (int)(entry & 0xFFFFFFFFull); break; }
    h = (h + 1u) & HMASK;
  }
  rev[e] = r;
}

// ---------------- CSR build ----------------
__global__ __launch_bounds__(256) void k_deg(
    const int* __restrict__ row, int* __restrict__ cnt, int E)
{
  int e = blockIdx.x*256 + threadIdx.x;
  if (e >= E) return;
  atomicAdd(&cnt[row[e]], 1);
}

__global__ __launch_bounds__(256) void k_scan(
    const int* __restrict__ cnt, int* __restrict__ off, int* __restrict__ nxt, int N)
{
  __shared__ int part[257];
  int tid = threadIdx.x;
  int chunk = (N + 255) >> 8;
  int lo = tid * chunk, hi = min(lo + chunk, N);
  if (lo > N) lo = N;
  if (hi < lo) hi = lo;
  int s = 0;
  for (int i = lo; i < hi; i++) s += cnt[i];
  part[tid + 1] = s;
  if (tid == 0) part[0] = 0;
  __syncthreads();
  if (tid == 0) { for (int i = 1; i <= 256; i++) part[i] += part[i - 1]; }
  __syncthreads();
  int run = part[tid];
  for (int i = lo; i < hi; i++) { off[i] = run; nxt[i] = run; run += cnt[i]; }
  if (tid == 255) off[N] = part[256];
}

__global__ __launch_bounds__(256) void k_fill(
    const int* __restrict__ row, int* __restrict__ nxt,
    int* __restrict__ perm, int* __restrict__ iperm, int E)
{
  int e = blockIdx.x*256 + threadIdx.x;
  if (e >= E) return;
  int pos = atomicAdd(&nxt[row[e]], 1);
  perm[pos] = e;
  iperm[e] = pos;
}

// permuted per-slot arrays: rowp, colp, revp
__global__ __launch_bounds__(256) void k_permarr(
    const int* __restrict__ perm, const int* __restrict__ iperm,
    const int* __restrict__ row, const int* __restrict__ col,
    const int* __restrict__ rev,
    int* __restrict__ rowp, int* __restrict__ colp, int* __restrict__ revp, int E)
{
  int i = blockIdx.x*256 + threadIdx.x;
  if (i >= E) return;
  int e = perm[i];
  rowp[i] = row[e];
  colp[i] = col[e];
  int r = rev[e];
  revp[i] = (r >= 0) ? iperm[r] : i;
}

// ---------------- x -> bf16 padded [N x 96] ----------------
__global__ __launch_bounds__(256) void k_xconv(
    const float* __restrict__ x, u16* __restrict__ xbf, int N)
{
  int t = blockIdx.x*256 + threadIdx.x;
  if (t >= N*96) return;
  int n = t / 96, k = t - n*96;
  xbf[t] = (k < 78) ? (u16)f2bf(x[(size_t)n*78 + k]) : (u16)0;
}

// ---------------- edge init into slot order: eh_p[i] = ea[perm[i]] @ We + be ----------------
__global__ __launch_bounds__(256) void k_edge_init(
    const float* __restrict__ ea, const int* __restrict__ perm,
    const float* __restrict__ We, const float* __restrict__ be,
    u16* __restrict__ eh, int E)
{
  int tid = blockIdx.x*256 + threadIdx.x;
  int i = tid >> 2;
  if (i >= E) return;
  int t = tid & 3;
  int e = perm[i];
  const float* a = ea + (size_t)e*6;
  float acc[16];
  #pragma unroll
  for (int j=0;j<16;j++) acc[j] = be[t*16+j];
  #pragma unroll
  for (int k=0;k<6;k++){
    float av = a[k];
    const float* w = We + k*64 + t*16;
    #pragma unroll
    for (int j=0;j<16;j++) acc[j] += av*w[j];
  }
  store16bf(eh + ((size_t)i<<6) + t*16, acc);
}

// ---------------- pack one layer's weights into MFMA B-fragments ----------------
// sections: top = Wm rows [0,XD) padded to KT*32 ; bot = Wm rows [XD,XD+64)
//           ntop = Wn rows [0,XD) padded      ; nbot = Wn rows [XD,XD+64)
// frag f = kk*4+nt; lane holds B[k][n]: n = nt*16+(lane&15), k = kk*32+(lane>>4)*8+j
__global__ __launch_bounds__(256) void k_prepw(
    const float* __restrict__ Wm, const float* __restrict__ Wn,
    int XD, int KT, u16* __restrict__ dst)
{
  int t = blockIdx.x*256 + threadIdx.x;
  int topFL = KT*256;
  const float* W; int rbase, rvalid, dofs, fl;
  if (t < topFL)                   { W = Wm; rbase = 0;  rvalid = XD; dofs = WP_TOP;  fl = t; }
  else if (t < topFL+512)          { W = Wm; rbase = XD; rvalid = 64; dofs = WP_BOT;  fl = t - topFL; }
  else if (t < 2*topFL+512)        { W = Wn; rbase = 0;  rvalid = XD; dofs = WP_NTOP; fl = t - topFL - 512; }
  else if (t < 2*topFL+1024)       { W = Wn; rbase = XD; rvalid = 64; dofs = WP_NBOT; fl = t - 2*topFL - 512; }
  else return;
  int f = fl >> 6, lane = fl & 63;
  int nt = f & 3, kk = f >> 2;
  int n = (nt<<4) + (lane & 15);
  int krel = (kk<<5) + ((lane>>4)<<3);
  u16* d = dst + dofs + (size_t)f*512 + lane*8;
  #pragma unroll
  for (int j=0;j<8;j++){
    int kr = krel + j;
    d[j] = (kr < rvalid) ? (u16)f2bf(W[(size_t)(rbase+kr)*64 + n]) : (u16)0;
  }
}

// ---------------- seg[n] = sum of contiguous eh_p slots (streaming), bf16 out ----------------
__global__ __launch_bounds__(256) void k_seg(
    const u16* __restrict__ eh, const int* __restrict__ off,
    u16* __restrict__ segb, int N)
{
  int w = (blockIdx.x << 2) + (threadIdx.x >> 6);
  if (w >= N) return;
  int lane = threadIdx.x & 63;
  int lo = off[w], hi = off[w+1];
  float s = 0.f;
  for (int i = lo; i < hi; i++) s += bf2f((u32)eh[((size_t)i<<6) + lane]);
  segb[((size_t)w<<6) + lane] = (u16)f2bf(s);
}

// ---------------- MFMA node projections: px = x@Wtop + bm ; ps = seg@Wbot ----------------
template<int KT>
__global__ __launch_bounds__(256) void k_proj(
    const u16* __restrict__ xin, const u16* __restrict__ segb,
    const u16* __restrict__ wp, const float* __restrict__ bm,
    u16* __restrict__ pxb, u16* __restrict__ psb, int N)
{
  int lane = threadIdx.x & 63;
  int wid = (blockIdx.x << 2) + (threadIdx.x >> 6);
  int base = wid << 4;
  if (base >= N) return;
  int nlo = lane & 15;
  int khi = (lane >> 4) << 3;

  short8 bt[KT][4];
  #pragma unroll
  for (int kk=0;kk<KT;kk++)
    #pragma unroll
    for (int nt=0;nt<4;nt++)
      bt[kk][nt] = *(const short8*)(wp + WP_TOP + ((size_t)((kk<<2)|nt)*64 + lane)*8);
  short8 bb[2][4];
  #pragma unroll
  for (int kk=0;kk<2;kk++)
    #pragma unroll
    for (int nt=0;nt<4;nt++)
      bb[kk][nt] = *(const short8*)(wp + WP_BOT + ((size_t)((kk<<2)|nt)*64 + lane)*8);

  int r0 = base + nlo; if (r0 > N-1) r0 = N-1;
  const u16* xrow = xin + (size_t)r0*(KT*32);
  short8 ax[KT];
  #pragma unroll
  for (int kk=0;kk<KT;kk++) ax[kk] = *(const short8*)(xrow + (kk<<5) + khi);
  const u16* srow = segb + ((size_t)r0<<6);
  short8 as[2];
  #pragma unroll
  for (int kk=0;kk<2;kk++) as[kk] = *(const short8*)(srow + (kk<<5) + khi);

  f32x4 accP[4], accS[4];
  #pragma unroll
  for (int nt=0;nt<4;nt++){ f32x4 z = {0.f,0.f,0.f,0.f}; accP[nt]=z; accS[nt]=z; }
  #pragma unroll
  for (int kk=0;kk<KT;kk++)
    #pragma unroll
    for (int nt=0;nt<4;nt++)
      accP[nt] = __builtin_amdgcn_mfma_f32_16x16x32_bf16(ax[kk], bt[kk][nt], accP[nt], 0,0,0);
  #pragma unroll
  for (int kk=0;kk<2;kk++)
    #pragma unroll
    for (int nt=0;nt<4;nt++)
      accS[nt] = __builtin_amdgcn_mfma_f32_16x16x32_bf16(as[kk], bb[kk][nt], accS[nt], 0,0,0);

  float bmv[4];
  #pragma unroll
  for (int nt=0;nt<4;nt++) bmv[nt] = bm[(nt<<4) + nlo];

  int mrow = (lane >> 4) << 2;
  #pragma unroll
  for (int r=0;r<4;r++){
    int node = base + mrow + r;
    if (node >= N) continue;
    #pragma unroll
    for (int nt=0;nt<4;nt++){
      pxb[((size_t)node<<6) + (nt<<4) + nlo] = (u16)f2bf(accP[nt][r] + bmv[nt]);
      psb[((size_t)node<<6) + (nt<<4) + nlo] = (u16)f2bf(accS[nt][r]);
    }
  }
}

// ---------------- fused MFMA edge kernel:
// msg[revp[i]] = relu( px[colp[i]] + ps[rowp[i]] - eh[i]@Wbot ) ----------------
__global__ __launch_bounds__(256) void k_scatmfma(
    const u16* __restrict__ eh, const u16* __restrict__ wp,
    const u16* __restrict__ pxb, const u16* __restrict__ psb,
    const int* __restrict__ rowp, const int* __restrict__ colp,
    const int* __restrict__ revp, u16* __restrict__ msg, int E)
{
  int lane = threadIdx.x & 63;
  int wid = (blockIdx.x << 2) + (threadIdx.x >> 6);
  int base = wid << 4;
  if (base >= E) return;
  int nlo = lane & 15;
  int khi = (lane >> 4) << 3;

  short8 bb[2][4];
  #pragma unroll
  for (int kk=0;kk<2;kk++)
    #pragma unroll
    for (int nt=0;nt<4;nt++)
      bb[kk][nt] = *(const short8*)(wp + WP_BOT + ((size_t)((kk<<2)|nt)*64 + lane)*8);

  int sa = base + nlo; if (sa > E-1) sa = E-1;
  const u16* ehp = eh + ((size_t)sa<<6) + khi;
  short8 a0 = *(const short8*)(ehp);
  short8 a1 = *(const short8*)(ehp + 32);

  f32x4 acc[4];
  #pragma unroll
  for (int nt=0;nt<4;nt++){
    f32x4 z = {0.f,0.f,0.f,0.f};
    acc[nt] = z;
    acc[nt] = __builtin_amdgcn_mfma_f32_16x16x32_bf16(a0, bb[0][nt], acc[nt], 0,0,0);
    acc[nt] = __builtin_amdgcn_mfma_f32_16x16x32_bf16(a1, bb[1][nt], acc[nt], 0,0,0);
  }

  int mrow = (lane >> 4) << 2;
  #pragma unroll
  for (int r=0;r<4;r++){
    int slot = base + mrow + r;
    if (slot >= E) continue;
    int rp = rowp[slot];
    int cp = colp[slot];
    int rv = revp[slot];
    const u16* pr = psb + ((size_t)rp<<6) + nlo;
    const u16* pc = pxb + ((size_t)cp<<6) + nlo;
    u16* ob = msg + ((size_t)rv<<6) + nlo;
    #pragma unroll
    for (int nt=0;nt<4;nt++){
      float v = bf2f((u32)pc[nt<<4]) + bf2f((u32)pr[nt<<4]) - acc[nt][r];
      ob[nt<<4] = (u16)f2bf(fmaxf(v, 0.f));
    }
  }
}

// ---------------- nmsg[n] = sum over j in rows(n) of msg[revp[j]]  (bf16 out) ----------------
__global__ __launch_bounds__(256) void k_gnmsg(
    const u16* __restrict__ msg, const int* __restrict__ revp,
    const int* __restrict__ off, u16* __restrict__ nmsgb, int N)
{
  int w = (blockIdx.x << 2) + (threadIdx.x >> 6);
  if (w >= N) return;
  int lane = threadIdx.x & 63;
  int lo = off[w], hi = off[w+1];
  float s = 0.f;
  for (int j = lo; j < hi; j++) {
    int i = revp[j];
    s += bf2f((u32)msg[((size_t)i<<6) + lane]);
  }
  nmsgb[((size_t)w<<6) + lane] = (u16)f2bf(s);
}

// ---------------- MFMA node update: xout = relu(x@WnTop + nmsg@WnBot + bn), bf16 out ----------------
template<int KT>
__global__ __launch_bounds__(256) void k_nodef(
    const u16* __restrict__ xin, const u16* __restrict__ nmsgb,
    const u16* __restrict__ wp, const float* __restrict__ bn,
    u16* __restrict__ xout, int N)
{
  int lane = threadIdx.x & 63;
  int wid = (blockIdx.x << 2) + (threadIdx.x >> 6);
  int base = wid << 4;
  if (base >= N) return;
  int nlo = lane & 15;
  int khi = (lane >> 4) << 3;

  short8 bt[KT][4];
  #pragma unroll
  for (int kk=0;kk<KT;kk++)
    #pragma unroll
    for (int nt=0;nt<4;nt++)
      bt[kk][nt] = *(const short8*)(wp + WP_NTOP + ((size_t)((kk<<2)|nt)*64 + lane)*8);
  short8 bb[2][4];
  #pragma unroll
  for (int kk=0;kk<2;kk++)
    #pragma unroll
    for (int nt=0;nt<4;nt++)
      bb[kk][nt] = *(const short8*)(wp + WP_NBOT + ((size_t)((kk<<2)|nt)*64 + lane)*8);

  int r0 = base + nlo; if (r0 > N-1) r0 = N-1;
  const u16* xrow = xin + (size_t)r0*(KT*32);
  short8 ax[KT];
  #pragma unroll
  for (int kk=0;kk<KT;kk++) ax[kk] = *(const short8*)(xrow + (kk<<5) + khi);
  const u16* mrp = nmsgb + ((size_t)r0<<6);
  short8 am[2];
  #pragma unroll
  for (int kk=0;kk<2;kk++) am[kk] = *(const short8*)(mrp + (kk<<5) + khi);

  f32x4 acc[4];
  #pragma unroll
  for (int nt=0;nt<4;nt++){ f32x4 z = {0.f,0.f,0.f,0.f}; acc[nt]=z; }
  #pragma unroll
  for (int kk=0;kk<KT;kk++)
    #pragma unroll
    for (int nt=0;nt<4;nt++)
      acc[nt] = __builtin_amdgcn_mfma_f32_16x16x32_bf16(ax[kk], bt[kk][nt], acc[nt], 0,0,0);
  #pragma unroll
  for (int kk=0;kk<2;kk++)
    #pragma unroll
    for (int nt=0;nt<4;nt++)
      acc[nt] = __builtin_amdgcn_mfma_f32_16x16x32_bf16(am[kk], bb[kk][nt], acc[nt], 0,0,0);

  float bnv[4];
  #pragma unroll
  for (int nt=0;nt<4;nt++) bnv[nt] = bn[(nt<<4) + nlo];

  int mrow = (lane >> 4) << 2;
  #pragma unroll
  for (int r=0;r<4;r++){
    int node = base + mrow + r;
    if (node >= N) continue;
    #pragma unroll
    for (int nt=0;nt<4;nt++)
      xout[((size_t)node<<6) + (nt<<4) + nlo] = (u16)f2bf(fmaxf(acc[nt][r] + bnv[nt], 0.f));
  }
}

// ---------------- pooling (batch is sorted) ----------------
__global__ __launch_bounds__(256) void k_goff(
    const int* __restrict__ batch, int* __restrict__ goff, int N, int B)
{
  int n = blockIdx.x*256 + threadIdx.x;
  if (n >= N) return;
  int bcur = batch[n];
  int bprev = (n == 0) ? -1 : batch[n-1];
  for (int g = bprev + 1; g <= bcur; ++g) goff[g] = n;
  if (n == N-1) { for (int g = bcur + 1; g <= B; ++g) goff[g] = N; }
}

__global__ __launch_bounds__(256) void k_pool(
    const u16* __restrict__ xin, const int* __restrict__ goff,
    float* __restrict__ pooled, int B)
{
  int g = (blockIdx.x << 2) + (threadIdx.x >> 6);
  if (g >= B) return;
  int lane = threadIdx.x & 63;
  int lo = goff[g], hi = goff[g + 1];
  float s = 0.f;
  for (int n = lo; n < hi; n++) s += bf2f((u32)xin[((size_t)n << 6) + lane]);
  pooled[((size_t)g << 6) + lane] = s;
}

// ---------------- MLP head ----------------
__global__ __launch_bounds__(256) void k_xg(
    const float* __restrict__ pooled, const float* __restrict__ Wxd,
    const float* __restrict__ bxd, float* __restrict__ xg, int B)
{
  int t = blockIdx.x*256 + threadIdx.x;
  if (t >= B*128) return;
  int r = t >> 7, j = t & 127;
  float acc = bxd[j];
  const float* p = pooled + ((size_t)r<<6);
  #pragma unroll
  for (int k=0;k<64;k++) acc += p[k]*Wxd[k*128+j];
  xg[t] = fmaxf(acc, 0.f);
}

__global__ __launch_bounds__(256) void k_h1(
    const float* __restrict__ xg, const float* __restrict__ xt,
    const float* __restrict__ W1, const float* __restrict__ b1,
    float* __restrict__ h1, int B)
{
  int t = blockIdx.x*256 + threadIdx.x;
  if (t >= B*1024) return;
  int r = t >> 10, j = t & 1023;
  float acc = b1[j];
  const float* g = xg + (size_t)r*128;
  const float* s = xt + (size_t)r*128;
  #pragma unroll 4
  for (int k=0;k<128;k++) acc += g[k]*W1[(size_t)k*1024+j];
  #pragma unroll 4
  for (int k=0;k<128;k++) acc += s[k]*W1[(size_t)(128+k)*1024+j];
  h1[t] = fmaxf(acc, 0.f);
}

__global__ __launch_bounds__(256) void k_h2(
    const float* __restrict__ h1, const float* __restrict__ W2,
    const float* __restrict__ b2, float* __restrict__ h2, int B)
{
  int t = blockIdx.x*256 + threadIdx.x;
  if (t >= B*256) return;
  int r = t >> 8, j = t & 255;
  float acc = b2[j];
  const float* h = h1 + (size_t)r*1024;
  #pragma unroll 4
  for (int k=0;k<1024;k++) acc += h[k]*W2[(size_t)k*256+j];
  h2[t] = fmaxf(acc, 0.f);
}

__global__ __launch_bounds__(256) void k_out(
    const float* __restrict__ h2, const float* __restrict__ Wo,
    const float* __restrict__ bo, float* __restrict__ out, int B)
{
  int t = blockIdx.x*256 + threadIdx.x;
  if (t >= B) return;
  float acc = bo[0];
  const float* h = h2 + (size_t)t*256;
  #pragma unroll 4
  for (int k=0;k<256;k++) acc += h[k]*Wo[k];
  out[t] = acc;
}

extern "C" void kernel_launch(void* const* d_in, const int* in_sizes, int n_in,
                              void* d_out, int out_size, void* d_ws, size_t ws_size,
                              hipStream_t stream)
{
  const float* x    = (const float*)d_in[0];
  const float* ea   = (const float*)d_in[1];
  const float* xt   = (const float*)d_in[2];
  const int*   eidx = (const int*)d_in[3];
  const int*   batch= (const int*)d_in[4];
  const float* We   = (const float*)d_in[6];
  const float* be   = (const float*)d_in[7];
  const float* Wm[3]= {(const float*)d_in[8],  (const float*)d_in[12], (const float*)d_in[16]};
  const float* bm[3]= {(const float*)d_in[9],  (const float*)d_in[13], (const float*)d_in[17]};
  const float* Wn[3]= {(const float*)d_in[10], (const float*)d_in[14], (const float*)d_in[18]};
  const float* bn[3]= {(const float*)d_in[11], (const float*)d_in[15], (const float*)d_in[19]};
  const float* Wxd  = (const float*)d_in[20];
  const float* bxd  = (const float*)d_in[21];
  const float* W1   = (const float*)d_in[22];
  const float* b1   = (const float*)d_in[23];
  const float* W2   = (const float*)d_in[24];
  const float* b2   = (const float*)d_in[25];
  const float* Wo   = (const float*)d_in[26];
  const float* bo   = (const float*)d_in[27];

  const int N = in_sizes[0] / 78;
  const int E = in_sizes[1] / 6;
  const int B = in_sizes[2] / 128;
  const int* row = eidx;
  const int* col = eidx + E;

  char* p = (char*)d_ws;
  size_t off = 0;
  auto alloc = [&](size_t b)->void* {
    void* r = p + off;
    off = (off + b + 255) & ~(size_t)255;
    return r;
  };
  // persistent buffers (~251 MB total; 259 MB proven safe in round 2)
  u16*   ehA   = (u16*)  alloc((size_t)E * 128);
  u16*   ehB   = (u16*)  alloc((size_t)E * 128);
  int*   rowp  = (int*)  alloc((size_t)E * 4);
  int*   colp  = (int*)  alloc((size_t)E * 4);
  int*   revp  = (int*)  alloc((size_t)E * 4);
  int*   offs  = (int*)  alloc((size_t)(N+1) * 4);
  u16*   xbf   = (u16*)  alloc((size_t)N * 192);   // [N x 96] bf16, zero-padded
  u16*   segb  = (u16*)  alloc((size_t)N * 128);   // seg, then reused as nmsg
  u16*   pxb   = (u16*)  alloc((size_t)N * 128);
  u16*   psb   = (u16*)  alloc((size_t)N * 128);
  u16*   xa    = (u16*)  alloc((size_t)N * 128);   // bf16 node states
  u16*   xb    = (u16*)  alloc((size_t)N * 128);
  int*   goff  = (int*)  alloc((size_t)(B+1) * 4);
  float* pooled= (float*)alloc((size_t)B * 256);
  float* xg    = (float*)alloc((size_t)B * 512);
  float* h1    = (float*)alloc((size_t)B * 4096);
  float* h2    = (float*)alloc((size_t)B * 1024);
  u16*   wpack = (u16*)  alloc((size_t)3 * WP_LAYER * 2);

  // setup transients aliased into ehB (all dead before ehB's first write in k_scatmfma L0)
  char* ehBc = (char*)ehB;
  u64* tab   = (u64*)ehBc;                                    // 16.8 MB
  int* rev   = (int*)(ehBc + (size_t)HSIZE*8);                // 3.2 MB
  int* perm  = rev + E;                                       // 3.2 MB
  int* iperm = perm + E;                                      // 3.2 MB
  int* cnt   = iperm + E;                                     // 0.16 MB
  int* nxt   = cnt + N;                                       // 0.16 MB

  dim3 blk(256);
  int gE   = (E + 255) / 256;
  int gE4  = ((size_t)E*4 + 255) / 256;
  int gEm  = (E + 63) / 64;      // mfma edge: 16 slots/wave, 4 waves/block
  int gN   = (N + 255) / 256;
  int gNm  = (N + 63) / 64;      // mfma node: 16 rows/wave, 4 waves/block
  int gNw  = (N + 3) / 4;
  int gBw  = (B + 3) / 4;
  int gXc  = (N*96 + 255) / 256;

  hipMemsetAsync(tab, 0xFF, (size_t)HSIZE * 8, stream);
  hipMemsetAsync(cnt, 0, (size_t)N * 4, stream);
  k_hash_insert<<<gE, blk, 0, stream>>>(row, col, tab, E, N);
  k_hash_lookup<<<gE, blk, 0, stream>>>(row, col, tab, rev, E, N);
  k_deg <<<gE, blk, 0, stream>>>(row, cnt, E);
  k_scan<<<1,  blk, 0, stream>>>(cnt, offs, nxt, N);
  k_fill<<<gE, blk, 0, stream>>>(row, nxt, perm, iperm, E);
  k_permarr<<<gE, blk, 0, stream>>>(perm, iperm, row, col, rev, rowp, colp, revp, E);
  k_edge_init<<<gE4, blk, 0, stream>>>(ea, perm, We, be, ehA, E);
  k_xconv<<<gXc, blk, 0, stream>>>(x, xbf, N);
  k_goff<<<gN, blk, 0, stream>>>(batch, goff, N, B);
  for (int L = 0; L < 3; ++L) {
    int XD = (L == 0) ? 78 : 64;
    int KT = (L == 0) ? 3 : 2;
    k_prepw<<<10, blk, 0, stream>>>(Wm[L], Wn[L], XD, KT, wpack + (size_t)L*WP_LAYER);
  }

  const u16* ehin = ehA;
  u16* ehout = ehB;
  const u16* xin = xbf;
  for (int L = 0; L < 3; ++L) {
    u16* xout = (L % 2 == 0) ? xa : xb;
    const u16* wp = wpack + (size_t)L*WP_LAYER;
    k_seg<<<gNw, blk, 0, stream>>>(ehin, offs, segb, N);
    if (L == 0) k_proj<3><<<gNm, blk, 0, stream>>>(xin, segb, wp, bm[L], pxb, psb, N);
    else        k_proj<2><<<gNm, blk, 0, stream>>>(xin, segb, wp, bm[L], pxb, psb, N);
    k_scatmfma<<<gEm, blk, 0, stream>>>(ehin, wp, pxb, psb, rowp, colp, revp, ehout, E);
    k_gnmsg<<<gNw, blk, 0, stream>>>(ehout, revp, offs, segb, N);
    if (L == 0) k_nodef<3><<<gNm, blk, 0, stream>>>(xin, segb, wp, bn[L], xout, N);
    else        k_nodef<2><<<gNm, blk, 0, stream>>>(xin, segb, wp, bn[L], xout, N);
    u16* tmp = (u16*)ehin; ehin = ehout; ehout = tmp;
    xin = xout;
  }

  k_pool<<<gBw, blk, 0, stream>>>(xa, goff, pooled, B);
  k_xg <<<(B*128 + 255)/256, blk, 0, stream>>>(pooled, Wxd, bxd, xg, B);
  k_h1 <<<(B*1024 + 255)/256, blk, 0, stream>>>(xg, xt, W1, b1, h1, B);
  k_h2 <<<(B*256 + 255)/256, blk, 0, stream>>>(h1, W2, b2, h2, B);
  k_out<<<(B + 255)/256, blk, 0, stream>>>(h2, Wo, bo, (float*)d_out, B);
}

// Round 6
// 1064.210 us; speedup vs baseline: 5.2321x; 1.1074x over previous
//
#include <hip/hip_runtime.h>
#include <hip/hip_bf16.h>

using u16 = unsigned short;
using u32 = unsigned int;
using u64 = unsigned long long;

typedef short short8 __attribute__((ext_vector_type(8)));
typedef float f32x4 __attribute__((ext_vector_type(4)));

#define HSIZE (1u<<21)
#define HMASK (HSIZE-1u)
#define HEMPTY 0xFFFFFFFFFFFFFFFFull

// wpack section offsets (u16 units) within one layer's 20480-u16 slab
#define WP_TOP   0
#define WP_BOT   6144
#define WP_NTOP  10240
#define WP_NBOT  16384
#define WP_LAYER 20480

__device__ __forceinline__ float bf2f(u32 u){ union{u32 i; float f;} v; v.i = u<<16; return v.f; }
__device__ __forceinline__ u32 f2bf(float f){ union{float f; u32 i;} v; v.f=f; u32 i=v.i; return (i + 0x7FFFu + ((i>>16)&1u)) >> 16; }
__device__ __forceinline__ u32 pack2(float a, float b){ return f2bf(a) | (f2bf(b)<<16); }

__device__ __forceinline__ void store16bf(u16* d, const float* a){
  uint4 u0, u1;
  u0.x = pack2(a[0],a[1]);   u0.y = pack2(a[2],a[3]);
  u0.z = pack2(a[4],a[5]);   u0.w = pack2(a[6],a[7]);
  u1.x = pack2(a[8],a[9]);   u1.y = pack2(a[10],a[11]);
  u1.z = pack2(a[12],a[13]); u1.w = pack2(a[14],a[15]);
  *(uint4*)(d)   = u0;
  *(uint4*)(d+8) = u1;
}

// ---------------- reverse-edge hash ----------------
__global__ __launch_bounds__(256) void k_hash_insert(
    const int* __restrict__ row, const int* __restrict__ col,
    u64* __restrict__ tab, int E, int N)
{
  int e = blockIdx.x*256 + threadIdx.x;
  if (e >= E) return;
  u32 key = (u32)row[e] * (u32)N + (u32)col[e];
  u64 entry = ((u64)key << 32) | (u32)e;
  u32 h = (key * 2654435761u) & HMASK;
  while (true) {
    u64 old = atomicCAS(&tab[h], HEMPTY, entry);
    if (old == HEMPTY) break;
    h = (h + 1u) & HMASK;
  }
}

__global__ __launch_bounds__(256) void k_hash_lookup(
    const int* __restrict__ row, const int* __restrict__ col,
    const u64* __restrict__ tab, int* __restrict__ rev, int E, int N)
{
  int e = blockIdx.x*256 + threadIdx.x;
  if (e >= E) return;
  u32 rkey = (u32)col[e] * (u32)N + (u32)row[e];
  u32 h = (rkey * 2654435761u) & HMASK;
  int r = -1;
  while (true) {
    u64 entry = tab[h];
    if (entry == HEMPTY) break;
    if ((u32)(entry >> 32) == rkey) { r = (int)(entry & 0xFFFFFFFFull); break; }
    h = (h + 1u) & HMASK;
  }
  rev[e] = r;
}

// ---------------- CSR build ----------------
__global__ __launch_bounds__(256) void k_deg(
    const int* __restrict__ row, int* __restrict__ cnt, int E)
{
  int e = blockIdx.x*256 + threadIdx.x;
  if (e >= E) return;
  atomicAdd(&cnt[row[e]], 1);
}

__global__ __launch_bounds__(256) void k_scan(
    const int* __restrict__ cnt, int* __restrict__ off, int* __restrict__ nxt, int N)
{
  __shared__ int part[257];
  int tid = threadIdx.x;
  int chunk = (N + 255) >> 8;
  int lo = tid * chunk, hi = min(lo + chunk, N);
  if (lo > N) lo = N;
  if (hi < lo) hi = lo;
  int s = 0;
  for (int i = lo; i < hi; i++) s += cnt[i];
  part[tid + 1] = s;
  if (tid == 0) part[0] = 0;
  __syncthreads();
  if (tid == 0) { for (int i = 1; i <= 256; i++) part[i] += part[i - 1]; }
  __syncthreads();
  int run = part[tid];
  for (int i = lo; i < hi; i++) { off[i] = run; nxt[i] = run; run += cnt[i]; }
  if (tid == 255) off[N] = part[256];
}

__global__ __launch_bounds__(256) void k_fill(
    const int* __restrict__ row, int* __restrict__ nxt,
    int* __restrict__ perm, int* __restrict__ iperm, int E)
{
  int e = blockIdx.x*256 + threadIdx.x;
  if (e >= E) return;
  int pos = atomicAdd(&nxt[row[e]], 1);
  perm[pos] = e;
  iperm[e] = pos;
}

// permuted per-slot arrays: rowp, colp, revp
__global__ __launch_bounds__(256) void k_permarr(
    const int* __restrict__ perm, const int* __restrict__ iperm,
    const int* __restrict__ row, const int* __restrict__ col,
    const int* __restrict__ rev,
    int* __restrict__ rowp, int* __restrict__ colp, int* __restrict__ revp, int E)
{
  int i = blockIdx.x*256 + threadIdx.x;
  if (i >= E) return;
  int e = perm[i];
  rowp[i] = row[e];
  colp[i] = col[e];
  int r = rev[e];
  revp[i] = (r >= 0) ? iperm[r] : i;
}

// ---------------- x -> bf16 padded [N x 96] ----------------
__global__ __launch_bounds__(256) void k_xconv(
    const float* __restrict__ x, u16* __restrict__ xbf, int N)
{
  int t = blockIdx.x*256 + threadIdx.x;
  if (t >= N*96) return;
  int n = t / 96, k = t - n*96;
  xbf[t] = (k < 78) ? (u16)f2bf(x[(size_t)n*78 + k]) : (u16)0;
}

// ---------------- edge init into slot order: eh_p[i] = ea[perm[i]] @ We + be ----------------
__global__ __launch_bounds__(256) void k_edge_init(
    const float* __restrict__ ea, const int* __restrict__ perm,
    const float* __restrict__ We, const float* __restrict__ be,
    u16* __restrict__ eh, int E)
{
  int tid = blockIdx.x*256 + threadIdx.x;
  int i = tid >> 2;
  if (i >= E) return;
  int t = tid & 3;
  int e = perm[i];
  const float* a = ea + (size_t)e*6;
  float acc[16];
  #pragma unroll
  for (int j=0;j<16;j++) acc[j] = be[t*16+j];
  #pragma unroll
  for (int k=0;k<6;k++){
    float av = a[k];
    const float* w = We + k*64 + t*16;
    #pragma unroll
    for (int j=0;j<16;j++) acc[j] += av*w[j];
  }
  store16bf(eh + ((size_t)i<<6) + t*16, acc);
}

// ---------------- pack one conv layer's weights into MFMA B-fragments ----------------
__global__ __launch_bounds__(256) void k_prepw(
    const float* __restrict__ Wm, const float* __restrict__ Wn,
    int XD, int KT, u16* __restrict__ dst)
{
  int t = blockIdx.x*256 + threadIdx.x;
  int topFL = KT*256;
  const float* W; int rbase, rvalid, dofs, fl;
  if (t < topFL)                   { W = Wm; rbase = 0;  rvalid = XD; dofs = WP_TOP;  fl = t; }
  else if (t < topFL+512)          { W = Wm; rbase = XD; rvalid = 64; dofs = WP_BOT;  fl = t - topFL; }
  else if (t < 2*topFL+512)        { W = Wn; rbase = 0;  rvalid = XD; dofs = WP_NTOP; fl = t - topFL - 512; }
  else if (t < 2*topFL+1024)       { W = Wn; rbase = XD; rvalid = 64; dofs = WP_NBOT; fl = t - 2*topFL - 512; }
  else return;
  int f = fl >> 6, lane = fl & 63;
  int nt = f & 3, kk = f >> 2;
  int n = (nt<<4) + (lane & 15);
  int krel = (kk<<5) + ((lane>>4)<<3);
  u16* d = dst + dofs + (size_t)f*512 + lane*8;
  #pragma unroll
  for (int j=0;j<8;j++){
    int kr = krel + j;
    d[j] = (kr < rvalid) ? (u16)f2bf(W[(size_t)(rbase+kr)*64 + n]) : (u16)0;
  }
}

// ---------------- generic pack: W [K x Nout] f32 -> B-frags (frag f = kk*NT+nt) ----------------
__global__ __launch_bounds__(256) void k_packw(
    const float* __restrict__ W, int K, int Nout, u16* __restrict__ dst)
{
  int t = blockIdx.x*256 + threadIdx.x;
  int NT = Nout >> 4;
  int total = (K >> 5) * NT * 64;
  if (t >= total) return;
  int f = t >> 6, lane = t & 63;
  int nt = f % NT, kk = f / NT;
  int n = (nt<<4) + (lane & 15);
  int kb = (kk<<5) + ((lane>>4)<<3);
  u16* d = dst + ((size_t)f*64 + lane)*8;
  #pragma unroll
  for (int j=0;j<8;j++) d[j] = (u16)f2bf(W[(size_t)(kb+j)*Nout + n]);
}

// ---------------- generic MFMA GEMM: out[M x Nout] = act(A[M x K] @ Wpack + bias) ----------------
// A bf16 (lda u16-stride), out written at col offset inside row of stride ldo.
// obf16: 1 -> write bf16 (u16*), 0 -> write f32 (float*)
__global__ __launch_bounds__(256) void k_gemm(
    const u16* __restrict__ A, int lda, const u16* __restrict__ BP,
    const float* __restrict__ bias, void* __restrict__ outv, int ldo,
    int M, int NT, int KT, int dorelu, int obf16)
{
  int lane = threadIdx.x & 63;
  int wid = (blockIdx.x << 2) + (threadIdx.x >> 6);
  int nb = NT >> 2;               // 64-col blocks
  int mblk = wid / nb, nblk = wid - mblk*nb;
  int m0 = mblk << 4;
  if (m0 >= M) return;
  int n0 = nblk << 6;
  int nlo = lane & 15;
  int khi = (lane >> 4) << 3;
  int r0 = m0 + nlo; if (r0 > M-1) r0 = M-1;

  f32x4 acc[4];
  #pragma unroll
  for (int nt=0;nt<4;nt++){ f32x4 z = {0.f,0.f,0.f,0.f}; acc[nt]=z; }
  for (int kk=0; kk<KT; kk++){
    short8 a = *(const short8*)(A + (size_t)r0*lda + (kk<<5) + khi);
    #pragma unroll
    for (int nt=0;nt<4;nt++){
      short8 b = *(const short8*)(BP + ((size_t)(kk*NT + (nblk<<2) + nt)*64 + lane)*8);
      acc[nt] = __builtin_amdgcn_mfma_f32_16x16x32_bf16(a, b, acc[nt], 0,0,0);
    }
  }
  int mrow = (lane >> 4) << 2;
  #pragma unroll
  for (int r=0;r<4;r++){
    int m = m0 + mrow + r;
    if (m >= M) continue;
    #pragma unroll
    for (int nt=0;nt<4;nt++){
      float v = acc[nt][r] + bias[n0 + (nt<<4) + nlo];
      if (dorelu) v = fmaxf(v, 0.f);
      if (obf16) ((u16*)outv)[(size_t)m*ldo + n0 + (nt<<4) + nlo] = (u16)f2bf(v);
      else       ((float*)outv)[(size_t)m*ldo + n0 + (nt<<4) + nlo] = v;
    }
  }
}

// ---------------- seg[n] = sum of contiguous eh_p slots (streaming), bf16 out ----------------
__global__ __launch_bounds__(256) void k_seg(
    const u16* __restrict__ eh, const int* __restrict__ off,
    u16* __restrict__ segb, int N)
{
  int w = (blockIdx.x << 2) + (threadIdx.x >> 6);
  if (w >= N) return;
  int lane = threadIdx.x & 63;
  int lo = off[w], hi = off[w+1];
  float s = 0.f;
  for (int i = lo; i < hi; i++) s += bf2f((u32)eh[((size_t)i<<6) + lane]);
  segb[((size_t)w<<6) + lane] = (u16)f2bf(s);
}

// ---------------- MFMA node projections: px = x@Wtop + bm ; ps = seg@Wbot ----------------
template<int KT>
__global__ __launch_bounds__(256) void k_proj(
    const u16* __restrict__ xin, const u16* __restrict__ segb,
    const u16* __restrict__ wp, const float* __restrict__ bm,
    u16* __restrict__ pxb, u16* __restrict__ psb, int N)
{
  int lane = threadIdx.x & 63;
  int wid = (blockIdx.x << 2) + (threadIdx.x >> 6);
  int base = wid << 4;
  if (base >= N) return;
  int nlo = lane & 15;
  int khi = (lane >> 4) << 3;

  short8 bt[KT][4];
  #pragma unroll
  for (int kk=0;kk<KT;kk++)
    #pragma unroll
    for (int nt=0;nt<4;nt++)
      bt[kk][nt] = *(const short8*)(wp + WP_TOP + ((size_t)((kk<<2)|nt)*64 + lane)*8);
  short8 bb[2][4];
  #pragma unroll
  for (int kk=0;kk<2;kk++)
    #pragma unroll
    for (int nt=0;nt<4;nt++)
      bb[kk][nt] = *(const short8*)(wp + WP_BOT + ((size_t)((kk<<2)|nt)*64 + lane)*8);

  int r0 = base + nlo; if (r0 > N-1) r0 = N-1;
  const u16* xrow = xin + (size_t)r0*(KT*32);
  short8 ax[KT];
  #pragma unroll
  for (int kk=0;kk<KT;kk++) ax[kk] = *(const short8*)(xrow + (kk<<5) + khi);
  const u16* srow = segb + ((size_t)r0<<6);
  short8 as[2];
  #pragma unroll
  for (int kk=0;kk<2;kk++) as[kk] = *(const short8*)(srow + (kk<<5) + khi);

  f32x4 accP[4], accS[4];
  #pragma unroll
  for (int nt=0;nt<4;nt++){ f32x4 z = {0.f,0.f,0.f,0.f}; accP[nt]=z; accS[nt]=z; }
  #pragma unroll
  for (int kk=0;kk<KT;kk++)
    #pragma unroll
    for (int nt=0;nt<4;nt++)
      accP[nt] = __builtin_amdgcn_mfma_f32_16x16x32_bf16(ax[kk], bt[kk][nt], accP[nt], 0,0,0);
  #pragma unroll
  for (int kk=0;kk<2;kk++)
    #pragma unroll
    for (int nt=0;nt<4;nt++)
      accS[nt] = __builtin_amdgcn_mfma_f32_16x16x32_bf16(as[kk], bb[kk][nt], accS[nt], 0,0,0);

  float bmv[4];
  #pragma unroll
  for (int nt=0;nt<4;nt++) bmv[nt] = bm[(nt<<4) + nlo];

  int mrow = (lane >> 4) << 2;
  #pragma unroll
  for (int r=0;r<4;r++){
    int node = base + mrow + r;
    if (node >= N) continue;
    #pragma unroll
    for (int nt=0;nt<4;nt++){
      pxb[((size_t)node<<6) + (nt<<4) + nlo] = (u16)f2bf(accP[nt][r] + bmv[nt]);
      psb[((size_t)node<<6) + (nt<<4) + nlo] = (u16)f2bf(accS[nt][r]);
    }
  }
}

// ---------------- fused MFMA edge kernel:
// msg[revp[i]] = relu( px[colp[i]] + ps[rowp[i]] - eh[i]@Wbot ) ----------------
__global__ __launch_bounds__(256) void k_scatmfma(
    const u16* __restrict__ eh, const u16* __restrict__ wp,
    const u16* __restrict__ pxb, const u16* __restrict__ psb,
    const int* __restrict__ rowp, const int* __restrict__ colp,
    const int* __restrict__ revp, u16* __restrict__ msg, int E)
{
  int lane = threadIdx.x & 63;
  int wid = (blockIdx.x << 2) + (threadIdx.x >> 6);
  int base = wid << 4;
  if (base >= E) return;
  int nlo = lane & 15;
  int khi = (lane >> 4) << 3;

  short8 bb[2][4];
  #pragma unroll
  for (int kk=0;kk<2;kk++)
    #pragma unroll
    for (int nt=0;nt<4;nt++)
      bb[kk][nt] = *(const short8*)(wp + WP_BOT + ((size_t)((kk<<2)|nt)*64 + lane)*8);

  int sa = base + nlo; if (sa > E-1) sa = E-1;
  const u16* ehp = eh + ((size_t)sa<<6) + khi;
  short8 a0 = *(const short8*)(ehp);
  short8 a1 = *(const short8*)(ehp + 32);

  f32x4 acc[4];
  #pragma unroll
  for (int nt=0;nt<4;nt++){
    f32x4 z = {0.f,0.f,0.f,0.f};
    acc[nt] = z;
    acc[nt] = __builtin_amdgcn_mfma_f32_16x16x32_bf16(a0, bb[0][nt], acc[nt], 0,0,0);
    acc[nt] = __builtin_amdgcn_mfma_f32_16x16x32_bf16(a1, bb[1][nt], acc[nt], 0,0,0);
  }

  int mrow = (lane >> 4) << 2;
  #pragma unroll
  for (int r=0;r<4;r++){
    int slot = base + mrow + r;
    if (slot >= E) continue;
    int rp = rowp[slot];
    int cp = colp[slot];
    int rv = revp[slot];
    const u16* pr = psb + ((size_t)rp<<6) + nlo;
    const u16* pc = pxb + ((size_t)cp<<6) + nlo;
    u16* ob = msg + ((size_t)rv<<6) + nlo;
    #pragma unroll
    for (int nt=0;nt<4;nt++){
      float v = bf2f((u32)pc[nt<<4]) + bf2f((u32)pr[nt<<4]) - acc[nt][r];
      ob[nt<<4] = (u16)f2bf(fmaxf(v, 0.f));
    }
  }
}

// ---------------- nmsg[n] = sum over j in rows(n) of msg[revp[j]]  (bf16 out) ----------------
__global__ __launch_bounds__(256) void k_gnmsg(
    const u16* __restrict__ msg, const int* __restrict__ revp,
    const int* __restrict__ off, u16* __restrict__ nmsgb, int N)
{
  int w = (blockIdx.x << 2) + (threadIdx.x >> 6);
  if (w >= N) return;
  int lane = threadIdx.x & 63;
  int lo = off[w], hi = off[w+1];
  float s = 0.f;
  for (int j = lo; j < hi; j++) {
    int i = revp[j];
    s += bf2f((u32)msg[((size_t)i<<6) + lane]);
  }
  nmsgb[((size_t)w<<6) + lane] = (u16)f2bf(s);
}

// ---------------- MFMA node update: xout = relu(x@WnTop + nmsg@WnBot + bn), bf16 out ----------------
template<int KT>
__global__ __launch_bounds__(256) void k_nodef(
    const u16* __restrict__ xin, const u16* __restrict__ nmsgb,
    const u16* __restrict__ wp, const float* __restrict__ bn,
    u16* __restrict__ xout, int N)
{
  int lane = threadIdx.x & 63;
  int wid = (blockIdx.x << 2) + (threadIdx.x >> 6);
  int base = wid << 4;
  if (base >= N) return;
  int nlo = lane & 15;
  int khi = (lane >> 4) << 3;

  short8 bt[KT][4];
  #pragma unroll
  for (int kk=0;kk<KT;kk++)
    #pragma unroll
    for (int nt=0;nt<4;nt++)
      bt[kk][nt] = *(const short8*)(wp + WP_NTOP + ((size_t)((kk<<2)|nt)*64 + lane)*8);
  short8 bb[2][4];
  #pragma unroll
  for (int kk=0;kk<2;kk++)
    #pragma unroll
    for (int nt=0;nt<4;nt++)
      bb[kk][nt] = *(const short8*)(wp + WP_NBOT + ((size_t)((kk<<2)|nt)*64 + lane)*8);

  int r0 = base + nlo; if (r0 > N-1) r0 = N-1;
  const u16* xrow = xin + (size_t)r0*(KT*32);
  short8 ax[KT];
  #pragma unroll
  for (int kk=0;kk<KT;kk++) ax[kk] = *(const short8*)(xrow + (kk<<5) + khi);
  const u16* mrp = nmsgb + ((size_t)r0<<6);
  short8 am[2];
  #pragma unroll
  for (int kk=0;kk<2;kk++) am[kk] = *(const short8*)(mrp + (kk<<5) + khi);

  f32x4 acc[4];
  #pragma unroll
  for (int nt=0;nt<4;nt++){ f32x4 z = {0.f,0.f,0.f,0.f}; acc[nt]=z; }
  #pragma unroll
  for (int kk=0;kk<KT;kk++)
    #pragma unroll
    for (int nt=0;nt<4;nt++)
      acc[nt] = __builtin_amdgcn_mfma_f32_16x16x32_bf16(ax[kk], bt[kk][nt], acc[nt], 0,0,0);
  #pragma unroll
  for (int kk=0;kk<2;kk++)
    #pragma unroll
    for (int nt=0;nt<4;nt++)
      acc[nt] = __builtin_amdgcn_mfma_f32_16x16x32_bf16(am[kk], bb[kk][nt], acc[nt], 0,0,0);

  float bnv[4];
  #pragma unroll
  for (int nt=0;nt<4;nt++) bnv[nt] = bn[(nt<<4) + nlo];

  int mrow = (lane >> 4) << 2;
  #pragma unroll
  for (int r=0;r<4;r++){
    int node = base + mrow + r;
    if (node >= N) continue;
    #pragma unroll
    for (int nt=0;nt<4;nt++)
      xout[((size_t)node<<6) + (nt<<4) + nlo] = (u16)f2bf(fmaxf(acc[nt][r] + bnv[nt], 0.f));
  }
}

// ---------------- pooling (batch is sorted), bf16 out ----------------
__global__ __launch_bounds__(256) void k_goff(
    const int* __restrict__ batch, int* __restrict__ goff, int N, int B)
{
  int n = blockIdx.x*256 + threadIdx.x;
  if (n >= N) return;
  int bcur = batch[n];
  int bprev = (n == 0) ? -1 : batch[n-1];
  for (int g = bprev + 1; g <= bcur; ++g) goff[g] = n;
  if (n == N-1) { for (int g = bcur + 1; g <= B; ++g) goff[g] = N; }
}

__global__ __launch_bounds__(256) void k_pool(
    const u16* __restrict__ xin, const int* __restrict__ goff,
    u16* __restrict__ pooledb, int B)
{
  int g = (blockIdx.x << 2) + (threadIdx.x >> 6);
  if (g >= B) return;
  int lane = threadIdx.x & 63;
  int lo = goff[g], hi = goff[g + 1];
  float s = 0.f;
  for (int n = lo; n < hi; n++) s += bf2f((u32)xin[((size_t)n << 6) + lane]);
  pooledb[((size_t)g << 6) + lane] = (u16)f2bf(s);
}

// ---------------- xt -> bf16 into ab1 cols 128..255 ----------------
__global__ __launch_bounds__(256) void k_xtconv(
    const float* __restrict__ xt, u16* __restrict__ ab1, int B)
{
  int t = blockIdx.x*256 + threadIdx.x;
  if (t >= B*128) return;
  int r = t >> 7, c = t & 127;
  ab1[(size_t)r*256 + 128 + c] = (u16)f2bf(xt[t]);
}

// ---------------- final dot: out[r] = h2[r]·Wo + bo (wave per row) ----------------
__global__ __launch_bounds__(256) void k_out(
    const float* __restrict__ h2, const float* __restrict__ Wo,
    const float* __restrict__ bo, float* __restrict__ out, int B)
{
  int w = (blockIdx.x << 2) + (threadIdx.x >> 6);
  if (w >= B) return;
  int lane = threadIdx.x & 63;
  const float* h = h2 + (size_t)w*256;
  float s = 0.f;
  #pragma unroll
  for (int k=0;k<4;k++) s += h[lane + (k<<6)] * Wo[lane + (k<<6)];
  #pragma unroll
  for (int off=32; off; off>>=1) s += __shfl_down(s, off, 64);
  if (lane == 0) out[w] = s + bo[0];
}

extern "C" void kernel_launch(void* const* d_in, const int* in_sizes, int n_in,
                              void* d_out, int out_size, void* d_ws, size_t ws_size,
                              hipStream_t stream)
{
  const float* x    = (const float*)d_in[0];
  const float* ea   = (const float*)d_in[1];
  const float* xt   = (const float*)d_in[2];
  const int*   eidx = (const int*)d_in[3];
  const int*   batch= (const int*)d_in[4];
  const float* We   = (const float*)d_in[6];
  const float* be   = (const float*)d_in[7];
  const float* Wm[3]= {(const float*)d_in[8],  (const float*)d_in[12], (const float*)d_in[16]};
  const float* bm[3]= {(const float*)d_in[9],  (const float*)d_in[13], (const float*)d_in[17]};
  const float* Wn[3]= {(const float*)d_in[10], (const float*)d_in[14], (const float*)d_in[18]};
  const float* bn[3]= {(const float*)d_in[11], (const float*)d_in[15], (const float*)d_in[19]};
  const float* Wxd  = (const float*)d_in[20];
  const float* bxd  = (const float*)d_in[21];
  const float* W1   = (const float*)d_in[22];
  const float* b1   = (const float*)d_in[23];
  const float* W2   = (const float*)d_in[24];
  const float* b2   = (const float*)d_in[25];
  const float* Wo   = (const float*)d_in[26];
  const float* bo   = (const float*)d_in[27];

  const int N = in_sizes[0] / 78;
  const int E = in_sizes[1] / 6;
  const int B = in_sizes[2] / 128;
  const int* row = eidx;
  const int* col = eidx + E;

  char* p = (char*)d_ws;
  size_t off = 0;
  auto alloc = [&](size_t b)->void* {
    void* r = p + off;
    off = (off + b + 255) & ~(size_t)255;
    return r;
  };
  // persistent buffers (~252 MB total; 259 MB proven safe in round 2)
  u16*   ehA   = (u16*)  alloc((size_t)E * 128);
  u16*   ehB   = (u16*)  alloc((size_t)E * 128);
  int*   rowp  = (int*)  alloc((size_t)E * 4);
  int*   colp  = (int*)  alloc((size_t)E * 4);
  int*   revp  = (int*)  alloc((size_t)E * 4);
  int*   offs  = (int*)  alloc((size_t)(N+1) * 4);
  u16*   xbf   = (u16*)  alloc((size_t)N * 192);   // [N x 96] bf16, zero-padded
  u16*   segb  = (u16*)  alloc((size_t)N * 128);   // seg, then reused as nmsg
  u16*   pxb   = (u16*)  alloc((size_t)N * 128);
  u16*   psb   = (u16*)  alloc((size_t)N * 128);
  u16*   xa    = (u16*)  alloc((size_t)N * 128);   // bf16 node states
  u16*   xb    = (u16*)  alloc((size_t)N * 128);
  int*   goff  = (int*)  alloc((size_t)(B+1) * 4);
  u16*   pooledb=(u16*)  alloc((size_t)B * 128);   // [B x 64] bf16
  u16*   ab1   = (u16*)  alloc((size_t)B * 512);   // [B x 256] bf16 (xg | xt)
  u16*   h1b   = (u16*)  alloc((size_t)B * 2048);  // [B x 1024] bf16
  float* h2f   = (float*)alloc((size_t)B * 1024);  // [B x 256] f32
  u16*   wpack = (u16*)  alloc((size_t)3 * WP_LAYER * 2);
  u16*   wxdP  = (u16*)  alloc((size_t)(64/32)*(128/16)*512 * 2);    // 16 frags
  u16*   w1P   = (u16*)  alloc((size_t)(256/32)*(1024/16)*512 * 2);  // 512 frags
  u16*   w2P   = (u16*)  alloc((size_t)(1024/32)*(256/16)*512 * 2);  // 512 frags

  // setup transients aliased into ehB (all dead before ehB's first write in k_scatmfma L0)
  char* ehBc = (char*)ehB;
  u64* tab   = (u64*)ehBc;                                    // 16.8 MB
  int* rev   = (int*)(ehBc + (size_t)HSIZE*8);                // 3.2 MB
  int* perm  = rev + E;                                       // 3.2 MB
  int* iperm = perm + E;                                      // 3.2 MB
  int* cnt   = iperm + E;                                     // 0.16 MB
  int* nxt   = cnt + N;                                       // 0.16 MB

  dim3 blk(256);
  int gE   = (E + 255) / 256;
  int gE4  = ((size_t)E*4 + 255) / 256;
  int gEm  = (E + 63) / 64;      // mfma edge: 16 slots/wave, 4 waves/block
  int gN   = (N + 255) / 256;
  int gNm  = (N + 63) / 64;      // mfma node: 16 rows/wave, 4 waves/block
  int gNw  = (N + 3) / 4;
  int gBw  = (B + 3) / 4;
  int gXc  = (N*96 + 255) / 256;

  hipMemsetAsync(tab, 0xFF, (size_t)HSIZE * 8, stream);
  hipMemsetAsync(cnt, 0, (size_t)N * 4, stream);
  k_hash_insert<<<gE, blk, 0, stream>>>(row, col, tab, E, N);
  k_hash_lookup<<<gE, blk, 0, stream>>>(row, col, tab, rev, E, N);
  k_deg <<<gE, blk, 0, stream>>>(row, cnt, E);
  k_scan<<<1,  blk, 0, stream>>>(cnt, offs, nxt, N);
  k_fill<<<gE, blk, 0, stream>>>(row, nxt, perm, iperm, E);
  k_permarr<<<gE, blk, 0, stream>>>(perm, iperm, row, col, rev, rowp, colp, revp, E);
  k_edge_init<<<gE4, blk, 0, stream>>>(ea, perm, We, be, ehA, E);
  k_xconv<<<gXc, blk, 0, stream>>>(x, xbf, N);
  k_goff<<<gN, blk, 0, stream>>>(batch, goff, N, B);
  for (int L = 0; L < 3; ++L) {
    int XD = (L == 0) ? 78 : 64;
    int KT = (L == 0) ? 3 : 2;
    k_prepw<<<10, blk, 0, stream>>>(Wm[L], Wn[L], XD, KT, wpack + (size_t)L*WP_LAYER);
  }
  k_packw<<<(1024 + 255)/256, blk, 0, stream>>>(Wxd, 64, 128, wxdP);
  k_packw<<<(32768 + 255)/256, blk, 0, stream>>>(W1, 256, 1024, w1P);
  k_packw<<<(32768 + 255)/256, blk, 0, stream>>>(W2, 1024, 256, w2P);

  const u16* ehin = ehA;
  u16* ehout = ehB;
  const u16* xin = xbf;
  for (int L = 0; L < 3; ++L) {
    u16* xout = (L % 2 == 0) ? xa : xb;
    const u16* wp = wpack + (size_t)L*WP_LAYER;
    k_seg<<<gNw, blk, 0, stream>>>(ehin, offs, segb, N);
    if (L == 0) k_proj<3><<<gNm, blk, 0, stream>>>(xin, segb, wp, bm[L], pxb, psb, N);
    else        k_proj<2><<<gNm, blk, 0, stream>>>(xin, segb, wp, bm[L], pxb, psb, N);
    k_scatmfma<<<gEm, blk, 0, stream>>>(ehin, wp, pxb, psb, rowp, colp, revp, ehout, E);
    k_gnmsg<<<gNw, blk, 0, stream>>>(ehout, revp, offs, segb, N);
    if (L == 0) k_nodef<3><<<gNm, blk, 0, stream>>>(xin, segb, wp, bn[L], xout, N);
    else        k_nodef<2><<<gNm, blk, 0, stream>>>(xin, segb, wp, bn[L], xout, N);
    u16* tmp = (u16*)ehin; ehin = ehout; ehout = tmp;
    xin = xout;
  }

  k_pool<<<gBw, blk, 0, stream>>>(xa, goff, pooledb, B);
  k_xtconv<<<(B*128 + 255)/256, blk, 0, stream>>>(xt, ab1, B);
  // xg = relu(pooled @ Wxd + bxd) -> ab1 cols [0,128)
  {
    int waves = ((B + 15)/16) * (128/64);
    k_gemm<<<(waves + 3)/4, blk, 0, stream>>>(pooledb, 64, wxdP, bxd, ab1, 256, B, 128>>4, 64>>5, 1, 1);
  }
  // h1 = relu(ab1 @ W1 + b1)
  {
    int waves = ((B + 15)/16) * (1024/64);
    k_gemm<<<(waves + 3)/4, blk, 0, stream>>>(ab1, 256, w1P, b1, h1b, 1024, B, 1024>>4, 256>>5, 1, 1);
  }
  // h2 = relu(h1 @ W2 + b2) -> f32
  {
    int waves = ((B + 15)/16) * (256/64);
    k_gemm<<<(waves + 3)/4, blk, 0, stream>>>(h1b, 1024, w2P, b2, h2f, 256, B, 256>>4, 1024>>5, 1, 0);
  }
  k_out<<<gBw, blk, 0, stream>>>(h2f, Wo, bo, (float*)d_out, B);
}

// Round 7
// 815.377 us; speedup vs baseline: 6.8288x; 1.3052x over previous
//
#include <hip/hip_runtime.h>
#include <hip/hip_bf16.h>

using u16 = unsigned short;
using u32 = unsigned int;
using u64 = unsigned long long;

typedef short short8 __attribute__((ext_vector_type(8)));
typedef float f32x4 __attribute__((ext_vector_type(4)));

// wpack section offsets (u16 units) within one layer's 20480-u16 slab
#define WP_TOP   0
#define WP_BOT   6144
#define WP_NTOP  10240
#define WP_NBOT  16384
#define WP_LAYER 20480

__device__ __forceinline__ float bf2f(u32 u){ union{u32 i; float f;} v; v.i = u<<16; return v.f; }
__device__ __forceinline__ u32 f2bf(float f){ union{float f; u32 i;} v; v.f=f; u32 i=v.i; return (i + 0x7FFFu + ((i>>16)&1u)) >> 16; }
__device__ __forceinline__ u32 pack2(float a, float b){ return f2bf(a) | (f2bf(b)<<16); }

__device__ __forceinline__ void store16bf(u16* d, const float* a){
  uint4 u0, u1;
  u0.x = pack2(a[0],a[1]);   u0.y = pack2(a[2],a[3]);
  u0.z = pack2(a[4],a[5]);   u0.w = pack2(a[6],a[7]);
  u1.x = pack2(a[8],a[9]);   u1.y = pack2(a[10],a[11]);
  u1.z = pack2(a[12],a[13]); u1.w = pack2(a[14],a[15]);
  *(uint4*)(d)   = u0;
  *(uint4*)(d+8) = u1;
}

// ---------------- CSR build ----------------
__global__ __launch_bounds__(256) void k_deg(
    const int* __restrict__ row, int* __restrict__ cnt, int E)
{
  int e = blockIdx.x*256 + threadIdx.x;
  if (e >= E) return;
  atomicAdd(&cnt[row[e]], 1);
}

// phase 1: per-block (256-chunk) sums
__global__ __launch_bounds__(256) void k_bsum(
    const int* __restrict__ cnt, int* __restrict__ bsum, int N)
{
  __shared__ int sh[256];
  int t = threadIdx.x;
  int i = blockIdx.x*256 + t;
  sh[t] = (i < N) ? cnt[i] : 0;
  __syncthreads();
  #pragma unroll
  for (int s=128; s; s>>=1){ if (t<s) sh[t]+=sh[t+s]; __syncthreads(); }
  if (t==0) bsum[blockIdx.x] = sh[0];
}

// phase 2: single-block exclusive scan of block sums (nb <= 256); writes off[N]=total
__global__ __launch_bounds__(256) void k_bscan(
    const int* __restrict__ bsum, int* __restrict__ bofs, int nb,
    int* __restrict__ off, int N)
{
  __shared__ int sh[256];
  int t = threadIdx.x;
  int v = (t < nb) ? bsum[t] : 0;
  sh[t] = v;
  __syncthreads();
  #pragma unroll
  for (int s=1; s<256; s<<=1){
    int u = (t>=s) ? sh[t-s] : 0;
    __syncthreads();
    sh[t] += u;
    __syncthreads();
  }
  if (t < nb) bofs[t] = sh[t] - v;          // exclusive
  if (t == 0) off[N] = sh[nb-1];            // grand total (nb>=1)
}

// phase 3: per-block exclusive scan + block offset -> off, nxt
__global__ __launch_bounds__(256) void k_apply(
    const int* __restrict__ cnt, const int* __restrict__ bofs,
    int* __restrict__ off, int* __restrict__ nxt, int N)
{
  __shared__ int sh[256];
  int t = threadIdx.x;
  int i = blockIdx.x*256 + t;
  int v = (i < N) ? cnt[i] : 0;
  sh[t] = v;
  __syncthreads();
  #pragma unroll
  for (int s=1; s<256; s<<=1){
    int u = (t>=s) ? sh[t-s] : 0;
    __syncthreads();
    sh[t] += u;
    __syncthreads();
  }
  if (i < N){
    int ex = sh[t] - v + bofs[blockIdx.x];
    off[i] = ex;
    nxt[i] = ex;
  }
}

__global__ __launch_bounds__(256) void k_fill(
    const int* __restrict__ row, int* __restrict__ nxt,
    int* __restrict__ perm, int* __restrict__ iperm, int E)
{
  int e = blockIdx.x*256 + threadIdx.x;
  if (e >= E) return;
  int pos = atomicAdd(&nxt[row[e]], 1);
  perm[pos] = e;
  iperm[e] = pos;
}

// permuted per-slot arrays; structural reverse: rev(e) = e<E2 ? e+E2 : e-E2
__global__ __launch_bounds__(256) void k_permarr(
    const int* __restrict__ perm, const int* __restrict__ iperm,
    const int* __restrict__ row, const int* __restrict__ col,
    int* __restrict__ rowp, int* __restrict__ colp, int* __restrict__ revp,
    int E, int E2)
{
  int i = blockIdx.x*256 + threadIdx.x;
  if (i >= E) return;
  int e = perm[i];
  rowp[i] = row[e];
  colp[i] = col[e];
  int re = (e < E2) ? e + E2 : e - E2;
  revp[i] = iperm[re];
}

// ---------------- x -> bf16 padded [N x 96] ----------------
__global__ __launch_bounds__(256) void k_xconv(
    const float* __restrict__ x, u16* __restrict__ xbf, int N)
{
  int t = blockIdx.x*256 + threadIdx.x;
  if (t >= N*96) return;
  int n = t / 96, k = t - n*96;
  xbf[t] = (k < 78) ? (u16)f2bf(x[(size_t)n*78 + k]) : (u16)0;
}

// ---------------- edge init into slot order: eh_p[i] = ea[perm[i]] @ We + be ----------------
__global__ __launch_bounds__(256) void k_edge_init(
    const float* __restrict__ ea, const int* __restrict__ perm,
    const float* __restrict__ We, const float* __restrict__ be,
    u16* __restrict__ eh, int E)
{
  int tid = blockIdx.x*256 + threadIdx.x;
  int i = tid >> 2;
  if (i >= E) return;
  int t = tid & 3;
  int e = perm[i];
  const float* a = ea + (size_t)e*6;
  float acc[16];
  #pragma unroll
  for (int j=0;j<16;j++) acc[j] = be[t*16+j];
  #pragma unroll
  for (int k=0;k<6;k++){
    float av = a[k];
    const float* w = We + k*64 + t*16;
    #pragma unroll
    for (int j=0;j<16;j++) acc[j] += av*w[j];
  }
  store16bf(eh + ((size_t)i<<6) + t*16, acc);
}

// ---------------- pack one conv layer's weights into MFMA B-fragments ----------------
__global__ __launch_bounds__(256) void k_prepw(
    const float* __restrict__ Wm, const float* __restrict__ Wn,
    int XD, int KT, u16* __restrict__ dst)
{
  int t = blockIdx.x*256 + threadIdx.x;
  int topFL = KT*256;
  const float* W; int rbase, rvalid, dofs, fl;
  if (t < topFL)                   { W = Wm; rbase = 0;  rvalid = XD; dofs = WP_TOP;  fl = t; }
  else if (t < topFL+512)          { W = Wm; rbase = XD; rvalid = 64; dofs = WP_BOT;  fl = t - topFL; }
  else if (t < 2*topFL+512)        { W = Wn; rbase = 0;  rvalid = XD; dofs = WP_NTOP; fl = t - topFL - 512; }
  else if (t < 2*topFL+1024)       { W = Wn; rbase = XD; rvalid = 64; dofs = WP_NBOT; fl = t - 2*topFL - 512; }
  else return;
  int f = fl >> 6, lane = fl & 63;
  int nt = f & 3, kk = f >> 2;
  int n = (nt<<4) + (lane & 15);
  int krel = (kk<<5) + ((lane>>4)<<3);
  u16* d = dst + dofs + (size_t)f*512 + lane*8;
  #pragma unroll
  for (int j=0;j<8;j++){
    int kr = krel + j;
    d[j] = (kr < rvalid) ? (u16)f2bf(W[(size_t)(rbase+kr)*64 + n]) : (u16)0;
  }
}

// ---------------- generic pack: W [K x Nout] f32 -> B-frags (frag f = kk*NT+nt) ----------------
__global__ __launch_bounds__(256) void k_packw(
    const float* __restrict__ W, int K, int Nout, u16* __restrict__ dst)
{
  int t = blockIdx.x*256 + threadIdx.x;
  int NT = Nout >> 4;
  int total = (K >> 5) * NT * 64;
  if (t >= total) return;
  int f = t >> 6, lane = t & 63;
  int nt = f % NT, kk = f / NT;
  int n = (nt<<4) + (lane & 15);
  int kb = (kk<<5) + ((lane>>4)<<3);
  u16* d = dst + ((size_t)f*64 + lane)*8;
  #pragma unroll
  for (int j=0;j<8;j++) d[j] = (u16)f2bf(W[(size_t)(kb+j)*Nout + n]);
}

// ---------------- generic MFMA GEMM: out[M x Nout] = act(A[M x K] @ Wpack + bias) ----------------
__global__ __launch_bounds__(256) void k_gemm(
    const u16* __restrict__ A, int lda, const u16* __restrict__ BP,
    const float* __restrict__ bias, void* __restrict__ outv, int ldo,
    int M, int NT, int KT, int dorelu, int obf16)
{
  int lane = threadIdx.x & 63;
  int wid = (blockIdx.x << 2) + (threadIdx.x >> 6);
  int nb = NT >> 2;               // 64-col blocks
  int mblk = wid / nb, nblk = wid - mblk*nb;
  int m0 = mblk << 4;
  if (m0 >= M) return;
  int n0 = nblk << 6;
  int nlo = lane & 15;
  int khi = (lane >> 4) << 3;
  int r0 = m0 + nlo; if (r0 > M-1) r0 = M-1;

  f32x4 acc[4];
  #pragma unroll
  for (int nt=0;nt<4;nt++){ f32x4 z = {0.f,0.f,0.f,0.f}; acc[nt]=z; }
  for (int kk=0; kk<KT; kk++){
    short8 a = *(const short8*)(A + (size_t)r0*lda + (kk<<5) + khi);
    #pragma unroll
    for (int nt=0;nt<4;nt++){
      short8 b = *(const short8*)(BP + ((size_t)(kk*NT + (nblk<<2) + nt)*64 + lane)*8);
      acc[nt] = __builtin_amdgcn_mfma_f32_16x16x32_bf16(a, b, acc[nt], 0,0,0);
    }
  }
  int mrow = (lane >> 4) << 2;
  #pragma unroll
  for (int r=0;r<4;r++){
    int m = m0 + mrow + r;
    if (m >= M) continue;
    #pragma unroll
    for (int nt=0;nt<4;nt++){
      float v = acc[nt][r] + bias[n0 + (nt<<4) + nlo];
      if (dorelu) v = fmaxf(v, 0.f);
      if (obf16) ((u16*)outv)[(size_t)m*ldo + n0 + (nt<<4) + nlo] = (u16)f2bf(v);
      else       ((float*)outv)[(size_t)m*ldo + n0 + (nt<<4) + nlo] = v;
    }
  }
}

// ---------------- seg[n] = sum of contiguous eh_p slots (streaming), bf16 out ----------------
__global__ __launch_bounds__(256) void k_seg(
    const u16* __restrict__ eh, const int* __restrict__ off,
    u16* __restrict__ segb, int N)
{
  int w = (blockIdx.x << 2) + (threadIdx.x >> 6);
  if (w >= N) return;
  int lane = threadIdx.x & 63;
  int lo = off[w], hi = off[w+1];
  float s = 0.f;
  for (int i = lo; i < hi; i++) s += bf2f((u32)eh[((size_t)i<<6) + lane]);
  segb[((size_t)w<<6) + lane] = (u16)f2bf(s);
}

// ---------------- MFMA node projections: px = x@Wtop + bm ; ps = seg@Wbot ----------------
template<int KT>
__global__ __launch_bounds__(256) void k_proj(
    const u16* __restrict__ xin, const u16* __restrict__ segb,
    const u16* __restrict__ wp, const float* __restrict__ bm,
    u16* __restrict__ pxb, u16* __restrict__ psb, int N)
{
  int lane = threadIdx.x & 63;
  int wid = (blockIdx.x << 2) + (threadIdx.x >> 6);
  int base = wid << 4;
  if (base >= N) return;
  int nlo = lane & 15;
  int khi = (lane >> 4) << 3;

  short8 bt[KT][4];
  #pragma unroll
  for (int kk=0;kk<KT;kk++)
    #pragma unroll
    for (int nt=0;nt<4;nt++)
      bt[kk][nt] = *(const short8*)(wp + WP_TOP + ((size_t)((kk<<2)|nt)*64 + lane)*8);
  short8 bb[2][4];
  #pragma unroll
  for (int kk=0;kk<2;kk++)
    #pragma unroll
    for (int nt=0;nt<4;nt++)
      bb[kk][nt] = *(const short8*)(wp + WP_BOT + ((size_t)((kk<<2)|nt)*64 + lane)*8);

  int r0 = base + nlo; if (r0 > N-1) r0 = N-1;
  const u16* xrow = xin + (size_t)r0*(KT*32);
  short8 ax[KT];
  #pragma unroll
  for (int kk=0;kk<KT;kk++) ax[kk] = *(const short8*)(xrow + (kk<<5) + khi);
  const u16* srow = segb + ((size_t)r0<<6);
  short8 as[2];
  #pragma unroll
  for (int kk=0;kk<2;kk++) as[kk] = *(const short8*)(srow + (kk<<5) + khi);

  f32x4 accP[4], accS[4];
  #pragma unroll
  for (int nt=0;nt<4;nt++){ f32x4 z = {0.f,0.f,0.f,0.f}; accP[nt]=z; accS[nt]=z; }
  #pragma unroll
  for (int kk=0;kk<KT;kk++)
    #pragma unroll
    for (int nt=0;nt<4;nt++)
      accP[nt] = __builtin_amdgcn_mfma_f32_16x16x32_bf16(ax[kk], bt[kk][nt], accP[nt], 0,0,0);
  #pragma unroll
  for (int kk=0;kk<2;kk++)
    #pragma unroll
    for (int nt=0;nt<4;nt++)
      accS[nt] = __builtin_amdgcn_mfma_f32_16x16x32_bf16(as[kk], bb[kk][nt], accS[nt], 0,0,0);

  float bmv[4];
  #pragma unroll
  for (int nt=0;nt<4;nt++) bmv[nt] = bm[(nt<<4) + nlo];

  int mrow = (lane >> 4) << 2;
  #pragma unroll
  for (int r=0;r<4;r++){
    int node = base + mrow + r;
    if (node >= N) continue;
    #pragma unroll
    for (int nt=0;nt<4;nt++){
      pxb[((size_t)node<<6) + (nt<<4) + nlo] = (u16)f2bf(accP[nt][r] + bmv[nt]);
      psb[((size_t)node<<6) + (nt<<4) + nlo] = (u16)f2bf(accS[nt][r]);
    }
  }
}

// ---------------- fused MFMA edge kernel:
// msg[revp[i]] = relu( px[colp[i]] + ps[rowp[i]] - eh[i]@Wbot ) ----------------
__global__ __launch_bounds__(256) void k_scatmfma(
    const u16* __restrict__ eh, const u16* __restrict__ wp,
    const u16* __restrict__ pxb, const u16* __restrict__ psb,
    const int* __restrict__ rowp, const int* __restrict__ colp,
    const int* __restrict__ revp, u16* __restrict__ msg, int E)
{
  int lane = threadIdx.x & 63;
  int wid = (blockIdx.x << 2) + (threadIdx.x >> 6);
  int base = wid << 4;
  if (base >= E) return;
  int nlo = lane & 15;
  int khi = (lane >> 4) << 3;

  short8 bb[2][4];
  #pragma unroll
  for (int kk=0;kk<2;kk++)
    #pragma unroll
    for (int nt=0;nt<4;nt++)
      bb[kk][nt] = *(const short8*)(wp + WP_BOT + ((size_t)((kk<<2)|nt)*64 + lane)*8);

  int sa = base + nlo; if (sa > E-1) sa = E-1;
  const u16* ehp = eh + ((size_t)sa<<6) + khi;
  short8 a0 = *(const short8*)(ehp);
  short8 a1 = *(const short8*)(ehp + 32);

  f32x4 acc[4];
  #pragma unroll
  for (int nt=0;nt<4;nt++){
    f32x4 z = {0.f,0.f,0.f,0.f};
    acc[nt] = z;
    acc[nt] = __builtin_amdgcn_mfma_f32_16x16x32_bf16(a0, bb[0][nt], acc[nt], 0,0,0);
    acc[nt] = __builtin_amdgcn_mfma_f32_16x16x32_bf16(a1, bb[1][nt], acc[nt], 0,0,0);
  }

  int mrow = (lane >> 4) << 2;
  #pragma unroll
  for (int r=0;r<4;r++){
    int slot = base + mrow + r;
    if (slot >= E) continue;
    int rp = rowp[slot];
    int cp = colp[slot];
    int rv = revp[slot];
    const u16* pr = psb + ((size_t)rp<<6) + nlo;
    const u16* pc = pxb + ((size_t)cp<<6) + nlo;
    u16* ob = msg + ((size_t)rv<<6) + nlo;
    #pragma unroll
    for (int nt=0;nt<4;nt++){
      float v = bf2f((u32)pc[nt<<4]) + bf2f((u32)pr[nt<<4]) - acc[nt][r];
      ob[nt<<4] = (u16)f2bf(fmaxf(v, 0.f));
    }
  }
}

// ---------------- fused: nmsg[n] = Σ msg[revp[j]]; segnext[n] = Σ msg[j]  (bf16 out) ----------------
__global__ __launch_bounds__(256) void k_gnmsg(
    const u16* __restrict__ msg, const int* __restrict__ revp,
    const int* __restrict__ off, u16* __restrict__ nmsgb,
    u16* __restrict__ segnext, int N)
{
  int w = (blockIdx.x << 2) + (threadIdx.x >> 6);
  if (w >= N) return;
  int lane = threadIdx.x & 63;
  int lo = off[w], hi = off[w+1];
  float s = 0.f, sg = 0.f;
  if (segnext) {
    for (int j = lo; j < hi; j++) {
      int i = revp[j];
      s  += bf2f((u32)msg[((size_t)i<<6) + lane]);
      sg += bf2f((u32)msg[((size_t)j<<6) + lane]);
    }
    segnext[((size_t)w<<6) + lane] = (u16)f2bf(sg);
  } else {
    for (int j = lo; j < hi; j++) {
      int i = revp[j];
      s += bf2f((u32)msg[((size_t)i<<6) + lane]);
    }
  }
  nmsgb[((size_t)w<<6) + lane] = (u16)f2bf(s);
}

// ---------------- MFMA node update: xout = relu(x@WnTop + nmsg@WnBot + bn), bf16 out ----------------
template<int KT>
__global__ __launch_bounds__(256) void k_nodef(
    const u16* __restrict__ xin, const u16* __restrict__ nmsgb,
    const u16* __restrict__ wp, const float* __restrict__ bn,
    u16* __restrict__ xout, int N)
{
  int lane = threadIdx.x & 63;
  int wid = (blockIdx.x << 2) + (threadIdx.x >> 6);
  int base = wid << 4;
  if (base >= N) return;
  int nlo = lane & 15;
  int khi = (lane >> 4) << 3;

  short8 bt[KT][4];
  #pragma unroll
  for (int kk=0;kk<KT;kk++)
    #pragma unroll
    for (int nt=0;nt<4;nt++)
      bt[kk][nt] = *(const short8*)(wp + WP_NTOP + ((size_t)((kk<<2)|nt)*64 + lane)*8);
  short8 bb[2][4];
  #pragma unroll
  for (int kk=0;kk<2;kk++)
    #pragma unroll
    for (int nt=0;nt<4;nt++)
      bb[kk][nt] = *(const short8*)(wp + WP_NBOT + ((size_t)((kk<<2)|nt)*64 + lane)*8);

  int r0 = base + nlo; if (r0 > N-1) r0 = N-1;
  const u16* xrow = xin + (size_t)r0*(KT*32);
  short8 ax[KT];
  #pragma unroll
  for (int kk=0;kk<KT;kk++) ax[kk] = *(const short8*)(xrow + (kk<<5) + khi);
  const u16* mrp = nmsgb + ((size_t)r0<<6);
  short8 am[2];
  #pragma unroll
  for (int kk=0;kk<2;kk++) am[kk] = *(const short8*)(mrp + (kk<<5) + khi);

  f32x4 acc[4];
  #pragma unroll
  for (int nt=0;nt<4;nt++){ f32x4 z = {0.f,0.f,0.f,0.f}; acc[nt]=z; }
  #pragma unroll
  for (int kk=0;kk<KT;kk++)
    #pragma unroll
    for (int nt=0;nt<4;nt++)
      acc[nt] = __builtin_amdgcn_mfma_f32_16x16x32_bf16(ax[kk], bt[kk][nt], acc[nt], 0,0,0);
  #pragma unroll
  for (int kk=0;kk<2;kk++)
    #pragma unroll
    for (int nt=0;nt<4;nt++)
      acc[nt] = __builtin_amdgcn_mfma_f32_16x16x32_bf16(am[kk], bb[kk][nt], acc[nt], 0,0,0);

  float bnv[4];
  #pragma unroll
  for (int nt=0;nt<4;nt++) bnv[nt] = bn[(nt<<4) + nlo];

  int mrow = (lane >> 4) << 2;
  #pragma unroll
  for (int r=0;r<4;r++){
    int node = base + mrow + r;
    if (node >= N) continue;
    #pragma unroll
    for (int nt=0;nt<4;nt++)
      xout[((size_t)node<<6) + (nt<<4) + nlo] = (u16)f2bf(fmaxf(acc[nt][r] + bnv[nt], 0.f));
  }
}

// ---------------- pooling (batch is sorted), bf16 out ----------------
__global__ __launch_bounds__(256) void k_goff(
    const int* __restrict__ batch, int* __restrict__ goff, int N, int B)
{
  int n = blockIdx.x*256 + threadIdx.x;
  if (n >= N) return;
  int bcur = batch[n];
  int bprev = (n == 0) ? -1 : batch[n-1];
  for (int g = bprev + 1; g <= bcur; ++g) goff[g] = n;
  if (n == N-1) { for (int g = bcur + 1; g <= B; ++g) goff[g] = N; }
}

__global__ __launch_bounds__(256) void k_pool(
    const u16* __restrict__ xin, const int* __restrict__ goff,
    u16* __restrict__ pooledb, int B)
{
  int g = (blockIdx.x << 2) + (threadIdx.x >> 6);
  if (g >= B) return;
  int lane = threadIdx.x & 63;
  int lo = goff[g], hi = goff[g + 1];
  float s = 0.f;
  for (int n = lo; n < hi; n++) s += bf2f((u32)xin[((size_t)n << 6) + lane]);
  pooledb[((size_t)g << 6) + lane] = (u16)f2bf(s);
}

// ---------------- xt -> bf16 into ab1 cols 128..255 ----------------
__global__ __launch_bounds__(256) void k_xtconv(
    const float* __restrict__ xt, u16* __restrict__ ab1, int B)
{
  int t = blockIdx.x*256 + threadIdx.x;
  if (t >= B*128) return;
  int r = t >> 7, c = t & 127;
  ab1[(size_t)r*256 + 128 + c] = (u16)f2bf(xt[t]);
}

// ---------------- final dot: out[r] = h2[r]·Wo + bo (wave per row) ----------------
__global__ __launch_bounds__(256) void k_out(
    const float* __restrict__ h2, const float* __restrict__ Wo,
    const float* __restrict__ bo, float* __restrict__ out, int B)
{
  int w = (blockIdx.x << 2) + (threadIdx.x >> 6);
  if (w >= B) return;
  int lane = threadIdx.x & 63;
  const float* h = h2 + (size_t)w*256;
  float s = 0.f;
  #pragma unroll
  for (int k=0;k<4;k++) s += h[lane + (k<<6)] * Wo[lane + (k<<6)];
  #pragma unroll
  for (int off=32; off; off>>=1) s += __shfl_down(s, off, 64);
  if (lane == 0) out[w] = s + bo[0];
}

extern "C" void kernel_launch(void* const* d_in, const int* in_sizes, int n_in,
                              void* d_out, int out_size, void* d_ws, size_t ws_size,
                              hipStream_t stream)
{
  const float* x    = (const float*)d_in[0];
  const float* ea   = (const float*)d_in[1];
  const float* xt   = (const float*)d_in[2];
  const int*   eidx = (const int*)d_in[3];
  const int*   batch= (const int*)d_in[4];
  const float* We   = (const float*)d_in[6];
  const float* be   = (const float*)d_in[7];
  const float* Wm[3]= {(const float*)d_in[8],  (const float*)d_in[12], (const float*)d_in[16]};
  const float* bm[3]= {(const float*)d_in[9],  (const float*)d_in[13], (const float*)d_in[17]};
  const float* Wn[3]= {(const float*)d_in[10], (const float*)d_in[14], (const float*)d_in[18]};
  const float* bn[3]= {(const float*)d_in[11], (const float*)d_in[15], (const float*)d_in[19]};
  const float* Wxd  = (const float*)d_in[20];
  const float* bxd  = (const float*)d_in[21];
  const float* W1   = (const float*)d_in[22];
  const float* b1   = (const float*)d_in[23];
  const float* W2   = (const float*)d_in[24];
  const float* b2   = (const float*)d_in[25];
  const float* Wo   = (const float*)d_in[26];
  const float* bo   = (const float*)d_in[27];

  const int N = in_sizes[0] / 78;
  const int E = in_sizes[1] / 6;
  const int B = in_sizes[2] / 128;
  const int E2 = E / 2;
  const int* row = eidx;
  const int* col = eidx + E;

  char* p = (char*)d_ws;
  size_t off = 0;
  auto alloc = [&](size_t b)->void* {
    void* r = p + off;
    off = (off + b + 255) & ~(size_t)255;
    return r;
  };
  // persistent buffers (~248 MB total; 259 MB proven safe)
  u16*   ehA   = (u16*)  alloc((size_t)E * 128);
  u16*   ehB   = (u16*)  alloc((size_t)E * 128);
  int*   rowp  = (int*)  alloc((size_t)E * 4);
  int*   colp  = (int*)  alloc((size_t)E * 4);
  int*   revp  = (int*)  alloc((size_t)E * 4);
  int*   offs  = (int*)  alloc((size_t)(N+1) * 4);
  u16*   xbf   = (u16*)  alloc((size_t)N * 192);   // [N x 96] bf16, zero-padded
  u16*   sA    = (u16*)  alloc((size_t)N * 128);   // seg ping
  u16*   sB    = (u16*)  alloc((size_t)N * 128);   // seg pong
  u16*   pxb   = (u16*)  alloc((size_t)N * 128);   // px, then reused as nmsg
  u16*   psb   = (u16*)  alloc((size_t)N * 128);
  u16*   xa    = (u16*)  alloc((size_t)N * 128);   // bf16 node states
  u16*   xb    = (u16*)  alloc((size_t)N * 128);
  int*   goff  = (int*)  alloc((size_t)(B+1) * 4);
  u16*   pooledb=(u16*)  alloc((size_t)B * 128);   // [B x 64] bf16
  u16*   ab1   = (u16*)  alloc((size_t)B * 512);   // [B x 256] bf16 (xg | xt)
  u16*   h1b   = (u16*)  alloc((size_t)B * 2048);  // [B x 1024] bf16
  float* h2f   = (float*)alloc((size_t)B * 1024);  // [B x 256] f32
  u16*   wpack = (u16*)  alloc((size_t)3 * WP_LAYER * 2);
  u16*   wxdP  = (u16*)  alloc((size_t)(64/32)*(128/16)*512 * 2);
  u16*   w1P   = (u16*)  alloc((size_t)(256/32)*(1024/16)*512 * 2);
  u16*   w2P   = (u16*)  alloc((size_t)(1024/32)*(256/16)*512 * 2);

  // setup transients aliased into ehB (all dead before ehB's first write in k_scatmfma L0)
  char* ehBc = (char*)ehB;
  int* perm  = (int*)ehBc;           // 3.2 MB
  int* iperm = perm + E;             // 3.2 MB
  int* cnt   = iperm + E;            // 0.16 MB
  int* nxt   = cnt + N;              // 0.16 MB
  int* bsum  = nxt + N;              // 4 KB
  int* bofs  = bsum + 1024;          // 4 KB

  dim3 blk(256);
  int gE   = (E + 255) / 256;
  int gE4  = ((size_t)E*4 + 255) / 256;
  int gEm  = (E + 63) / 64;      // mfma edge: 16 slots/wave, 4 waves/block
  int gN   = (N + 255) / 256;
  int gNm  = (N + 63) / 64;      // mfma node: 16 rows/wave, 4 waves/block
  int gNw  = (N + 3) / 4;
  int gBw  = (B + 3) / 4;
  int gXc  = (N*96 + 255) / 256;
  int nb   = (N + 255) / 256;    // scan blocks (<=256 required; N=40000 -> 157)

  hipMemsetAsync(cnt, 0, (size_t)N * 4, stream);
  k_deg  <<<gE, blk, 0, stream>>>(row, cnt, E);
  k_bsum <<<nb, blk, 0, stream>>>(cnt, bsum, N);
  k_bscan<<<1,  blk, 0, stream>>>(bsum, bofs, nb, offs, N);
  k_apply<<<nb, blk, 0, stream>>>(cnt, bofs, offs, nxt, N);
  k_fill <<<gE, blk, 0, stream>>>(row, nxt, perm, iperm, E);
  k_permarr<<<gE, blk, 0, stream>>>(perm, iperm, row, col, rowp, colp, revp, E, E2);
  k_edge_init<<<gE4, blk, 0, stream>>>(ea, perm, We, be, ehA, E);
  k_xconv<<<gXc, blk, 0, stream>>>(x, xbf, N);
  k_goff<<<gN, blk, 0, stream>>>(batch, goff, N, B);
  for (int L = 0; L < 3; ++L) {
    int XD = (L == 0) ? 78 : 64;
    int KT = (L == 0) ? 3 : 2;
    k_prepw<<<10, blk, 0, stream>>>(Wm[L], Wn[L], XD, KT, wpack + (size_t)L*WP_LAYER);
  }
  k_packw<<<(1024 + 255)/256, blk, 0, stream>>>(Wxd, 64, 128, wxdP);
  k_packw<<<(32768 + 255)/256, blk, 0, stream>>>(W1, 256, 1024, w1P);
  k_packw<<<(32768 + 255)/256, blk, 0, stream>>>(W2, 1024, 256, w2P);

  // L0 seg from ehA; later segs come fused out of k_gnmsg
  k_seg<<<gNw, blk, 0, stream>>>(ehA, offs, sA, N);

  const u16* ehin = ehA;
  u16* ehout = ehB;
  const u16* xin = xbf;
  u16* segcur = sA;
  u16* segnxt = sB;
  for (int L = 0; L < 3; ++L) {
    u16* xout = (L % 2 == 0) ? xa : xb;
    const u16* wp = wpack + (size_t)L*WP_LAYER;
    if (L == 0) k_proj<3><<<gNm, blk, 0, stream>>>(xin, segcur, wp, bm[L], pxb, psb, N);
    else        k_proj<2><<<gNm, blk, 0, stream>>>(xin, segcur, wp, bm[L], pxb, psb, N);
    k_scatmfma<<<gEm, blk, 0, stream>>>(ehin, wp, pxb, psb, rowp, colp, revp, ehout, E);
    // nmsg -> pxb (px is dead after k_scatmfma); seg for next layer -> segnxt
    k_gnmsg<<<gNw, blk, 0, stream>>>(ehout, revp, offs, pxb, (L < 2) ? segnxt : (u16*)nullptr, N);
    if (L == 0) k_nodef<3><<<gNm, blk, 0, stream>>>(xin, pxb, wp, bn[L], xout, N);
    else        k_nodef<2><<<gNm, blk, 0, stream>>>(xin, pxb, wp, bn[L], xout, N);
    u16* tmp = (u16*)ehin; ehin = ehout; ehout = tmp;
    u16* ts = segcur; segcur = segnxt; segnxt = ts;
    xin = xout;
  }

  k_pool<<<gBw, blk, 0, stream>>>(xa, goff, pooledb, B);
  k_xtconv<<<(B*128 + 255)/256, blk, 0, stream>>>(xt, ab1, B);
  {
    int waves = ((B + 15)/16) * (128/64);
    k_gemm<<<(waves + 3)/4, blk, 0, stream>>>(pooledb, 64, wxdP, bxd, ab1, 256, B, 128>>4, 64>>5, 1, 1);
  }
  {
    int waves = ((B + 15)/16) * (1024/64);
    k_gemm<<<(waves + 3)/4, blk, 0, stream>>>(ab1, 256, w1P, b1, h1b, 1024, B, 1024>>4, 256>>5, 1, 1);
  }
  {
    int waves = ((B + 15)/16) * (256/64);
    k_gemm<<<(waves + 3)/4, blk, 0, stream>>>(h1b, 1024, w2P, b2, h2f, 256, B, 256>>4, 1024>>5, 1, 0);
  }
  k_out<<<gBw, blk, 0, stream>>>(h2f, Wo, bo, (float*)d_out, B);
}

// Round 9
// 728.900 us; speedup vs baseline: 7.6389x; 1.1186x over previous
//
#include <hip/hip_runtime.h>
#include <hip/hip_fp16.h>

using u16 = unsigned short;
using u32 = unsigned int;
using u64 = unsigned long long;

typedef short short8 __attribute__((ext_vector_type(8)));
typedef float f32x4 __attribute__((ext_vector_type(4)));

// wpack section offsets (u16 units) within one layer's 20480-u16 slab
#define WP_TOP   0
#define WP_BOT   6144
#define WP_NTOP  10240
#define WP_NBOT  16384
#define WP_LAYER 20480

// fp16 storage helpers (RNE hardware converts)
__device__ __forceinline__ float h2f(u16 u){ union{u16 s; _Float16 h;} v; v.s=u; return (float)v.h; }
__device__ __forceinline__ u16 f2h(float f){ union{u16 s; _Float16 h;} v; v.h=(_Float16)f; return v.s; }
__device__ __forceinline__ u32 pack2(float a, float b){ return (u32)f2h(a) | ((u32)f2h(b)<<16); }

__device__ __forceinline__ void store16h(u16* d, const float* a){
  uint4 u0, u1;
  u0.x = pack2(a[0],a[1]);   u0.y = pack2(a[2],a[3]);
  u0.z = pack2(a[4],a[5]);   u0.w = pack2(a[6],a[7]);
  u1.x = pack2(a[8],a[9]);   u1.y = pack2(a[10],a[11]);
  u1.z = pack2(a[12],a[13]); u1.w = pack2(a[14],a[15]);
  *(uint4*)(d)   = u0;
  *(uint4*)(d+8) = u1;
}

// ---------------- CSR build ----------------
__global__ __launch_bounds__(256) void k_deg(
    const int* __restrict__ row, int* __restrict__ cnt, int E)
{
  int e = blockIdx.x*256 + threadIdx.x;
  if (e >= E) return;
  atomicAdd(&cnt[row[e]], 1);
}

__global__ __launch_bounds__(256) void k_bsum(
    const int* __restrict__ cnt, int* __restrict__ bsum, int N)
{
  __shared__ int sh[256];
  int t = threadIdx.x;
  int i = blockIdx.x*256 + t;
  sh[t] = (i < N) ? cnt[i] : 0;
  __syncthreads();
  #pragma unroll
  for (int s=128; s; s>>=1){ if (t<s) sh[t]+=sh[t+s]; __syncthreads(); }
  if (t==0) bsum[blockIdx.x] = sh[0];
}

__global__ __launch_bounds__(256) void k_bscan(
    const int* __restrict__ bsum, int* __restrict__ bofs, int nb,
    int* __restrict__ off, int N)
{
  __shared__ int sh[256];
  int t = threadIdx.x;
  int v = (t < nb) ? bsum[t] : 0;
  sh[t] = v;
  __syncthreads();
  #pragma unroll
  for (int s=1; s<256; s<<=1){
    int u = (t>=s) ? sh[t-s] : 0;
    __syncthreads();
    sh[t] += u;
    __syncthreads();
  }
  if (t < nb) bofs[t] = sh[t] - v;
  if (t == 0) off[N] = sh[nb-1];
}

__global__ __launch_bounds__(256) void k_apply(
    const int* __restrict__ cnt, const int* __restrict__ bofs,
    int* __restrict__ off, int* __restrict__ nxt, int N)
{
  __shared__ int sh[256];
  int t = threadIdx.x;
  int i = blockIdx.x*256 + t;
  int v = (i < N) ? cnt[i] : 0;
  sh[t] = v;
  __syncthreads();
  #pragma unroll
  for (int s=1; s<256; s<<=1){
    int u = (t>=s) ? sh[t-s] : 0;
    __syncthreads();
    sh[t] += u;
    __syncthreads();
  }
  if (i < N){
    int ex = sh[t] - v + bofs[blockIdx.x];
    off[i] = ex;
    nxt[i] = ex;
  }
}

__global__ __launch_bounds__(256) void k_fill(
    const int* __restrict__ row, int* __restrict__ nxt,
    int* __restrict__ perm, int* __restrict__ iperm, int E)
{
  int e = blockIdx.x*256 + threadIdx.x;
  if (e >= E) return;
  int pos = atomicAdd(&nxt[row[e]], 1);
  perm[pos] = e;
  iperm[e] = pos;
}

// permuted per-slot arrays; structural reverse: rev(e) = e<E2 ? e+E2 : e-E2
__global__ __launch_bounds__(256) void k_permarr(
    const int* __restrict__ perm, const int* __restrict__ iperm,
    const int* __restrict__ row, const int* __restrict__ col,
    int* __restrict__ rowp, int* __restrict__ colp, int* __restrict__ revp,
    int E, int E2)
{
  int i = blockIdx.x*256 + threadIdx.x;
  if (i >= E) return;
  int e = perm[i];
  rowp[i] = row[e];
  colp[i] = col[e];
  int re = (e < E2) ? e + E2 : e - E2;
  revp[i] = iperm[re];
}

// ---------------- x -> fp16 padded [N x 96] ----------------
__global__ __launch_bounds__(256) void k_xconv(
    const float* __restrict__ x, u16* __restrict__ xh, int N)
{
  int t = blockIdx.x*256 + threadIdx.x;
  if (t >= N*96) return;
  int n = t / 96, k = t - n*96;
  xh[t] = (k < 78) ? f2h(x[(size_t)n*78 + k]) : (u16)0;
}

// ---------------- edge init (scatter form): eh[iperm[e]] = ea[e] @ We + be ----------------
__global__ __launch_bounds__(256) void k_edge_init(
    const float* __restrict__ ea, const int* __restrict__ iperm,
    const float* __restrict__ We, const float* __restrict__ be,
    u16* __restrict__ eh, int E)
{
  int tid = blockIdx.x*256 + threadIdx.x;
  int e = tid >> 2;
  if (e >= E) return;
  int t = tid & 3;
  int slot = iperm[e];
  const float* a = ea + (size_t)e*6;   // coalesced/broadcast: edge-order read
  float acc[16];
  #pragma unroll
  for (int j=0;j<16;j++) acc[j] = be[t*16+j];
  #pragma unroll
  for (int k=0;k<6;k++){
    float av = a[k];
    const float* w = We + k*64 + t*16;
    #pragma unroll
    for (int j=0;j<16;j++) acc[j] += av*w[j];
  }
  store16h(eh + ((size_t)slot<<6) + t*16, acc);
}

// ---------------- seg0[n] = (sum of ea rows of n's out-edges)@We + deg*be  (fp16 out) ----------------
__global__ __launch_bounds__(256) void k_seg0(
    const float* __restrict__ ea, const int* __restrict__ perm,
    const int* __restrict__ off, const float* __restrict__ We,
    const float* __restrict__ be, u16* __restrict__ segb, int N)
{
  int w = (blockIdx.x << 2) + (threadIdx.x >> 6);
  if (w >= N) return;
  int lane = threadIdx.x & 63;
  int lo = off[w], hi = off[w+1];
  float wcol[6];
  #pragma unroll
  for (int k=0;k<6;k++) wcol[k] = We[k*64 + lane];
  float es[6] = {0.f,0.f,0.f,0.f,0.f,0.f};
  for (int j = lo; j < hi; j++){
    int e = perm[j];
    const float* a = ea + (size_t)e*6;
    #pragma unroll
    for (int k=0;k<6;k++) es[k] += a[k];
  }
  float acc = (float)(hi - lo) * be[lane];
  #pragma unroll
  for (int k=0;k<6;k++) acc += es[k]*wcol[k];
  segb[((size_t)w<<6) + lane] = f2h(acc);
}

// ---------------- pack one conv layer's weights into MFMA B-fragments (fp16) ----------------
__global__ __launch_bounds__(256) void k_prepw(
    const float* __restrict__ Wm, const float* __restrict__ Wn,
    int XD, int KT, u16* __restrict__ dst)
{
  int t = blockIdx.x*256 + threadIdx.x;
  int topFL = KT*256;
  const float* W; int rbase, rvalid, dofs, fl;
  if (t < topFL)                   { W = Wm; rbase = 0;  rvalid = XD; dofs = WP_TOP;  fl = t; }
  else if (t < topFL+512)          { W = Wm; rbase = XD; rvalid = 64; dofs = WP_BOT;  fl = t - topFL; }
  else if (t < 2*topFL+512)        { W = Wn; rbase = 0;  rvalid = XD; dofs = WP_NTOP; fl = t - topFL - 512; }
  else if (t < 2*topFL+1024)       { W = Wn; rbase = XD; rvalid = 64; dofs = WP_NBOT; fl = t - 2*topFL - 512; }
  else return;
  int f = fl >> 6, lane = fl & 63;
  int nt = f & 3, kk = f >> 2;
  int n = (nt<<4) + (lane & 15);
  int krel = (kk<<5) + ((lane>>4)<<3);
  u16* d = dst + dofs + (size_t)f*512 + lane*8;
  #pragma unroll
  for (int j=0;j<8;j++){
    int kr = krel + j;
    d[j] = (kr < rvalid) ? f2h(W[(size_t)(rbase+kr)*64 + n]) : (u16)0;
  }
}

// ---------------- generic pack: W [K x Nout] f32 -> fp16 B-frags ----------------
__global__ __launch_bounds__(256) void k_packw(
    const float* __restrict__ W, int K, int Nout, u16* __restrict__ dst)
{
  int t = blockIdx.x*256 + threadIdx.x;
  int NT = Nout >> 4;
  int total = (K >> 5) * NT * 64;
  if (t >= total) return;
  int f = t >> 6, lane = t & 63;
  int nt = f % NT, kk = f / NT;
  int n = (nt<<4) + (lane & 15);
  int kb = (kk<<5) + ((lane>>4)<<3);
  u16* d = dst + ((size_t)f*64 + lane)*8;
  #pragma unroll
  for (int j=0;j<8;j++) d[j] = f2h(W[(size_t)(kb+j)*Nout + n]);
}

// ---------------- generic MFMA GEMM (fp16 in, f32 acc) ----------------
__global__ __launch_bounds__(256) void k_gemm(
    const u16* __restrict__ A, int lda, const u16* __restrict__ BP,
    const float* __restrict__ bias, void* __restrict__ outv, int ldo,
    int M, int NT, int KT, int dorelu, int oh16)
{
  int lane = threadIdx.x & 63;
  int wid = (blockIdx.x << 2) + (threadIdx.x >> 6);
  int nb = NT >> 2;
  int mblk = wid / nb, nblk = wid - mblk*nb;
  int m0 = mblk << 4;
  if (m0 >= M) return;
  int n0 = nblk << 6;
  int nlo = lane & 15;
  int khi = (lane >> 4) << 3;
  int r0 = m0 + nlo; if (r0 > M-1) r0 = M-1;

  f32x4 acc[4];
  #pragma unroll
  for (int nt=0;nt<4;nt++){ f32x4 z = {0.f,0.f,0.f,0.f}; acc[nt]=z; }
  for (int kk=0; kk<KT; kk++){
    short8 a = *(const short8*)(A + (size_t)r0*lda + (kk<<5) + khi);
    #pragma unroll
    for (int nt=0;nt<4;nt++){
      short8 b = *(const short8*)(BP + ((size_t)(kk*NT + (nblk<<2) + nt)*64 + lane)*8);
      acc[nt] = __builtin_amdgcn_mfma_f32_16x16x32_f16(a, b, acc[nt], 0,0,0);
    }
  }
  int mrow = (lane >> 4) << 2;
  #pragma unroll
  for (int r=0;r<4;r++){
    int m = m0 + mrow + r;
    if (m >= M) continue;
    #pragma unroll
    for (int nt=0;nt<4;nt++){
      float v = acc[nt][r] + bias[n0 + (nt<<4) + nlo];
      if (dorelu) v = fmaxf(v, 0.f);
      if (oh16) ((u16*)outv)[(size_t)m*ldo + n0 + (nt<<4) + nlo] = f2h(v);
      else      ((float*)outv)[(size_t)m*ldo + n0 + (nt<<4) + nlo] = v;
    }
  }
}

// ---------------- MFMA node projections: px = x@Wtop + bm ; ps = seg@Wbot ----------------
template<int KT>
__global__ __launch_bounds__(256) void k_proj(
    const u16* __restrict__ xin, const u16* __restrict__ segb,
    const u16* __restrict__ wp, const float* __restrict__ bm,
    u16* __restrict__ pxb, u16* __restrict__ psb, int N)
{
  int lane = threadIdx.x & 63;
  int wid = (blockIdx.x << 2) + (threadIdx.x >> 6);
  int base = wid << 4;
  if (base >= N) return;
  int nlo = lane & 15;
  int khi = (lane >> 4) << 3;

  short8 bt[KT][4];
  #pragma unroll
  for (int kk=0;kk<KT;kk++)
    #pragma unroll
    for (int nt=0;nt<4;nt++)
      bt[kk][nt] = *(const short8*)(wp + WP_TOP + ((size_t)((kk<<2)|nt)*64 + lane)*8);
  short8 bb[2][4];
  #pragma unroll
  for (int kk=0;kk<2;kk++)
    #pragma unroll
    for (int nt=0;nt<4;nt++)
      bb[kk][nt] = *(const short8*)(wp + WP_BOT + ((size_t)((kk<<2)|nt)*64 + lane)*8);

  int r0 = base + nlo; if (r0 > N-1) r0 = N-1;
  const u16* xrow = xin + (size_t)r0*(KT*32);
  short8 ax[KT];
  #pragma unroll
  for (int kk=0;kk<KT;kk++) ax[kk] = *(const short8*)(xrow + (kk<<5) + khi);
  const u16* srow = segb + ((size_t)r0<<6);
  short8 as[2];
  #pragma unroll
  for (int kk=0;kk<2;kk++) as[kk] = *(const short8*)(srow + (kk<<5) + khi);

  f32x4 accP[4], accS[4];
  #pragma unroll
  for (int nt=0;nt<4;nt++){ f32x4 z = {0.f,0.f,0.f,0.f}; accP[nt]=z; accS[nt]=z; }
  #pragma unroll
  for (int kk=0;kk<KT;kk++)
    #pragma unroll
    for (int nt=0;nt<4;nt++)
      accP[nt] = __builtin_amdgcn_mfma_f32_16x16x32_f16(ax[kk], bt[kk][nt], accP[nt], 0,0,0);
  #pragma unroll
  for (int kk=0;kk<2;kk++)
    #pragma unroll
    for (int nt=0;nt<4;nt++)
      accS[nt] = __builtin_amdgcn_mfma_f32_16x16x32_f16(as[kk], bb[kk][nt], accS[nt], 0,0,0);

  float bmv[4];
  #pragma unroll
  for (int nt=0;nt<4;nt++) bmv[nt] = bm[(nt<<4) + nlo];

  int mrow = (lane >> 4) << 2;
  #pragma unroll
  for (int r=0;r<4;r++){
    int node = base + mrow + r;
    if (node >= N) continue;
    #pragma unroll
    for (int nt=0;nt<4;nt++){
      pxb[((size_t)node<<6) + (nt<<4) + nlo] = f2h(accP[nt][r] + bmv[nt]);
      psb[((size_t)node<<6) + (nt<<4) + nlo] = f2h(accS[nt][r]);
    }
  }
}

// ---------------- fused MFMA edge kernel:
// msg[revp[i]] = relu( px[colp[i]] + ps[rowp[i]] - eh[i]@Wbot ) ----------------
__global__ __launch_bounds__(256) void k_scatmfma(
    const u16* __restrict__ eh, const u16* __restrict__ wp,
    const u16* __restrict__ pxb, const u16* __restrict__ psb,
    const int* __restrict__ rowp, const int* __restrict__ colp,
    const int* __restrict__ revp, u16* __restrict__ msg, int E)
{
  int lane = threadIdx.x & 63;
  int wid = (blockIdx.x << 2) + (threadIdx.x >> 6);
  int base = wid << 4;
  if (base >= E) return;
  int nlo = lane & 15;
  int khi = (lane >> 4) << 3;

  short8 bb[2][4];
  #pragma unroll
  for (int kk=0;kk<2;kk++)
    #pragma unroll
    for (int nt=0;nt<4;nt++)
      bb[kk][nt] = *(const short8*)(wp + WP_BOT + ((size_t)((kk<<2)|nt)*64 + lane)*8);

  int sa = base + nlo; if (sa > E-1) sa = E-1;
  const u16* ehp = eh + ((size_t)sa<<6) + khi;
  short8 a0 = *(const short8*)(ehp);
  short8 a1 = *(const short8*)(ehp + 32);

  f32x4 acc[4];
  #pragma unroll
  for (int nt=0;nt<4;nt++){
    f32x4 z = {0.f,0.f,0.f,0.f};
    acc[nt] = z;
    acc[nt] = __builtin_amdgcn_mfma_f32_16x16x32_f16(a0, bb[0][nt], acc[nt], 0,0,0);
    acc[nt] = __builtin_amdgcn_mfma_f32_16x16x32_f16(a1, bb[1][nt], acc[nt], 0,0,0);
  }

  int mrow = (lane >> 4) << 2;
  #pragma unroll
  for (int r=0;r<4;r++){
    int slot = base + mrow + r;
    if (slot >= E) continue;
    int rp = rowp[slot];
    int cp = colp[slot];
    int rv = revp[slot];
    const u16* pr = psb + ((size_t)rp<<6) + nlo;
    const u16* pc = pxb + ((size_t)cp<<6) + nlo;
    u16* ob = msg + ((size_t)rv<<6) + nlo;
    #pragma unroll
    for (int nt=0;nt<4;nt++){
      float v = h2f(pc[nt<<4]) + h2f(pr[nt<<4]) - acc[nt][r];
      ob[nt<<4] = f2h(fmaxf(v, 0.f));
    }
  }
}

// ---------------- fused: nmsg[n] = Σ msg[revp[j]]; segnext[n] = Σ msg[j]
// 4 rows in flight per wave: groups of 16 lanes, uint2 (4 ch) per lane ----------------
__global__ __launch_bounds__(256) void k_gnmsg(
    const u16* __restrict__ msg, const int* __restrict__ revp,
    const int* __restrict__ off, u16* __restrict__ nmsgb,
    u16* __restrict__ segnext, int N)
{
  int w = (blockIdx.x << 2) + (threadIdx.x >> 6);
  if (w >= N) return;
  int lane = threadIdx.x & 63;
  int g = lane >> 4, l = lane & 15;
  int lo = off[w], hi = off[w+1];
  float s0=0.f,s1=0.f,s2=0.f,s3=0.f;
  float t0=0.f,t1=0.f,t2=0.f,t3=0.f;
  if (segnext){
    for (int j = lo + g; j < hi; j += 4){
      int i = revp[j];
      uint2 v = *(const uint2*)(msg + ((size_t)i<<6) + (l<<2));
      uint2 u = *(const uint2*)(msg + ((size_t)j<<6) + (l<<2));
      s0 += h2f((u16)v.x); s1 += h2f((u16)(v.x>>16)); s2 += h2f((u16)v.y); s3 += h2f((u16)(v.y>>16));
      t0 += h2f((u16)u.x); t1 += h2f((u16)(u.x>>16)); t2 += h2f((u16)u.y); t3 += h2f((u16)(u.y>>16));
    }
  } else {
    for (int j = lo + g; j < hi; j += 4){
      int i = revp[j];
      uint2 v = *(const uint2*)(msg + ((size_t)i<<6) + (l<<2));
      s0 += h2f((u16)v.x); s1 += h2f((u16)(v.x>>16)); s2 += h2f((u16)v.y); s3 += h2f((u16)(v.y>>16));
    }
  }
  s0 += __shfl_xor(s0,16,64); s0 += __shfl_xor(s0,32,64);
  s1 += __shfl_xor(s1,16,64); s1 += __shfl_xor(s1,32,64);
  s2 += __shfl_xor(s2,16,64); s2 += __shfl_xor(s2,32,64);
  s3 += __shfl_xor(s3,16,64); s3 += __shfl_xor(s3,32,64);
  if (segnext){
    t0 += __shfl_xor(t0,16,64); t0 += __shfl_xor(t0,32,64);
    t1 += __shfl_xor(t1,16,64); t1 += __shfl_xor(t1,32,64);
    t2 += __shfl_xor(t2,16,64); t2 += __shfl_xor(t2,32,64);
    t3 += __shfl_xor(t3,16,64); t3 += __shfl_xor(t3,32,64);
  }
  if (g == 0){
    uint2 o; o.x = pack2(s0,s1); o.y = pack2(s2,s3);
    *(uint2*)(nmsgb + ((size_t)w<<6) + (l<<2)) = o;
    if (segnext){
      uint2 q; q.x = pack2(t0,t1); q.y = pack2(t2,t3);
      *(uint2*)(segnext + ((size_t)w<<6) + (l<<2)) = q;
    }
  }
}

// ---------------- MFMA node update: xout = relu(x@WnTop + nmsg@WnBot + bn), fp16 out ----------------
template<int KT>
__global__ __launch_bounds__(256) void k_nodef(
    const u16* __restrict__ xin, const u16* __restrict__ nmsgb,
    const u16* __restrict__ wp, const float* __restrict__ bn,
    u16* __restrict__ xout, int N)
{
  int lane = threadIdx.x & 63;
  int wid = (blockIdx.x << 2) + (threadIdx.x >> 6);
  int base = wid << 4;
  if (base >= N) return;
  int nlo = lane & 15;
  int khi = (lane >> 4) << 3;

  short8 bt[KT][4];
  #pragma unroll
  for (int kk=0;kk<KT;kk++)
    #pragma unroll
    for (int nt=0;nt<4;nt++)
      bt[kk][nt] = *(const short8*)(wp + WP_NTOP + ((size_t)((kk<<2)|nt)*64 + lane)*8);
  short8 bb[2][4];
  #pragma unroll
  for (int kk=0;kk<2;kk++)
    #pragma unroll
    for (int nt=0;nt<4;nt++)
      bb[kk][nt] = *(const short8*)(wp + WP_NBOT + ((size_t)((kk<<2)|nt)*64 + lane)*8);

  int r0 = base + nlo; if (r0 > N-1) r0 = N-1;
  const u16* xrow = xin + (size_t)r0*(KT*32);
  short8 ax[KT];
  #pragma unroll
  for (int kk=0;kk<KT;kk++) ax[kk] = *(const short8*)(xrow + (kk<<5) + khi);
  const u16* mrp = nmsgb + ((size_t)r0<<6);
  short8 am[2];
  #pragma unroll
  for (int kk=0;kk<2;kk++) am[kk] = *(const short8*)(mrp + (kk<<5) + khi);

  f32x4 acc[4];
  #pragma unroll
  for (int nt=0;nt<4;nt++){ f32x4 z = {0.f,0.f,0.f,0.f}; acc[nt]=z; }
  #pragma unroll
  for (int kk=0;kk<KT;kk++)
    #pragma unroll
    for (int nt=0;nt<4;nt++)
      acc[nt] = __builtin_amdgcn_mfma_f32_16x16x32_f16(ax[kk], bt[kk][nt], acc[nt], 0,0,0);
  #pragma unroll
  for (int kk=0;kk<2;kk++)
    #pragma unroll
    for (int nt=0;nt<4;nt++)
      acc[nt] = __builtin_amdgcn_mfma_f32_16x16x32_f16(am[kk], bb[kk][nt], acc[nt], 0,0,0);

  float bnv[4];
  #pragma unroll
  for (int nt=0;nt<4;nt++) bnv[nt] = bn[(nt<<4) + nlo];

  int mrow = (lane >> 4) << 2;
  #pragma unroll
  for (int r=0;r<4;r++){
    int node = base + mrow + r;
    if (node >= N) continue;
    #pragma unroll
    for (int nt=0;nt<4;nt++)
      xout[((size_t)node<<6) + (nt<<4) + nlo] = f2h(fmaxf(acc[nt][r] + bnv[nt], 0.f));
  }
}

// ---------------- pooling (batch is sorted), fp16 out ----------------
__global__ __launch_bounds__(256) void k_goff(
    const int* __restrict__ batch, int* __restrict__ goff, int N, int B)
{
  int n = blockIdx.x*256 + threadIdx.x;
  if (n >= N) return;
  int bcur = batch[n];
  int bprev = (n == 0) ? -1 : batch[n-1];
  for (int g = bprev + 1; g <= bcur; ++g) goff[g] = n;
  if (n == N-1) { for (int g = bcur + 1; g <= B; ++g) goff[g] = N; }
}

__global__ __launch_bounds__(256) void k_pool(
    const u16* __restrict__ xin, const int* __restrict__ goff,
    u16* __restrict__ pooledh, int B)
{
  int g = (blockIdx.x << 2) + (threadIdx.x >> 6);
  if (g >= B) return;
  int lane = threadIdx.x & 63;
  int lo = goff[g], hi = goff[g + 1];
  float s = 0.f;
  for (int n = lo; n < hi; n++) s += h2f(xin[((size_t)n << 6) + lane]);
  pooledh[((size_t)g << 6) + lane] = f2h(s);
}

// ---------------- xt -> fp16 into ab1 cols 128..255 ----------------
__global__ __launch_bounds__(256) void k_xtconv(
    const float* __restrict__ xt, u16* __restrict__ ab1, int B)
{
  int t = blockIdx.x*256 + threadIdx.x;
  if (t >= B*128) return;
  int r = t >> 7, c = t & 127;
  ab1[(size_t)r*256 + 128 + c] = f2h(xt[t]);
}

// ---------------- final dot: out[r] = h2[r]·Wo + bo (wave per row) ----------------
__global__ __launch_bounds__(256) void k_out(
    const float* __restrict__ h2, const float* __restrict__ Wo,
    const float* __restrict__ bo, float* __restrict__ out, int B)
{
  int w = (blockIdx.x << 2) + (threadIdx.x >> 6);
  if (w >= B) return;
  int lane = threadIdx.x & 63;
  const float* h = h2 + (size_t)w*256;
  float s = 0.f;
  #pragma unroll
  for (int k=0;k<4;k++) s += h[lane + (k<<6)] * Wo[lane + (k<<6)];
  #pragma unroll
  for (int off=32; off; off>>=1) s += __shfl_down(s, off, 64);
  if (lane == 0) out[w] = s + bo[0];
}

extern "C" void kernel_launch(void* const* d_in, const int* in_sizes, int n_in,
                              void* d_out, int out_size, void* d_ws, size_t ws_size,
                              hipStream_t stream)
{
  const float* x    = (const float*)d_in[0];
  const float* ea   = (const float*)d_in[1];
  const float* xt   = (const float*)d_in[2];
  const int*   eidx = (const int*)d_in[3];
  const int*   batch= (const int*)d_in[4];
  const float* We   = (const float*)d_in[6];
  const float* be   = (const float*)d_in[7];
  const float* Wm[3]= {(const float*)d_in[8],  (const float*)d_in[12], (const float*)d_in[16]};
  const float* bm[3]= {(const float*)d_in[9],  (const float*)d_in[13], (const float*)d_in[17]};
  const float* Wn[3]= {(const float*)d_in[10], (const float*)d_in[14], (const float*)d_in[18]};
  const float* bn[3]= {(const float*)d_in[11], (const float*)d_in[15], (const float*)d_in[19]};
  const float* Wxd  = (const float*)d_in[20];
  const float* bxd  = (const float*)d_in[21];
  const float* W1   = (const float*)d_in[22];
  const float* b1   = (const float*)d_in[23];
  const float* W2   = (const float*)d_in[24];
  const float* b2   = (const float*)d_in[25];
  const float* Wo   = (const float*)d_in[26];
  const float* bo   = (const float*)d_in[27];

  const int N = in_sizes[0] / 78;
  const int E = in_sizes[1] / 6;
  const int B = in_sizes[2] / 128;
  const int E2 = E / 2;
  const int* row = eidx;
  const int* col = eidx + E;

  char* p = (char*)d_ws;
  size_t off = 0;
  auto alloc = [&](size_t b)->void* {
    void* r = p + off;
    off = (off + b + 255) & ~(size_t)255;
    return r;
  };
  // persistent buffers (~248 MB total; 259 MB proven safe)
  u16*   ehA   = (u16*)  alloc((size_t)E * 128);
  u16*   ehB   = (u16*)  alloc((size_t)E * 128);
  int*   rowp  = (int*)  alloc((size_t)E * 4);
  int*   colp  = (int*)  alloc((size_t)E * 4);
  int*   revp  = (int*)  alloc((size_t)E * 4);
  int*   offs  = (int*)  alloc((size_t)(N+1) * 4);
  u16*   xh    = (u16*)  alloc((size_t)N * 192);   // [N x 96] fp16, zero-padded
  u16*   sA    = (u16*)  alloc((size_t)N * 128);   // seg ping
  u16*   sB    = (u16*)  alloc((size_t)N * 128);   // seg pong
  u16*   pxb   = (u16*)  alloc((size_t)N * 128);   // px, then reused as nmsg
  u16*   psb   = (u16*)  alloc((size_t)N * 128);
  u16*   xa    = (u16*)  alloc((size_t)N * 128);   // fp16 node states
  u16*   xb    = (u16*)  alloc((size_t)N * 128);
  int*   goff  = (int*)  alloc((size_t)(B+1) * 4);
  u16*   pooledh=(u16*)  alloc((size_t)B * 128);
  u16*   ab1   = (u16*)  alloc((size_t)B * 512);
  u16*   h1h   = (u16*)  alloc((size_t)B * 2048);
  float* h2f   = (float*)alloc((size_t)B * 1024);
  u16*   wpack = (u16*)  alloc((size_t)3 * WP_LAYER * 2);
  u16*   wxdP  = (u16*)  alloc((size_t)(64/32)*(128/16)*512 * 2);
  u16*   w1P   = (u16*)  alloc((size_t)(256/32)*(1024/16)*512 * 2);
  u16*   w2P   = (u16*)  alloc((size_t)(1024/32)*(256/16)*512 * 2);

  // setup transients aliased into ehB (all dead before ehB's first write in k_scatmfma L0)
  char* ehBc = (char*)ehB;
  int* perm  = (int*)ehBc;           // 3.2 MB
  int* iperm = perm + E;             // 3.2 MB
  int* cnt   = iperm + E;            // 0.16 MB
  int* nxt   = cnt + N;              // 0.16 MB
  int* bsum  = nxt + N;              // 4 KB
  int* bofs  = bsum + 1024;          // 4 KB

  dim3 blk(256);
  int gE   = (E + 255) / 256;
  int gE4  = ((size_t)E*4 + 255) / 256;
  int gEm  = (E + 63) / 64;
  int gN   = (N + 255) / 256;
  int gNm  = (N + 63) / 64;
  int gNw  = (N + 3) / 4;
  int gBw  = (B + 3) / 4;
  int gXc  = (N*96 + 255) / 256;
  int nb   = (N + 255) / 256;    // scan blocks (N=40000 -> 157, <=256 ok)

  hipMemsetAsync(cnt, 0, (size_t)N * 4, stream);
  k_deg  <<<gE, blk, 0, stream>>>(row, cnt, E);
  k_bsum <<<nb, blk, 0, stream>>>(cnt, bsum, N);
  k_bscan<<<1,  blk, 0, stream>>>(bsum, bofs, nb, offs, N);
  k_apply<<<nb, blk, 0, stream>>>(cnt, bofs, offs, nxt, N);
  k_fill <<<gE, blk, 0, stream>>>(row, nxt, perm, iperm, E);
  k_permarr<<<gE, blk, 0, stream>>>(perm, iperm, row, col, rowp, colp, revp, E, E2);
  k_edge_init<<<gE4, blk, 0, stream>>>(ea, iperm, We, be, ehA, E);
  k_seg0<<<gNw, blk, 0, stream>>>(ea, perm, offs, We, be, sA, N);
  k_xconv<<<gXc, blk, 0, stream>>>(x, xh, N);
  k_goff<<<gN, blk, 0, stream>>>(batch, goff, N, B);
  for (int L = 0; L < 3; ++L) {
    int XD = (L == 0) ? 78 : 64;
    int KT = (L == 0) ? 3 : 2;
    k_prepw<<<10, blk, 0, stream>>>(Wm[L], Wn[L], XD, KT, wpack + (size_t)L*WP_LAYER);
  }
  k_packw<<<(1024 + 255)/256, blk, 0, stream>>>(Wxd, 64, 128, wxdP);
  k_packw<<<(32768 + 255)/256, blk, 0, stream>>>(W1, 256, 1024, w1P);
  k_packw<<<(32768 + 255)/256, blk, 0, stream>>>(W2, 1024, 256, w2P);

  const u16* ehin = ehA;
  u16* ehout = ehB;
  const u16* xin = xh;
  u16* segcur = sA;
  u16* segnxt = sB;
  for (int L = 0; L < 3; ++L) {
    u16* xout = (L % 2 == 0) ? xa : xb;
    const u16* wp = wpack + (size_t)L*WP_LAYER;
    if (L == 0) k_proj<3><<<gNm, blk, 0, stream>>>(xin, segcur, wp, bm[L], pxb, psb, N);
    else        k_proj<2><<<gNm, blk, 0, stream>>>(xin, segcur, wp, bm[L], pxb, psb, N);
    k_scatmfma<<<gEm, blk, 0, stream>>>(ehin, wp, pxb, psb, rowp, colp, revp, ehout, E);
    k_gnmsg<<<gNw, blk, 0, stream>>>(ehout, revp, offs, pxb, (L < 2) ? segnxt : (u16*)nullptr, N);
    if (L == 0) k_nodef<3><<<gNm, blk, 0, stream>>>(xin, pxb, wp, bn[L], xout, N);
    else        k_nodef<2><<<gNm, blk, 0, stream>>>(xin, pxb, wp, bn[L], xout, N);
    u16* tmp = (u16*)ehin; ehin = ehout; ehout = tmp;
    u16* ts = segcur; segcur = segnxt; segnxt = ts;
    xin = xout;
  }

  k_pool<<<gBw, blk, 0, stream>>>(xa, goff, pooledh, B);
  k_xtconv<<<(B*128 + 255)/256, blk, 0, stream>>>(xt, ab1, B);
  {
    int waves = ((B + 15)/16) * (128/64);
    k_gemm<<<(waves + 3)/4, blk, 0, stream>>>(pooledh, 64, wxdP, bxd, ab1, 256, B, 128>>4, 64>>5, 1, 1);
  }
  {
    int waves = ((B + 15)/16) * (1024/64);
    k_gemm<<<(waves + 3)/4, blk, 0, stream>>>(ab1, 256, w1P, b1, h1h, 1024, B, 1024>>4, 256>>5, 1, 1);
  }
  {
    int waves = ((B + 15)/16) * (256/64);
    k_gemm<<<(waves + 3)/4, blk, 0, stream>>>(h1h, 1024, w2P, b2, h2f, 256, B, 256>>4, 1024>>5, 1, 0);
  }
  k_out<<<gBw, blk, 0, stream>>>(h2f, Wo, bo, (float*)d_out, B);
}

// Round 10
// 677.411 us; speedup vs baseline: 8.2196x; 1.0760x over previous
//
#include <hip/hip_runtime.h>
#include <hip/hip_fp16.h>

using u16 = unsigned short;
using u32 = unsigned int;
using u64 = unsigned long long;

typedef short short8 __attribute__((ext_vector_type(8)));
typedef float f32x4 __attribute__((ext_vector_type(4)));

// wpack section offsets (u16 units) within one layer's 20480-u16 slab
#define WP_TOP   0
#define WP_BOT   6144
#define WP_NTOP  10240
#define WP_NBOT  16384
#define WP_LAYER 20480

// fp16 storage helpers (RNE hardware converts)
__device__ __forceinline__ float h2f(u16 u){ union{u16 s; _Float16 h;} v; v.s=u; return (float)v.h; }
__device__ __forceinline__ u16 f2h(float f){ union{u16 s; _Float16 h;} v; v.h=(_Float16)f; return v.s; }
__device__ __forceinline__ u32 pack2(float a, float b){ return (u32)f2h(a) | ((u32)f2h(b)<<16); }

__device__ __forceinline__ void store16h(u16* d, const float* a){
  uint4 u0, u1;
  u0.x = pack2(a[0],a[1]);   u0.y = pack2(a[2],a[3]);
  u0.z = pack2(a[4],a[5]);   u0.w = pack2(a[6],a[7]);
  u1.x = pack2(a[8],a[9]);   u1.y = pack2(a[10],a[11]);
  u1.z = pack2(a[12],a[13]); u1.w = pack2(a[14],a[15]);
  *(uint4*)(d)   = u0;
  *(uint4*)(d+8) = u1;
}

__device__ __forceinline__ void load16h(const u16* p, float* out){
  uint4 v0 = *(const uint4*)(p);
  uint4 v1 = *(const uint4*)(p+8);
  out[0]=h2f((u16)v0.x);  out[1]=h2f((u16)(v0.x>>16));
  out[2]=h2f((u16)v0.y);  out[3]=h2f((u16)(v0.y>>16));
  out[4]=h2f((u16)v0.z);  out[5]=h2f((u16)(v0.z>>16));
  out[6]=h2f((u16)v0.w);  out[7]=h2f((u16)(v0.w>>16));
  out[8]=h2f((u16)v1.x);  out[9]=h2f((u16)(v1.x>>16));
  out[10]=h2f((u16)v1.y); out[11]=h2f((u16)(v1.y>>16));
  out[12]=h2f((u16)v1.z); out[13]=h2f((u16)(v1.z>>16));
  out[14]=h2f((u16)v1.w); out[15]=h2f((u16)(v1.w>>16));
}

// ---------------- CSR build ----------------
__global__ __launch_bounds__(256) void k_deg(
    const int* __restrict__ row, int* __restrict__ cnt, int E)
{
  int e = blockIdx.x*256 + threadIdx.x;
  if (e >= E) return;
  atomicAdd(&cnt[row[e]], 1);
}

__global__ __launch_bounds__(256) void k_bsum(
    const int* __restrict__ cnt, int* __restrict__ bsum, int N)
{
  __shared__ int sh[256];
  int t = threadIdx.x;
  int i = blockIdx.x*256 + t;
  sh[t] = (i < N) ? cnt[i] : 0;
  __syncthreads();
  #pragma unroll
  for (int s=128; s; s>>=1){ if (t<s) sh[t]+=sh[t+s]; __syncthreads(); }
  if (t==0) bsum[blockIdx.x] = sh[0];
}

__global__ __launch_bounds__(256) void k_bscan(
    const int* __restrict__ bsum, int* __restrict__ bofs, int nb,
    int* __restrict__ off, int N)
{
  __shared__ int sh[256];
  int t = threadIdx.x;
  int v = (t < nb) ? bsum[t] : 0;
  sh[t] = v;
  __syncthreads();
  #pragma unroll
  for (int s=1; s<256; s<<=1){
    int u = (t>=s) ? sh[t-s] : 0;
    __syncthreads();
    sh[t] += u;
    __syncthreads();
  }
  if (t < nb) bofs[t] = sh[t] - v;
  if (t == 0) off[N] = sh[nb-1];
}

__global__ __launch_bounds__(256) void k_apply(
    const int* __restrict__ cnt, const int* __restrict__ bofs,
    int* __restrict__ off, int* __restrict__ nxt, int N)
{
  __shared__ int sh[256];
  int t = threadIdx.x;
  int i = blockIdx.x*256 + t;
  int v = (i < N) ? cnt[i] : 0;
  sh[t] = v;
  __syncthreads();
  #pragma unroll
  for (int s=1; s<256; s<<=1){
    int u = (t>=s) ? sh[t-s] : 0;
    __syncthreads();
    sh[t] += u;
    __syncthreads();
  }
  if (i < N){
    int ex = sh[t] - v + bofs[blockIdx.x];
    off[i] = ex;
    nxt[i] = ex;
  }
}

__global__ __launch_bounds__(256) void k_fill(
    const int* __restrict__ row, int* __restrict__ nxt,
    int* __restrict__ perm, int* __restrict__ iperm, int E)
{
  int e = blockIdx.x*256 + threadIdx.x;
  if (e >= E) return;
  int pos = atomicAdd(&nxt[row[e]], 1);
  perm[pos] = e;
  iperm[e] = pos;
}

// permuted per-slot arrays; structural reverse: rev(e) = e<E2 ? e+E2 : e-E2
__global__ __launch_bounds__(256) void k_permarr(
    const int* __restrict__ perm, const int* __restrict__ iperm,
    const int* __restrict__ row, const int* __restrict__ col,
    int* __restrict__ rowp, int* __restrict__ colp, int* __restrict__ revp,
    int E, int E2)
{
  int i = blockIdx.x*256 + threadIdx.x;
  if (i >= E) return;
  int e = perm[i];
  rowp[i] = row[e];
  colp[i] = col[e];
  int re = (e < E2) ? e + E2 : e - E2;
  revp[i] = iperm[re];
}

// ---------------- x -> fp16 padded [N x 96] ----------------
__global__ __launch_bounds__(256) void k_xconv(
    const float* __restrict__ x, u16* __restrict__ xh, int N)
{
  int t = blockIdx.x*256 + threadIdx.x;
  if (t >= N*96) return;
  int n = t / 96, k = t - n*96;
  xh[t] = (k < 78) ? f2h(x[(size_t)n*78 + k]) : (u16)0;
}

// ---------------- seg0[n] = (sum of ea rows of n's out-edges)@We + deg*be  (fp16 out) ----------------
__global__ __launch_bounds__(256) void k_seg0(
    const float* __restrict__ ea, const int* __restrict__ perm,
    const int* __restrict__ off, const float* __restrict__ We,
    const float* __restrict__ be, u16* __restrict__ segb, int N)
{
  int w = (blockIdx.x << 2) + (threadIdx.x >> 6);
  if (w >= N) return;
  int lane = threadIdx.x & 63;
  int lo = off[w], hi = off[w+1];
  float wcol[6];
  #pragma unroll
  for (int k=0;k<6;k++) wcol[k] = We[k*64 + lane];
  float es[6] = {0.f,0.f,0.f,0.f,0.f,0.f};
  for (int j = lo; j < hi; j++){
    int e = perm[j];
    const float* a = ea + (size_t)e*6;
    #pragma unroll
    for (int k=0;k<6;k++) es[k] += a[k];
  }
  float acc = (float)(hi - lo) * be[lane];
  #pragma unroll
  for (int k=0;k<6;k++) acc += es[k]*wcol[k];
  segb[((size_t)w<<6) + lane] = f2h(acc);
}

// ---------------- fused L0 weights: W'[k][n] = (We@Wb)[k][n] (k<6), row 6 = be@Wb ----------------
__global__ __launch_bounds__(256) void k_fusew(
    const float* __restrict__ We, const float* __restrict__ be,
    const float* __restrict__ Wb, float* __restrict__ wf)
{
  int t = blockIdx.x*256 + threadIdx.x;
  if (t >= 448) return;
  int k = t >> 6, n = t & 63;
  float s = 0.f;
  if (k < 6) {
    for (int j=0;j<64;j++) s += We[k*64 + j] * Wb[(size_t)j*64 + n];
  } else {
    for (int j=0;j<64;j++) s += be[j] * Wb[(size_t)j*64 + n];
  }
  wf[t] = s;
}

// ---------------- pack one conv layer's weights into MFMA B-fragments (fp16) ----------------
__global__ __launch_bounds__(256) void k_prepw(
    const float* __restrict__ Wm, const float* __restrict__ Wn,
    int XD, int KT, u16* __restrict__ dst)
{
  int t = blockIdx.x*256 + threadIdx.x;
  int topFL = KT*256;
  const float* W; int rbase, rvalid, dofs, fl;
  if (t < topFL)                   { W = Wm; rbase = 0;  rvalid = XD; dofs = WP_TOP;  fl = t; }
  else if (t < topFL+512)          { W = Wm; rbase = XD; rvalid = 64; dofs = WP_BOT;  fl = t - topFL; }
  else if (t < 2*topFL+512)        { W = Wn; rbase = 0;  rvalid = XD; dofs = WP_NTOP; fl = t - topFL - 512; }
  else if (t < 2*topFL+1024)       { W = Wn; rbase = XD; rvalid = 64; dofs = WP_NBOT; fl = t - 2*topFL - 512; }
  else return;
  int f = fl >> 6, lane = fl & 63;
  int nt = f & 3, kk = f >> 2;
  int n = (nt<<4) + (lane & 15);
  int krel = (kk<<5) + ((lane>>4)<<3);
  u16* d = dst + dofs + (size_t)f*512 + lane*8;
  #pragma unroll
  for (int j=0;j<8;j++){
    int kr = krel + j;
    d[j] = (kr < rvalid) ? f2h(W[(size_t)(rbase+kr)*64 + n]) : (u16)0;
  }
}

// ---------------- generic pack: W [K x Nout] f32 -> fp16 B-frags ----------------
__global__ __launch_bounds__(256) void k_packw(
    const float* __restrict__ W, int K, int Nout, u16* __restrict__ dst)
{
  int t = blockIdx.x*256 + threadIdx.x;
  int NT = Nout >> 4;
  int total = (K >> 5) * NT * 64;
  if (t >= total) return;
  int f = t >> 6, lane = t & 63;
  int nt = f % NT, kk = f / NT;
  int n = (nt<<4) + (lane & 15);
  int kb = (kk<<5) + ((lane>>4)<<3);
  u16* d = dst + ((size_t)f*64 + lane)*8;
  #pragma unroll
  for (int j=0;j<8;j++) d[j] = f2h(W[(size_t)(kb+j)*Nout + n]);
}

// ---------------- generic MFMA GEMM (fp16 in, f32 acc) ----------------
__global__ __launch_bounds__(256) void k_gemm(
    const u16* __restrict__ A, int lda, const u16* __restrict__ BP,
    const float* __restrict__ bias, void* __restrict__ outv, int ldo,
    int M, int NT, int KT, int dorelu, int oh16)
{
  int lane = threadIdx.x & 63;
  int wid = (blockIdx.x << 2) + (threadIdx.x >> 6);
  int nb = NT >> 2;
  int mblk = wid / nb, nblk = wid - mblk*nb;
  int m0 = mblk << 4;
  if (m0 >= M) return;
  int n0 = nblk << 6;
  int nlo = lane & 15;
  int khi = (lane >> 4) << 3;
  int r0 = m0 + nlo; if (r0 > M-1) r0 = M-1;

  f32x4 acc[4];
  #pragma unroll
  for (int nt=0;nt<4;nt++){ f32x4 z = {0.f,0.f,0.f,0.f}; acc[nt]=z; }
  for (int kk=0; kk<KT; kk++){
    short8 a = *(const short8*)(A + (size_t)r0*lda + (kk<<5) + khi);
    #pragma unroll
    for (int nt=0;nt<4;nt++){
      short8 b = *(const short8*)(BP + ((size_t)(kk*NT + (nblk<<2) + nt)*64 + lane)*8);
      acc[nt] = __builtin_amdgcn_mfma_f32_16x16x32_f16(a, b, acc[nt], 0,0,0);
    }
  }
  int mrow = (lane >> 4) << 2;
  #pragma unroll
  for (int r=0;r<4;r++){
    int m = m0 + mrow + r;
    if (m >= M) continue;
    #pragma unroll
    for (int nt=0;nt<4;nt++){
      float v = acc[nt][r] + bias[n0 + (nt<<4) + nlo];
      if (dorelu) v = fmaxf(v, 0.f);
      if (oh16) ((u16*)outv)[(size_t)m*ldo + n0 + (nt<<4) + nlo] = f2h(v);
      else      ((float*)outv)[(size_t)m*ldo + n0 + (nt<<4) + nlo] = v;
    }
  }
}

// ---------------- MFMA node projections: px = x@Wtop + bm ; ps = seg@Wbot ----------------
template<int KT>
__global__ __launch_bounds__(256) void k_proj(
    const u16* __restrict__ xin, const u16* __restrict__ segb,
    const u16* __restrict__ wp, const float* __restrict__ bm,
    u16* __restrict__ pxb, u16* __restrict__ psb, int N)
{
  int lane = threadIdx.x & 63;
  int wid = (blockIdx.x << 2) + (threadIdx.x >> 6);
  int base = wid << 4;
  if (base >= N) return;
  int nlo = lane & 15;
  int khi = (lane >> 4) << 3;

  short8 bt[KT][4];
  #pragma unroll
  for (int kk=0;kk<KT;kk++)
    #pragma unroll
    for (int nt=0;nt<4;nt++)
      bt[kk][nt] = *(const short8*)(wp + WP_TOP + ((size_t)((kk<<2)|nt)*64 + lane)*8);
  short8 bb[2][4];
  #pragma unroll
  for (int kk=0;kk<2;kk++)
    #pragma unroll
    for (int nt=0;nt<4;nt++)
      bb[kk][nt] = *(const short8*)(wp + WP_BOT + ((size_t)((kk<<2)|nt)*64 + lane)*8);

  int r0 = base + nlo; if (r0 > N-1) r0 = N-1;
  const u16* xrow = xin + (size_t)r0*(KT*32);
  short8 ax[KT];
  #pragma unroll
  for (int kk=0;kk<KT;kk++) ax[kk] = *(const short8*)(xrow + (kk<<5) + khi);
  const u16* srow = segb + ((size_t)r0<<6);
  short8 as[2];
  #pragma unroll
  for (int kk=0;kk<2;kk++) as[kk] = *(const short8*)(srow + (kk<<5) + khi);

  f32x4 accP[4], accS[4];
  #pragma unroll
  for (int nt=0;nt<4;nt++){ f32x4 z = {0.f,0.f,0.f,0.f}; accP[nt]=z; accS[nt]=z; }
  #pragma unroll
  for (int kk=0;kk<KT;kk++)
    #pragma unroll
    for (int nt=0;nt<4;nt++)
      accP[nt] = __builtin_amdgcn_mfma_f32_16x16x32_f16(ax[kk], bt[kk][nt], accP[nt], 0,0,0);
  #pragma unroll
  for (int kk=0;kk<2;kk++)
    #pragma unroll
    for (int nt=0;nt<4;nt++)
      accS[nt] = __builtin_amdgcn_mfma_f32_16x16x32_f16(as[kk], bb[kk][nt], accS[nt], 0,0,0);

  float bmv[4];
  #pragma unroll
  for (int nt=0;nt<4;nt++) bmv[nt] = bm[(nt<<4) + nlo];

  int mrow = (lane >> 4) << 2;
  #pragma unroll
  for (int r=0;r<4;r++){
    int node = base + mrow + r;
    if (node >= N) continue;
    #pragma unroll
    for (int nt=0;nt<4;nt++){
      pxb[((size_t)node<<6) + (nt<<4) + nlo] = f2h(accP[nt][r] + bmv[nt]);
      psb[((size_t)node<<6) + (nt<<4) + nlo] = f2h(accS[nt][r]);
    }
  }
}

// ---------------- fused L0 edge kernel (no eh0 materialization):
// msg[revp[i]] = relu( px[colp[i]] + ps[rowp[i]] - (ea[perm[i]]@W' + b') ) ----------------
__global__ __launch_bounds__(256) void k_scat0(
    const float* __restrict__ ea, const int* __restrict__ perm,
    const float* __restrict__ wf,
    const u16* __restrict__ pxb, const u16* __restrict__ psb,
    const int* __restrict__ rowp, const int* __restrict__ colp,
    const int* __restrict__ revp, u16* __restrict__ msg, int E)
{
  int tid = blockIdx.x*256 + threadIdx.x;
  int i = tid >> 2;
  if (i >= E) return;
  int t = tid & 3;
  int e  = perm[i];
  int rp = rowp[i];
  int cp = colp[i];
  int rv = revp[i];
  const float* a = ea + (size_t)e*6;
  float av[6];
  #pragma unroll
  for (int k=0;k<6;k++) av[k] = a[k];
  float proj[16];
  const float* bp = wf + 384 + t*16;
  #pragma unroll
  for (int j=0;j<16;j++) proj[j] = bp[j];
  #pragma unroll
  for (int k=0;k<6;k++){
    const float* w = wf + k*64 + t*16;
    #pragma unroll
    for (int j=0;j<16;j++) proj[j] += av[k]*w[j];
  }
  float pc[16], pr[16];
  load16h(pxb + ((size_t)cp<<6) + t*16, pc);
  load16h(psb + ((size_t)rp<<6) + t*16, pr);
  float val[16];
  #pragma unroll
  for (int j=0;j<16;j++) val[j] = fmaxf(pc[j] + pr[j] - proj[j], 0.f);
  store16h(msg + ((size_t)rv<<6) + t*16, val);
}

// ---------------- fused MFMA edge kernel (L1/L2):
// msg[revp[i]] = relu( px[colp[i]] + ps[rowp[i]] - eh[i]@Wbot ) ----------------
__global__ __launch_bounds__(256) void k_scatmfma(
    const u16* __restrict__ eh, const u16* __restrict__ wp,
    const u16* __restrict__ pxb, const u16* __restrict__ psb,
    const int* __restrict__ rowp, const int* __restrict__ colp,
    const int* __restrict__ revp, u16* __restrict__ msg, int E)
{
  int lane = threadIdx.x & 63;
  int wid = (blockIdx.x << 2) + (threadIdx.x >> 6);
  int base = wid << 4;
  if (base >= E) return;
  int nlo = lane & 15;
  int khi = (lane >> 4) << 3;

  short8 bb[2][4];
  #pragma unroll
  for (int kk=0;kk<2;kk++)
    #pragma unroll
    for (int nt=0;nt<4;nt++)
      bb[kk][nt] = *(const short8*)(wp + WP_BOT + ((size_t)((kk<<2)|nt)*64 + lane)*8);

  int sa = base + nlo; if (sa > E-1) sa = E-1;
  const u16* ehp = eh + ((size_t)sa<<6) + khi;
  short8 a0 = *(const short8*)(ehp);
  short8 a1 = *(const short8*)(ehp + 32);

  f32x4 acc[4];
  #pragma unroll
  for (int nt=0;nt<4;nt++){
    f32x4 z = {0.f,0.f,0.f,0.f};
    acc[nt] = z;
    acc[nt] = __builtin_amdgcn_mfma_f32_16x16x32_f16(a0, bb[0][nt], acc[nt], 0,0,0);
    acc[nt] = __builtin_amdgcn_mfma_f32_16x16x32_f16(a1, bb[1][nt], acc[nt], 0,0,0);
  }

  int mrow = (lane >> 4) << 2;
  #pragma unroll
  for (int r=0;r<4;r++){
    int slot = base + mrow + r;
    if (slot >= E) continue;
    int rp = rowp[slot];
    int cp = colp[slot];
    int rv = revp[slot];
    const u16* pr = psb + ((size_t)rp<<6) + nlo;
    const u16* pc = pxb + ((size_t)cp<<6) + nlo;
    u16* ob = msg + ((size_t)rv<<6) + nlo;
    #pragma unroll
    for (int nt=0;nt<4;nt++){
      float v = h2f(pc[nt<<4]) + h2f(pr[nt<<4]) - acc[nt][r];
      ob[nt<<4] = f2h(fmaxf(v, 0.f));
    }
  }
}

// ---------------- fused: nmsg[n] = Σ msg[revp[j]]; segnext[n] = Σ msg[j]
// 4 rows in flight per wave: groups of 16 lanes, uint2 (4 ch) per lane ----------------
__global__ __launch_bounds__(256) void k_gnmsg(
    const u16* __restrict__ msg, const int* __restrict__ revp,
    const int* __restrict__ off, u16* __restrict__ nmsgb,
    u16* __restrict__ segnext, int N)
{
  int w = (blockIdx.x << 2) + (threadIdx.x >> 6);
  if (w >= N) return;
  int lane = threadIdx.x & 63;
  int g = lane >> 4, l = lane & 15;
  int lo = off[w], hi = off[w+1];
  float s0=0.f,s1=0.f,s2=0.f,s3=0.f;
  float t0=0.f,t1=0.f,t2=0.f,t3=0.f;
  if (segnext){
    for (int j = lo + g; j < hi; j += 4){
      int i = revp[j];
      uint2 v = *(const uint2*)(msg + ((size_t)i<<6) + (l<<2));
      uint2 u = *(const uint2*)(msg + ((size_t)j<<6) + (l<<2));
      s0 += h2f((u16)v.x); s1 += h2f((u16)(v.x>>16)); s2 += h2f((u16)v.y); s3 += h2f((u16)(v.y>>16));
      t0 += h2f((u16)u.x); t1 += h2f((u16)(u.x>>16)); t2 += h2f((u16)u.y); t3 += h2f((u16)(u.y>>16));
    }
  } else {
    for (int j = lo + g; j < hi; j += 4){
      int i = revp[j];
      uint2 v = *(const uint2*)(msg + ((size_t)i<<6) + (l<<2));
      s0 += h2f((u16)v.x); s1 += h2f((u16)(v.x>>16)); s2 += h2f((u16)v.y); s3 += h2f((u16)(v.y>>16));
    }
  }
  s0 += __shfl_xor(s0,16,64); s0 += __shfl_xor(s0,32,64);
  s1 += __shfl_xor(s1,16,64); s1 += __shfl_xor(s1,32,64);
  s2 += __shfl_xor(s2,16,64); s2 += __shfl_xor(s2,32,64);
  s3 += __shfl_xor(s3,16,64); s3 += __shfl_xor(s3,32,64);
  if (segnext){
    t0 += __shfl_xor(t0,16,64); t0 += __shfl_xor(t0,32,64);
    t1 += __shfl_xor(t1,16,64); t1 += __shfl_xor(t1,32,64);
    t2 += __shfl_xor(t2,16,64); t2 += __shfl_xor(t2,32,64);
    t3 += __shfl_xor(t3,16,64); t3 += __shfl_xor(t3,32,64);
  }
  if (g == 0){
    uint2 o; o.x = pack2(s0,s1); o.y = pack2(s2,s3);
    *(uint2*)(nmsgb + ((size_t)w<<6) + (l<<2)) = o;
    if (segnext){
      uint2 q; q.x = pack2(t0,t1); q.y = pack2(t2,t3);
      *(uint2*)(segnext + ((size_t)w<<6) + (l<<2)) = q;
    }
  }
}

// ---------------- MFMA node update: xout = relu(x@WnTop + nmsg@WnBot + bn), fp16 out ----------------
template<int KT>
__global__ __launch_bounds__(256) void k_nodef(
    const u16* __restrict__ xin, const u16* __restrict__ nmsgb,
    const u16* __restrict__ wp, const float* __restrict__ bn,
    u16* __restrict__ xout, int N)
{
  int lane = threadIdx.x & 63;
  int wid = (blockIdx.x << 2) + (threadIdx.x >> 6);
  int base = wid << 4;
  if (base >= N) return;
  int nlo = lane & 15;
  int khi = (lane >> 4) << 3;

  short8 bt[KT][4];
  #pragma unroll
  for (int kk=0;kk<KT;kk++)
    #pragma unroll
    for (int nt=0;nt<4;nt++)
      bt[kk][nt] = *(const short8*)(wp + WP_NTOP + ((size_t)((kk<<2)|nt)*64 + lane)*8);
  short8 bb[2][4];
  #pragma unroll
  for (int kk=0;kk<2;kk++)
    #pragma unroll
    for (int nt=0;nt<4;nt++)
      bb[kk][nt] = *(const short8*)(wp + WP_NBOT + ((size_t)((kk<<2)|nt)*64 + lane)*8);

  int r0 = base + nlo; if (r0 > N-1) r0 = N-1;
  const u16* xrow = xin + (size_t)r0*(KT*32);
  short8 ax[KT];
  #pragma unroll
  for (int kk=0;kk<KT;kk++) ax[kk] = *(const short8*)(xrow + (kk<<5) + khi);
  const u16* mrp = nmsgb + ((size_t)r0<<6);
  short8 am[2];
  #pragma unroll
  for (int kk=0;kk<2;kk++) am[kk] = *(const short8*)(mrp + (kk<<5) + khi);

  f32x4 acc[4];
  #pragma unroll
  for (int nt=0;nt<4;nt++){ f32x4 z = {0.f,0.f,0.f,0.f}; acc[nt]=z; }
  #pragma unroll
  for (int kk=0;kk<KT;kk++)
    #pragma unroll
    for (int nt=0;nt<4;nt++)
      acc[nt] = __builtin_amdgcn_mfma_f32_16x16x32_f16(ax[kk], bt[kk][nt], acc[nt], 0,0,0);
  #pragma unroll
  for (int kk=0;kk<2;kk++)
    #pragma unroll
    for (int nt=0;nt<4;nt++)
      acc[nt] = __builtin_amdgcn_mfma_f32_16x16x32_f16(am[kk], bb[kk][nt], acc[nt], 0,0,0);

  float bnv[4];
  #pragma unroll
  for (int nt=0;nt<4;nt++) bnv[nt] = bn[(nt<<4) + nlo];

  int mrow = (lane >> 4) << 2;
  #pragma unroll
  for (int r=0;r<4;r++){
    int node = base + mrow + r;
    if (node >= N) continue;
    #pragma unroll
    for (int nt=0;nt<4;nt++)
      xout[((size_t)node<<6) + (nt<<4) + nlo] = f2h(fmaxf(acc[nt][r] + bnv[nt], 0.f));
  }
}

// ---------------- pooling (batch is sorted), fp16 out ----------------
__global__ __launch_bounds__(256) void k_goff(
    const int* __restrict__ batch, int* __restrict__ goff, int N, int B)
{
  int n = blockIdx.x*256 + threadIdx.x;
  if (n >= N) return;
  int bcur = batch[n];
  int bprev = (n == 0) ? -1 : batch[n-1];
  for (int g = bprev + 1; g <= bcur; ++g) goff[g] = n;
  if (n == N-1) { for (int g = bcur + 1; g <= B; ++g) goff[g] = N; }
}

__global__ __launch_bounds__(256) void k_pool(
    const u16* __restrict__ xin, const int* __restrict__ goff,
    u16* __restrict__ pooledh, int B)
{
  int g = (blockIdx.x << 2) + (threadIdx.x >> 6);
  if (g >= B) return;
  int lane = threadIdx.x & 63;
  int lo = goff[g], hi = goff[g + 1];
  float s = 0.f;
  for (int n = lo; n < hi; n++) s += h2f(xin[((size_t)n << 6) + lane]);
  pooledh[((size_t)g << 6) + lane] = f2h(s);
}

// ---------------- xt -> fp16 into ab1 cols 128..255 ----------------
__global__ __launch_bounds__(256) void k_xtconv(
    const float* __restrict__ xt, u16* __restrict__ ab1, int B)
{
  int t = blockIdx.x*256 + threadIdx.x;
  if (t >= B*128) return;
  int r = t >> 7, c = t & 127;
  ab1[(size_t)r*256 + 128 + c] = f2h(xt[t]);
}

// ---------------- final dot: out[r] = h2[r]·Wo + bo (wave per row) ----------------
__global__ __launch_bounds__(256) void k_out(
    const float* __restrict__ h2, const float* __restrict__ Wo,
    const float* __restrict__ bo, float* __restrict__ out, int B)
{
  int w = (blockIdx.x << 2) + (threadIdx.x >> 6);
  if (w >= B) return;
  int lane = threadIdx.x & 63;
  const float* h = h2 + (size_t)w*256;
  float s = 0.f;
  #pragma unroll
  for (int k=0;k<4;k++) s += h[lane + (k<<6)] * Wo[lane + (k<<6)];
  #pragma unroll
  for (int off=32; off; off>>=1) s += __shfl_down(s, off, 64);
  if (lane == 0) out[w] = s + bo[0];
}

extern "C" void kernel_launch(void* const* d_in, const int* in_sizes, int n_in,
                              void* d_out, int out_size, void* d_ws, size_t ws_size,
                              hipStream_t stream)
{
  const float* x    = (const float*)d_in[0];
  const float* ea   = (const float*)d_in[1];
  const float* xt   = (const float*)d_in[2];
  const int*   eidx = (const int*)d_in[3];
  const int*   batch= (const int*)d_in[4];
  const float* We   = (const float*)d_in[6];
  const float* be   = (const float*)d_in[7];
  const float* Wm[3]= {(const float*)d_in[8],  (const float*)d_in[12], (const float*)d_in[16]};
  const float* bm[3]= {(const float*)d_in[9],  (const float*)d_in[13], (const float*)d_in[17]};
  const float* Wn[3]= {(const float*)d_in[10], (const float*)d_in[14], (const float*)d_in[18]};
  const float* bn[3]= {(const float*)d_in[11], (const float*)d_in[15], (const float*)d_in[19]};
  const float* Wxd  = (const float*)d_in[20];
  const float* bxd  = (const float*)d_in[21];
  const float* W1   = (const float*)d_in[22];
  const float* b1   = (const float*)d_in[23];
  const float* W2   = (const float*)d_in[24];
  const float* b2   = (const float*)d_in[25];
  const float* Wo   = (const float*)d_in[26];
  const float* bo   = (const float*)d_in[27];

  const int N = in_sizes[0] / 78;
  const int E = in_sizes[1] / 6;
  const int B = in_sizes[2] / 128;
  const int E2 = E / 2;
  const int* row = eidx;
  const int* col = eidx + E;

  char* p = (char*)d_ws;
  size_t off = 0;
  auto alloc = [&](size_t b)->void* {
    void* r = p + off;
    off = (off + b + 255) & ~(size_t)255;
    return r;
  };
  // persistent buffers (~248 MB total; 259 MB proven safe)
  u16*   ehA   = (u16*)  alloc((size_t)E * 128);
  u16*   ehB   = (u16*)  alloc((size_t)E * 128);
  int*   rowp  = (int*)  alloc((size_t)E * 4);
  int*   colp  = (int*)  alloc((size_t)E * 4);
  int*   revp  = (int*)  alloc((size_t)E * 4);
  int*   offs  = (int*)  alloc((size_t)(N+1) * 4);
  u16*   xh    = (u16*)  alloc((size_t)N * 192);   // [N x 96] fp16, zero-padded
  u16*   sA    = (u16*)  alloc((size_t)N * 128);   // seg ping
  u16*   sB    = (u16*)  alloc((size_t)N * 128);   // seg pong
  u16*   pxb   = (u16*)  alloc((size_t)N * 128);   // px, then reused as nmsg
  u16*   psb   = (u16*)  alloc((size_t)N * 128);
  u16*   xa    = (u16*)  alloc((size_t)N * 128);   // fp16 node states
  u16*   xb    = (u16*)  alloc((size_t)N * 128);
  int*   goff  = (int*)  alloc((size_t)(B+1) * 4);
  u16*   pooledh=(u16*)  alloc((size_t)B * 128);
  u16*   ab1   = (u16*)  alloc((size_t)B * 512);
  u16*   h1h   = (u16*)  alloc((size_t)B * 2048);
  float* h2f_  = (float*)alloc((size_t)B * 1024);
  u16*   wpack = (u16*)  alloc((size_t)3 * WP_LAYER * 2);
  u16*   wxdP  = (u16*)  alloc((size_t)(64/32)*(128/16)*512 * 2);
  u16*   w1P   = (u16*)  alloc((size_t)(256/32)*(1024/16)*512 * 2);
  u16*   w2P   = (u16*)  alloc((size_t)(1024/32)*(256/16)*512 * 2);
  float* wfuse = (float*)alloc((size_t)448 * 4);   // W' (6x64) + b' (64), f32

  // setup transients aliased into ehA (ehA's first write is L1 k_scatmfma,
  // after perm's last use in k_scat0/k_seg0)
  char* ehAc = (char*)ehA;
  int* perm  = (int*)ehAc;           // 3.2 MB
  int* iperm = perm + E;             // 3.2 MB
  int* cnt   = iperm + E;            // 0.16 MB
  int* nxt   = cnt + N;              // 0.16 MB
  int* bsum  = nxt + N;              // 4 KB
  int* bofs  = bsum + 1024;          // 4 KB

  dim3 blk(256);
  int gE   = (E + 255) / 256;
  int gE4  = ((size_t)E*4 + 255) / 256;
  int gEm  = (E + 63) / 64;
  int gN   = (N + 255) / 256;
  int gNm  = (N + 63) / 64;
  int gNw  = (N + 3) / 4;
  int gBw  = (B + 3) / 4;
  int gXc  = (N*96 + 255) / 256;
  int nb   = (N + 255) / 256;    // scan blocks (N=40000 -> 157, <=256 ok)

  hipMemsetAsync(cnt, 0, (size_t)N * 4, stream);
  k_deg  <<<gE, blk, 0, stream>>>(row, cnt, E);
  k_bsum <<<nb, blk, 0, stream>>>(cnt, bsum, N);
  k_bscan<<<1,  blk, 0, stream>>>(bsum, bofs, nb, offs, N);
  k_apply<<<nb, blk, 0, stream>>>(cnt, bofs, offs, nxt, N);
  k_fill <<<gE, blk, 0, stream>>>(row, nxt, perm, iperm, E);
  k_permarr<<<gE, blk, 0, stream>>>(perm, iperm, row, col, rowp, colp, revp, E, E2);
  k_seg0<<<gNw, blk, 0, stream>>>(ea, perm, offs, We, be, sA, N);
  k_xconv<<<gXc, blk, 0, stream>>>(x, xh, N);
  k_goff<<<gN, blk, 0, stream>>>(batch, goff, N, B);
  k_fusew<<<2, blk, 0, stream>>>(We, be, Wm[0] + (size_t)78*64, wfuse);
  for (int L = 0; L < 3; ++L) {
    int XD = (L == 0) ? 78 : 64;
    int KT = (L == 0) ? 3 : 2;
    k_prepw<<<10, blk, 0, stream>>>(Wm[L], Wn[L], XD, KT, wpack + (size_t)L*WP_LAYER);
  }
  k_packw<<<(1024 + 255)/256, blk, 0, stream>>>(Wxd, 64, 128, wxdP);
  k_packw<<<(32768 + 255)/256, blk, 0, stream>>>(W1, 256, 1024, w1P);
  k_packw<<<(32768 + 255)/256, blk, 0, stream>>>(W2, 1024, 256, w2P);

  const u16* wp0 = wpack;
  const u16* wp1 = wpack + (size_t)WP_LAYER;
  const u16* wp2 = wpack + (size_t)2*WP_LAYER;

  // ---- L0 (eh0 never materialized) ----
  k_proj<3><<<gNm, blk, 0, stream>>>(xh, sA, wp0, bm[0], pxb, psb, N);
  k_scat0<<<gE4, blk, 0, stream>>>(ea, perm, wfuse, pxb, psb, rowp, colp, revp, ehB, E);
  k_gnmsg<<<gNw, blk, 0, stream>>>(ehB, revp, offs, pxb, sB, N);
  k_nodef<3><<<gNm, blk, 0, stream>>>(xh, pxb, wp0, bn[0], xa, N);
  // ---- L1 ----
  k_proj<2><<<gNm, blk, 0, stream>>>(xa, sB, wp1, bm[1], pxb, psb, N);
  k_scatmfma<<<gEm, blk, 0, stream>>>(ehB, wp1, pxb, psb, rowp, colp, revp, ehA, E);
  k_gnmsg<<<gNw, blk, 0, stream>>>(ehA, revp, offs, pxb, sA, N);
  k_nodef<2><<<gNm, blk, 0, stream>>>(xa, pxb, wp1, bn[1], xb, N);
  // ---- L2 ----
  k_proj<2><<<gNm, blk, 0, stream>>>(xb, sA, wp2, bm[2], pxb, psb, N);
  k_scatmfma<<<gEm, blk, 0, stream>>>(ehA, wp2, pxb, psb, rowp, colp, revp, ehB, E);
  k_gnmsg<<<gNw, blk, 0, stream>>>(ehB, revp, offs, pxb, (u16*)nullptr, N);
  k_nodef<2><<<gNm, blk, 0, stream>>>(xb, pxb, wp2, bn[2], xa, N);

  k_pool<<<gBw, blk, 0, stream>>>(xa, goff, pooledh, B);
  k_xtconv<<<(B*128 + 255)/256, blk, 0, stream>>>(xt, ab1, B);
  {
    int waves = ((B + 15)/16) * (128/64);
    k_gemm<<<(waves + 3)/4, blk, 0, stream>>>(pooledh, 64, wxdP, bxd, ab1, 256, B, 128>>4, 64>>5, 1, 1);
  }
  {
    int waves = ((B + 15)/16) * (1024/64);
    k_gemm<<<(waves + 3)/4, blk, 0, stream>>>(ab1, 256, w1P, b1, h1h, 1024, B, 1024>>4, 256>>5, 1, 1);
  }
  {
    int waves = ((B + 15)/16) * (256/64);
    k_gemm<<<(waves + 3)/4, blk, 0, stream>>>(h1h, 1024, w2P, b2, h2f_, 256, B, 256>>4, 1024>>5, 1, 0);
  }
  k_out<<<gBw, blk, 0, stream>>>(h2f_, Wo, bo, (float*)d_out, B);
}

// Round 11
// 676.778 us; speedup vs baseline: 8.2272x; 1.0009x over previous
//
#include <hip/hip_runtime.h>
#include <hip/hip_fp16.h>

using u16 = unsigned short;
using u32 = unsigned int;
using u64 = unsigned long long;

typedef short short8 __attribute__((ext_vector_type(8)));
typedef float f32x4 __attribute__((ext_vector_type(4)));

// wpack section offsets (u16 units) within one layer's 20480-u16 slab
#define WP_TOP   0
#define WP_BOT   6144
#define WP_NTOP  10240
#define WP_NBOT  16384
#define WP_LAYER 20480

// fp16 storage helpers (RNE hardware converts)
__device__ __forceinline__ float h2f(u16 u){ union{u16 s; _Float16 h;} v; v.s=u; return (float)v.h; }
__device__ __forceinline__ u16 f2h(float f){ union{u16 s; _Float16 h;} v; v.h=(_Float16)f; return v.s; }
__device__ __forceinline__ u32 pack2(float a, float b){ return (u32)f2h(a) | ((u32)f2h(b)<<16); }

// bijective XCD-chunked block swizzle (8 XCDs; m204 formula, any grid size)
__device__ __forceinline__ int xswz(int bid, int G){
  int q = G >> 3, r = G & 7;
  int x = bid & 7, idx = bid >> 3;
  int base = (x < r) ? x*(q+1) : r*(q+1) + (x - r)*q;
  return base + idx;
}

__device__ __forceinline__ void store16h(u16* d, const float* a){
  uint4 u0, u1;
  u0.x = pack2(a[0],a[1]);   u0.y = pack2(a[2],a[3]);
  u0.z = pack2(a[4],a[5]);   u0.w = pack2(a[6],a[7]);
  u1.x = pack2(a[8],a[9]);   u1.y = pack2(a[10],a[11]);
  u1.z = pack2(a[12],a[13]); u1.w = pack2(a[14],a[15]);
  *(uint4*)(d)   = u0;
  *(uint4*)(d+8) = u1;
}

__device__ __forceinline__ void load16h(const u16* p, float* out){
  uint4 v0 = *(const uint4*)(p);
  uint4 v1 = *(const uint4*)(p+8);
  out[0]=h2f((u16)v0.x);  out[1]=h2f((u16)(v0.x>>16));
  out[2]=h2f((u16)v0.y);  out[3]=h2f((u16)(v0.y>>16));
  out[4]=h2f((u16)v0.z);  out[5]=h2f((u16)(v0.z>>16));
  out[6]=h2f((u16)v0.w);  out[7]=h2f((u16)(v0.w>>16));
  out[8]=h2f((u16)v1.x);  out[9]=h2f((u16)(v1.x>>16));
  out[10]=h2f((u16)v1.y); out[11]=h2f((u16)(v1.y>>16));
  out[12]=h2f((u16)v1.z); out[13]=h2f((u16)(v1.z>>16));
  out[14]=h2f((u16)v1.w); out[15]=h2f((u16)(v1.w>>16));
}

// ---------------- CSR build ----------------
__global__ __launch_bounds__(256) void k_deg(
    const int* __restrict__ row, int* __restrict__ cnt, int E)
{
  int e = blockIdx.x*256 + threadIdx.x;
  if (e >= E) return;
  atomicAdd(&cnt[row[e]], 1);
}

__global__ __launch_bounds__(256) void k_bsum(
    const int* __restrict__ cnt, int* __restrict__ bsum, int N)
{
  __shared__ int sh[256];
  int t = threadIdx.x;
  int i = blockIdx.x*256 + t;
  sh[t] = (i < N) ? cnt[i] : 0;
  __syncthreads();
  #pragma unroll
  for (int s=128; s; s>>=1){ if (t<s) sh[t]+=sh[t+s]; __syncthreads(); }
  if (t==0) bsum[blockIdx.x] = sh[0];
}

__global__ __launch_bounds__(256) void k_bscan(
    const int* __restrict__ bsum, int* __restrict__ bofs, int nb,
    int* __restrict__ off, int N)
{
  __shared__ int sh[256];
  int t = threadIdx.x;
  int v = (t < nb) ? bsum[t] : 0;
  sh[t] = v;
  __syncthreads();
  #pragma unroll
  for (int s=1; s<256; s<<=1){
    int u = (t>=s) ? sh[t-s] : 0;
    __syncthreads();
    sh[t] += u;
    __syncthreads();
  }
  if (t < nb) bofs[t] = sh[t] - v;
  if (t == 0) off[N] = sh[nb-1];
}

__global__ __launch_bounds__(256) void k_apply(
    const int* __restrict__ cnt, const int* __restrict__ bofs,
    int* __restrict__ off, int* __restrict__ nxt, int N)
{
  __shared__ int sh[256];
  int t = threadIdx.x;
  int i = blockIdx.x*256 + t;
  int v = (i < N) ? cnt[i] : 0;
  sh[t] = v;
  __syncthreads();
  #pragma unroll
  for (int s=1; s<256; s<<=1){
    int u = (t>=s) ? sh[t-s] : 0;
    __syncthreads();
    sh[t] += u;
    __syncthreads();
  }
  if (i < N){
    int ex = sh[t] - v + bofs[blockIdx.x];
    off[i] = ex;
    nxt[i] = ex;
  }
}

__global__ __launch_bounds__(256) void k_fill(
    const int* __restrict__ row, int* __restrict__ nxt,
    int* __restrict__ perm, int* __restrict__ iperm, int E)
{
  int e = blockIdx.x*256 + threadIdx.x;
  if (e >= E) return;
  int pos = atomicAdd(&nxt[row[e]], 1);
  perm[pos] = e;
  iperm[e] = pos;
}

// permuted per-slot arrays; structural reverse: rev(e) = e<E2 ? e+E2 : e-E2
__global__ __launch_bounds__(256) void k_permarr(
    const int* __restrict__ perm, const int* __restrict__ iperm,
    const int* __restrict__ row, const int* __restrict__ col,
    int* __restrict__ rowp, int* __restrict__ colp, int* __restrict__ revp,
    int E, int E2)
{
  int i = blockIdx.x*256 + threadIdx.x;
  if (i >= E) return;
  int e = perm[i];
  rowp[i] = row[e];
  colp[i] = col[e];
  int re = (e < E2) ? e + E2 : e - E2;
  revp[i] = iperm[re];
}

// ---------------- x -> fp16 padded [N x 96] ----------------
__global__ __launch_bounds__(256) void k_xconv(
    const float* __restrict__ x, u16* __restrict__ xh, int N)
{
  int t = blockIdx.x*256 + threadIdx.x;
  if (t >= N*96) return;
  int n = t / 96, k = t - n*96;
  xh[t] = (k < 78) ? f2h(x[(size_t)n*78 + k]) : (u16)0;
}

// ---------------- seg0[n] = (sum of ea rows of n's out-edges)@We + deg*be  (fp16 out) ----------------
__global__ __launch_bounds__(256) void k_seg0(
    const float* __restrict__ ea, const int* __restrict__ perm,
    const int* __restrict__ off, const float* __restrict__ We,
    const float* __restrict__ be, u16* __restrict__ segb, int N)
{
  int w = (blockIdx.x << 2) + (threadIdx.x >> 6);
  if (w >= N) return;
  int lane = threadIdx.x & 63;
  int lo = off[w], hi = off[w+1];
  float wcol[6];
  #pragma unroll
  for (int k=0;k<6;k++) wcol[k] = We[k*64 + lane];
  float es[6] = {0.f,0.f,0.f,0.f,0.f,0.f};
  for (int j = lo; j < hi; j++){
    int e = perm[j];
    const float* a = ea + (size_t)e*6;
    #pragma unroll
    for (int k=0;k<6;k++) es[k] += a[k];
  }
  float acc = (float)(hi - lo) * be[lane];
  #pragma unroll
  for (int k=0;k<6;k++) acc += es[k]*wcol[k];
  segb[((size_t)w<<6) + lane] = f2h(acc);
}

// ---------------- fused L0 weights: W'[k][n] = (We@Wb)[k][n] (k<6), row 6 = be@Wb ----------------
__global__ __launch_bounds__(256) void k_fusew(
    const float* __restrict__ We, const float* __restrict__ be,
    const float* __restrict__ Wb, float* __restrict__ wf)
{
  int t = blockIdx.x*256 + threadIdx.x;
  if (t >= 448) return;
  int k = t >> 6, n = t & 63;
  float s = 0.f;
  if (k < 6) {
    for (int j=0;j<64;j++) s += We[k*64 + j] * Wb[(size_t)j*64 + n];
  } else {
    for (int j=0;j<64;j++) s += be[j] * Wb[(size_t)j*64 + n];
  }
  wf[t] = s;
}

// ---------------- pack one conv layer's weights into MFMA B-fragments (fp16) ----------------
__global__ __launch_bounds__(256) void k_prepw(
    const float* __restrict__ Wm, const float* __restrict__ Wn,
    int XD, int KT, u16* __restrict__ dst)
{
  int t = blockIdx.x*256 + threadIdx.x;
  int topFL = KT*256;
  const float* W; int rbase, rvalid, dofs, fl;
  if (t < topFL)                   { W = Wm; rbase = 0;  rvalid = XD; dofs = WP_TOP;  fl = t; }
  else if (t < topFL+512)          { W = Wm; rbase = XD; rvalid = 64; dofs = WP_BOT;  fl = t - topFL; }
  else if (t < 2*topFL+512)        { W = Wn; rbase = 0;  rvalid = XD; dofs = WP_NTOP; fl = t - topFL - 512; }
  else if (t < 2*topFL+1024)       { W = Wn; rbase = XD; rvalid = 64; dofs = WP_NBOT; fl = t - 2*topFL - 512; }
  else return;
  int f = fl >> 6, lane = fl & 63;
  int nt = f & 3, kk = f >> 2;
  int n = (nt<<4) + (lane & 15);
  int krel = (kk<<5) + ((lane>>4)<<3);
  u16* d = dst + dofs + (size_t)f*512 + lane*8;
  #pragma unroll
  for (int j=0;j<8;j++){
    int kr = krel + j;
    d[j] = (kr < rvalid) ? f2h(W[(size_t)(rbase+kr)*64 + n]) : (u16)0;
  }
}

// ---------------- generic pack: W [K x Nout] f32 -> fp16 B-frags ----------------
__global__ __launch_bounds__(256) void k_packw(
    const float* __restrict__ W, int K, int Nout, u16* __restrict__ dst)
{
  int t = blockIdx.x*256 + threadIdx.x;
  int NT = Nout >> 4;
  int total = (K >> 5) * NT * 64;
  if (t >= total) return;
  int f = t >> 6, lane = t & 63;
  int nt = f % NT, kk = f / NT;
  int n = (nt<<4) + (lane & 15);
  int kb = (kk<<5) + ((lane>>4)<<3);
  u16* d = dst + ((size_t)f*64 + lane)*8;
  #pragma unroll
  for (int j=0;j<8;j++) d[j] = f2h(W[(size_t)(kb+j)*Nout + n]);
}

// ---------------- generic MFMA GEMM (fp16 in, f32 acc) ----------------
__global__ __launch_bounds__(256) void k_gemm(
    const u16* __restrict__ A, int lda, const u16* __restrict__ BP,
    const float* __restrict__ bias, void* __restrict__ outv, int ldo,
    int M, int NT, int KT, int dorelu, int oh16)
{
  int lane = threadIdx.x & 63;
  int wid = (blockIdx.x << 2) + (threadIdx.x >> 6);
  int nb = NT >> 2;
  int mblk = wid / nb, nblk = wid - mblk*nb;
  int m0 = mblk << 4;
  if (m0 >= M) return;
  int n0 = nblk << 6;
  int nlo = lane & 15;
  int khi = (lane >> 4) << 3;
  int r0 = m0 + nlo; if (r0 > M-1) r0 = M-1;

  f32x4 acc[4];
  #pragma unroll
  for (int nt=0;nt<4;nt++){ f32x4 z = {0.f,0.f,0.f,0.f}; acc[nt]=z; }
  for (int kk=0; kk<KT; kk++){
    short8 a = *(const short8*)(A + (size_t)r0*lda + (kk<<5) + khi);
    #pragma unroll
    for (int nt=0;nt<4;nt++){
      short8 b = *(const short8*)(BP + ((size_t)(kk*NT + (nblk<<2) + nt)*64 + lane)*8);
      acc[nt] = __builtin_amdgcn_mfma_f32_16x16x32_f16(a, b, acc[nt], 0,0,0);
    }
  }
  int mrow = (lane >> 4) << 2;
  #pragma unroll
  for (int r=0;r<4;r++){
    int m = m0 + mrow + r;
    if (m >= M) continue;
    #pragma unroll
    for (int nt=0;nt<4;nt++){
      float v = acc[nt][r] + bias[n0 + (nt<<4) + nlo];
      if (dorelu) v = fmaxf(v, 0.f);
      if (oh16) ((u16*)outv)[(size_t)m*ldo + n0 + (nt<<4) + nlo] = f2h(v);
      else      ((float*)outv)[(size_t)m*ldo + n0 + (nt<<4) + nlo] = v;
    }
  }
}

// ---------------- MFMA node projections: px = x@Wtop + bm ; ps = seg@Wbot ----------------
template<int KT>
__global__ __launch_bounds__(256) void k_proj(
    const u16* __restrict__ xin, const u16* __restrict__ segb,
    const u16* __restrict__ wp, const float* __restrict__ bm,
    u16* __restrict__ pxb, u16* __restrict__ psb, int N)
{
  int lane = threadIdx.x & 63;
  int wid = (blockIdx.x << 2) + (threadIdx.x >> 6);
  int base = wid << 4;
  if (base >= N) return;
  int nlo = lane & 15;
  int khi = (lane >> 4) << 3;

  short8 bt[KT][4];
  #pragma unroll
  for (int kk=0;kk<KT;kk++)
    #pragma unroll
    for (int nt=0;nt<4;nt++)
      bt[kk][nt] = *(const short8*)(wp + WP_TOP + ((size_t)((kk<<2)|nt)*64 + lane)*8);
  short8 bb[2][4];
  #pragma unroll
  for (int kk=0;kk<2;kk++)
    #pragma unroll
    for (int nt=0;nt<4;nt++)
      bb[kk][nt] = *(const short8*)(wp + WP_BOT + ((size_t)((kk<<2)|nt)*64 + lane)*8);

  int r0 = base + nlo; if (r0 > N-1) r0 = N-1;
  const u16* xrow = xin + (size_t)r0*(KT*32);
  short8 ax[KT];
  #pragma unroll
  for (int kk=0;kk<KT;kk++) ax[kk] = *(const short8*)(xrow + (kk<<5) + khi);
  const u16* srow = segb + ((size_t)r0<<6);
  short8 as[2];
  #pragma unroll
  for (int kk=0;kk<2;kk++) as[kk] = *(const short8*)(srow + (kk<<5) + khi);

  f32x4 accP[4], accS[4];
  #pragma unroll
  for (int nt=0;nt<4;nt++){ f32x4 z = {0.f,0.f,0.f,0.f}; accP[nt]=z; accS[nt]=z; }
  #pragma unroll
  for (int kk=0;kk<KT;kk++)
    #pragma unroll
    for (int nt=0;nt<4;nt++)
      accP[nt] = __builtin_amdgcn_mfma_f32_16x16x32_f16(ax[kk], bt[kk][nt], accP[nt], 0,0,0);
  #pragma unroll
  for (int kk=0;kk<2;kk++)
    #pragma unroll
    for (int nt=0;nt<4;nt++)
      accS[nt] = __builtin_amdgcn_mfma_f32_16x16x32_f16(as[kk], bb[kk][nt], accS[nt], 0,0,0);

  float bmv[4];
  #pragma unroll
  for (int nt=0;nt<4;nt++) bmv[nt] = bm[(nt<<4) + nlo];

  int mrow = (lane >> 4) << 2;
  #pragma unroll
  for (int r=0;r<4;r++){
    int node = base + mrow + r;
    if (node >= N) continue;
    #pragma unroll
    for (int nt=0;nt<4;nt++){
      pxb[((size_t)node<<6) + (nt<<4) + nlo] = f2h(accP[nt][r] + bmv[nt]);
      psb[((size_t)node<<6) + (nt<<4) + nlo] = f2h(accS[nt][r]);
    }
  }
}

// ---------------- fused L0 edge kernel (no eh0 materialization):
// msg[revp[i]] = relu( px[colp[i]] + ps[rowp[i]] - (ea[perm[i]]@W' + b') ) ----------------
__global__ __launch_bounds__(256) void k_scat0(
    const float* __restrict__ ea, const int* __restrict__ perm,
    const float* __restrict__ wf,
    const u16* __restrict__ pxb, const u16* __restrict__ psb,
    const int* __restrict__ rowp, const int* __restrict__ colp,
    const int* __restrict__ revp, u16* __restrict__ msg, int E)
{
  int b = xswz(blockIdx.x, gridDim.x);
  int tid = b*256 + threadIdx.x;
  int i = tid >> 2;
  if (i >= E) return;
  int t = tid & 3;
  int e  = perm[i];
  int rp = rowp[i];
  int cp = colp[i];
  int rv = revp[i];
  const float* a = ea + (size_t)e*6;
  float av[6];
  #pragma unroll
  for (int k=0;k<6;k++) av[k] = a[k];
  float proj[16];
  const float* bp = wf + 384 + t*16;
  #pragma unroll
  for (int j=0;j<16;j++) proj[j] = bp[j];
  #pragma unroll
  for (int k=0;k<6;k++){
    const float* w = wf + k*64 + t*16;
    #pragma unroll
    for (int j=0;j<16;j++) proj[j] += av[k]*w[j];
  }
  float pc[16], pr[16];
  load16h(pxb + ((size_t)cp<<6) + t*16, pc);
  load16h(psb + ((size_t)rp<<6) + t*16, pr);
  float val[16];
  #pragma unroll
  for (int j=0;j<16;j++) val[j] = fmaxf(pc[j] + pr[j] - proj[j], 0.f);
  store16h(msg + ((size_t)rv<<6) + t*16, val);
}

// ---------------- fused MFMA edge kernel (L1/L2):
// msg[revp[i]] = relu( px[colp[i]] + ps[rowp[i]] - eh[i]@Wbot ) ----------------
__global__ __launch_bounds__(256) void k_scatmfma(
    const u16* __restrict__ eh, const u16* __restrict__ wp,
    const u16* __restrict__ pxb, const u16* __restrict__ psb,
    const int* __restrict__ rowp, const int* __restrict__ colp,
    const int* __restrict__ revp, u16* __restrict__ msg, int E)
{
  int lane = threadIdx.x & 63;
  int b = xswz(blockIdx.x, gridDim.x);
  int wid = (b << 2) + (threadIdx.x >> 6);
  int base = wid << 4;
  if (base >= E) return;
  int nlo = lane & 15;
  int khi = (lane >> 4) << 3;

  short8 bb[2][4];
  #pragma unroll
  for (int kk=0;kk<2;kk++)
    #pragma unroll
    for (int nt=0;nt<4;nt++)
      bb[kk][nt] = *(const short8*)(wp + WP_BOT + ((size_t)((kk<<2)|nt)*64 + lane)*8);

  int sa = base + nlo; if (sa > E-1) sa = E-1;
  const u16* ehp = eh + ((size_t)sa<<6) + khi;
  short8 a0 = *(const short8*)(ehp);
  short8 a1 = *(const short8*)(ehp + 32);

  f32x4 acc[4];
  #pragma unroll
  for (int nt=0;nt<4;nt++){
    f32x4 z = {0.f,0.f,0.f,0.f};
    acc[nt] = z;
    acc[nt] = __builtin_amdgcn_mfma_f32_16x16x32_f16(a0, bb[0][nt], acc[nt], 0,0,0);
    acc[nt] = __builtin_amdgcn_mfma_f32_16x16x32_f16(a1, bb[1][nt], acc[nt], 0,0,0);
  }

  int mrow = (lane >> 4) << 2;
  #pragma unroll
  for (int r=0;r<4;r++){
    int slot = base + mrow + r;
    if (slot >= E) continue;
    int rp = rowp[slot];
    int cp = colp[slot];
    int rv = revp[slot];
    const u16* pr = psb + ((size_t)rp<<6) + nlo;
    const u16* pc = pxb + ((size_t)cp<<6) + nlo;
    u16* ob = msg + ((size_t)rv<<6) + nlo;
    #pragma unroll
    for (int nt=0;nt<4;nt++){
      float v = h2f(pc[nt<<4]) + h2f(pr[nt<<4]) - acc[nt][r];
      ob[nt<<4] = f2h(fmaxf(v, 0.f));
    }
  }
}

// ---------------- fused: nmsg[n] = Σ msg[revp[j]]; segnext[n] = Σ msg[j]
// 4 rows in flight per wave: groups of 16 lanes, uint2 (4 ch) per lane ----------------
__global__ __launch_bounds__(256) void k_gnmsg(
    const u16* __restrict__ msg, const int* __restrict__ revp,
    const int* __restrict__ off, u16* __restrict__ nmsgb,
    u16* __restrict__ segnext, int N)
{
  int b = xswz(blockIdx.x, gridDim.x);
  int w = (b << 2) + (threadIdx.x >> 6);
  if (w >= N) return;
  int lane = threadIdx.x & 63;
  int g = lane >> 4, l = lane & 15;
  int lo = off[w], hi = off[w+1];
  float s0=0.f,s1=0.f,s2=0.f,s3=0.f;
  float t0=0.f,t1=0.f,t2=0.f,t3=0.f;
  if (segnext){
    for (int j = lo + g; j < hi; j += 4){
      int i = revp[j];
      uint2 v = *(const uint2*)(msg + ((size_t)i<<6) + (l<<2));
      uint2 u = *(const uint2*)(msg + ((size_t)j<<6) + (l<<2));
      s0 += h2f((u16)v.x); s1 += h2f((u16)(v.x>>16)); s2 += h2f((u16)v.y); s3 += h2f((u16)(v.y>>16));
      t0 += h2f((u16)u.x); t1 += h2f((u16)(u.x>>16)); t2 += h2f((u16)u.y); t3 += h2f((u16)(u.y>>16));
    }
  } else {
    for (int j = lo + g; j < hi; j += 4){
      int i = revp[j];
      uint2 v = *(const uint2*)(msg + ((size_t)i<<6) + (l<<2));
      s0 += h2f((u16)v.x); s1 += h2f((u16)(v.x>>16)); s2 += h2f((u16)v.y); s3 += h2f((u16)(v.y>>16));
    }
  }
  s0 += __shfl_xor(s0,16,64); s0 += __shfl_xor(s0,32,64);
  s1 += __shfl_xor(s1,16,64); s1 += __shfl_xor(s1,32,64);
  s2 += __shfl_xor(s2,16,64); s2 += __shfl_xor(s2,32,64);
  s3 += __shfl_xor(s3,16,64); s3 += __shfl_xor(s3,32,64);
  if (segnext){
    t0 += __shfl_xor(t0,16,64); t0 += __shfl_xor(t0,32,64);
    t1 += __shfl_xor(t1,16,64); t1 += __shfl_xor(t1,32,64);
    t2 += __shfl_xor(t2,16,64); t2 += __shfl_xor(t2,32,64);
    t3 += __shfl_xor(t3,16,64); t3 += __shfl_xor(t3,32,64);
  }
  if (g == 0){
    uint2 o; o.x = pack2(s0,s1); o.y = pack2(s2,s3);
    *(uint2*)(nmsgb + ((size_t)w<<6) + (l<<2)) = o;
    if (segnext){
      uint2 q; q.x = pack2(t0,t1); q.y = pack2(t2,t3);
      *(uint2*)(segnext + ((size_t)w<<6) + (l<<2)) = q;
    }
  }
}

// ---------------- MFMA node update: xout = relu(x@WnTop + nmsg@WnBot + bn), fp16 out ----------------
template<int KT>
__global__ __launch_bounds__(256) void k_nodef(
    const u16* __restrict__ xin, const u16* __restrict__ nmsgb,
    const u16* __restrict__ wp, const float* __restrict__ bn,
    u16* __restrict__ xout, int N)
{
  int lane = threadIdx.x & 63;
  int wid = (blockIdx.x << 2) + (threadIdx.x >> 6);
  int base = wid << 4;
  if (base >= N) return;
  int nlo = lane & 15;
  int khi = (lane >> 4) << 3;

  short8 bt[KT][4];
  #pragma unroll
  for (int kk=0;kk<KT;kk++)
    #pragma unroll
    for (int nt=0;nt<4;nt++)
      bt[kk][nt] = *(const short8*)(wp + WP_NTOP + ((size_t)((kk<<2)|nt)*64 + lane)*8);
  short8 bb[2][4];
  #pragma unroll
  for (int kk=0;kk<2;kk++)
    #pragma unroll
    for (int nt=0;nt<4;nt++)
      bb[kk][nt] = *(const short8*)(wp + WP_NBOT + ((size_t)((kk<<2)|nt)*64 + lane)*8);

  int r0 = base + nlo; if (r0 > N-1) r0 = N-1;
  const u16* xrow = xin + (size_t)r0*(KT*32);
  short8 ax[KT];
  #pragma unroll
  for (int kk=0;kk<KT;kk++) ax[kk] = *(const short8*)(xrow + (kk<<5) + khi);
  const u16* mrp = nmsgb + ((size_t)r0<<6);
  short8 am[2];
  #pragma unroll
  for (int kk=0;kk<2;kk++) am[kk] = *(const short8*)(mrp + (kk<<5) + khi);

  f32x4 acc[4];
  #pragma unroll
  for (int nt=0;nt<4;nt++){ f32x4 z = {0.f,0.f,0.f,0.f}; acc[nt]=z; }
  #pragma unroll
  for (int kk=0;kk<KT;kk++)
    #pragma unroll
    for (int nt=0;nt<4;nt++)
      acc[nt] = __builtin_amdgcn_mfma_f32_16x16x32_f16(ax[kk], bt[kk][nt], acc[nt], 0,0,0);
  #pragma unroll
  for (int kk=0;kk<2;kk++)
    #pragma unroll
    for (int nt=0;nt<4;nt++)
      acc[nt] = __builtin_amdgcn_mfma_f32_16x16x32_f16(am[kk], bb[kk][nt], acc[nt], 0,0,0);

  float bnv[4];
  #pragma unroll
  for (int nt=0;nt<4;nt++) bnv[nt] = bn[(nt<<4) + nlo];

  int mrow = (lane >> 4) << 2;
  #pragma unroll
  for (int r=0;r<4;r++){
    int node = base + mrow + r;
    if (node >= N) continue;
    #pragma unroll
    for (int nt=0;nt<4;nt++)
      xout[((size_t)node<<6) + (nt<<4) + nlo] = f2h(fmaxf(acc[nt][r] + bnv[nt], 0.f));
  }
}

// ---------------- pooling (batch is sorted), fp16 out ----------------
__global__ __launch_bounds__(256) void k_goff(
    const int* __restrict__ batch, int* __restrict__ goff, int N, int B)
{
  int n = blockIdx.x*256 + threadIdx.x;
  if (n >= N) return;
  int bcur = batch[n];
  int bprev = (n == 0) ? -1 : batch[n-1];
  for (int g = bprev + 1; g <= bcur; ++g) goff[g] = n;
  if (n == N-1) { for (int g = bcur + 1; g <= B; ++g) goff[g] = N; }
}

__global__ __launch_bounds__(256) void k_pool(
    const u16* __restrict__ xin, const int* __restrict__ goff,
    u16* __restrict__ pooledh, int B)
{
  int g = (blockIdx.x << 2) + (threadIdx.x >> 6);
  if (g >= B) return;
  int lane = threadIdx.x & 63;
  int lo = goff[g], hi = goff[g + 1];
  float s = 0.f;
  for (int n = lo; n < hi; n++) s += h2f(xin[((size_t)n << 6) + lane]);
  pooledh[((size_t)g << 6) + lane] = f2h(s);
}

// ---------------- xt -> fp16 into ab1 cols 128..255 ----------------
__global__ __launch_bounds__(256) void k_xtconv(
    const float* __restrict__ xt, u16* __restrict__ ab1, int B)
{
  int t = blockIdx.x*256 + threadIdx.x;
  if (t >= B*128) return;
  int r = t >> 7, c = t & 127;
  ab1[(size_t)r*256 + 128 + c] = f2h(xt[t]);
}

// ---------------- final dot: out[r] = h2[r]·Wo + bo (wave per row) ----------------
__global__ __launch_bounds__(256) void k_out(
    const float* __restrict__ h2, const float* __restrict__ Wo,
    const float* __restrict__ bo, float* __restrict__ out, int B)
{
  int w = (blockIdx.x << 2) + (threadIdx.x >> 6);
  if (w >= B) return;
  int lane = threadIdx.x & 63;
  const float* h = h2 + (size_t)w*256;
  float s = 0.f;
  #pragma unroll
  for (int k=0;k<4;k++) s += h[lane + (k<<6)] * Wo[lane + (k<<6)];
  #pragma unroll
  for (int off=32; off; off>>=1) s += __shfl_down(s, off, 64);
  if (lane == 0) out[w] = s + bo[0];
}

extern "C" void kernel_launch(void* const* d_in, const int* in_sizes, int n_in,
                              void* d_out, int out_size, void* d_ws, size_t ws_size,
                              hipStream_t stream)
{
  const float* x    = (const float*)d_in[0];
  const float* ea   = (const float*)d_in[1];
  const float* xt   = (const float*)d_in[2];
  const int*   eidx = (const int*)d_in[3];
  const int*   batch= (const int*)d_in[4];
  const float* We   = (const float*)d_in[6];
  const float* be   = (const float*)d_in[7];
  const float* Wm[3]= {(const float*)d_in[8],  (const float*)d_in[12], (const float*)d_in[16]};
  const float* bm[3]= {(const float*)d_in[9],  (const float*)d_in[13], (const float*)d_in[17]};
  const float* Wn[3]= {(const float*)d_in[10], (const float*)d_in[14], (const float*)d_in[18]};
  const float* bn[3]= {(const float*)d_in[11], (const float*)d_in[15], (const float*)d_in[19]};
  const float* Wxd  = (const float*)d_in[20];
  const float* bxd  = (const float*)d_in[21];
  const float* W1   = (const float*)d_in[22];
  const float* b1   = (const float*)d_in[23];
  const float* W2   = (const float*)d_in[24];
  const float* b2   = (const float*)d_in[25];
  const float* Wo   = (const float*)d_in[26];
  const float* bo   = (const float*)d_in[27];

  const int N = in_sizes[0] / 78;
  const int E = in_sizes[1] / 6;
  const int B = in_sizes[2] / 128;
  const int E2 = E / 2;
  const int* row = eidx;
  const int* col = eidx + E;

  char* p = (char*)d_ws;
  size_t off = 0;
  auto alloc = [&](size_t b)->void* {
    void* r = p + off;
    off = (off + b + 255) & ~(size_t)255;
    return r;
  };
  // persistent buffers (~248 MB total; 259 MB proven safe)
  u16*   ehA   = (u16*)  alloc((size_t)E * 128);
  u16*   ehB   = (u16*)  alloc((size_t)E * 128);
  int*   rowp  = (int*)  alloc((size_t)E * 4);
  int*   colp  = (int*)  alloc((size_t)E * 4);
  int*   revp  = (int*)  alloc((size_t)E * 4);
  int*   offs  = (int*)  alloc((size_t)(N+1) * 4);
  u16*   xh    = (u16*)  alloc((size_t)N * 192);   // [N x 96] fp16, zero-padded
  u16*   sA    = (u16*)  alloc((size_t)N * 128);   // seg ping
  u16*   sB    = (u16*)  alloc((size_t)N * 128);   // seg pong
  u16*   pxb   = (u16*)  alloc((size_t)N * 128);   // px, then reused as nmsg
  u16*   psb   = (u16*)  alloc((size_t)N * 128);
  u16*   xa    = (u16*)  alloc((size_t)N * 128);   // fp16 node states
  u16*   xb    = (u16*)  alloc((size_t)N * 128);
  int*   goff  = (int*)  alloc((size_t)(B+1) * 4);
  u16*   pooledh=(u16*)  alloc((size_t)B * 128);
  u16*   ab1   = (u16*)  alloc((size_t)B * 512);
  u16*   h1h   = (u16*)  alloc((size_t)B * 2048);
  float* h2f_  = (float*)alloc((size_t)B * 1024);
  u16*   wpack = (u16*)  alloc((size_t)3 * WP_LAYER * 2);
  u16*   wxdP  = (u16*)  alloc((size_t)(64/32)*(128/16)*512 * 2);
  u16*   w1P   = (u16*)  alloc((size_t)(256/32)*(1024/16)*512 * 2);
  u16*   w2P   = (u16*)  alloc((size_t)(1024/32)*(256/16)*512 * 2);
  float* wfuse = (float*)alloc((size_t)448 * 4);   // W' (6x64) + b' (64), f32

  // setup transients aliased into ehA (ehA's first write is L1 k_scatmfma,
  // after perm's last use in k_scat0/k_seg0)
  char* ehAc = (char*)ehA;
  int* perm  = (int*)ehAc;           // 3.2 MB
  int* iperm = perm + E;             // 3.2 MB
  int* cnt   = iperm + E;            // 0.16 MB
  int* nxt   = cnt + N;              // 0.16 MB
  int* bsum  = nxt + N;              // 4 KB
  int* bofs  = bsum + 1024;          // 4 KB

  dim3 blk(256);
  int gE   = (E + 255) / 256;
  int gE4  = ((size_t)E*4 + 255) / 256;
  int gEm  = (E + 63) / 64;
  int gN   = (N + 255) / 256;
  int gNm  = (N + 63) / 64;
  int gNw  = (N + 3) / 4;
  int gBw  = (B + 3) / 4;
  int gXc  = (N*96 + 255) / 256;
  int nb   = (N + 255) / 256;    // scan blocks (N=40000 -> 157, <=256 ok)

  hipMemsetAsync(cnt, 0, (size_t)N * 4, stream);
  k_deg  <<<gE, blk, 0, stream>>>(row, cnt, E);
  k_bsum <<<nb, blk, 0, stream>>>(cnt, bsum, N);
  k_bscan<<<1,  blk, 0, stream>>>(bsum, bofs, nb, offs, N);
  k_apply<<<nb, blk, 0, stream>>>(cnt, bofs, offs, nxt, N);
  k_fill <<<gE, blk, 0, stream>>>(row, nxt, perm, iperm, E);
  k_permarr<<<gE, blk, 0, stream>>>(perm, iperm, row, col, rowp, colp, revp, E, E2);
  k_seg0<<<gNw, blk, 0, stream>>>(ea, perm, offs, We, be, sA, N);
  k_xconv<<<gXc, blk, 0, stream>>>(x, xh, N);
  k_goff<<<gN, blk, 0, stream>>>(batch, goff, N, B);
  k_fusew<<<2, blk, 0, stream>>>(We, be, Wm[0] + (size_t)78*64, wfuse);
  for (int L = 0; L < 3; ++L) {
    int XD = (L == 0) ? 78 : 64;
    int KT = (L == 0) ? 3 : 2;
    k_prepw<<<10, blk, 0, stream>>>(Wm[L], Wn[L], XD, KT, wpack + (size_t)L*WP_LAYER);
  }
  k_packw<<<(1024 + 255)/256, blk, 0, stream>>>(Wxd, 64, 128, wxdP);
  k_packw<<<(32768 + 255)/256, blk, 0, stream>>>(W1, 256, 1024, w1P);
  k_packw<<<(32768 + 255)/256, blk, 0, stream>>>(W2, 1024, 256, w2P);

  const u16* wp0 = wpack;
  const u16* wp1 = wpack + (size_t)WP_LAYER;
  const u16* wp2 = wpack + (size_t)2*WP_LAYER;

  // ---- L0 (eh0 never materialized) ----
  k_proj<3><<<gNm, blk, 0, stream>>>(xh, sA, wp0, bm[0], pxb, psb, N);
  k_scat0<<<gE4, blk, 0, stream>>>(ea, perm, wfuse, pxb, psb, rowp, colp, revp, ehB, E);
  k_gnmsg<<<gNw, blk, 0, stream>>>(ehB, revp, offs, pxb, sB, N);
  k_nodef<3><<<gNm, blk, 0, stream>>>(xh, pxb, wp0, bn[0], xa, N);
  // ---- L1 ----
  k_proj<2><<<gNm, blk, 0, stream>>>(xa, sB, wp1, bm[1], pxb, psb, N);
  k_scatmfma<<<gEm, blk, 0, stream>>>(ehB, wp1, pxb, psb, rowp, colp, revp, ehA, E);
  k_gnmsg<<<gNw, blk, 0, stream>>>(ehA, revp, offs, pxb, sA, N);
  k_nodef<2><<<gNm, blk, 0, stream>>>(xa, pxb, wp1, bn[1], xb, N);
  // ---- L2 ----
  k_proj<2><<<gNm, blk, 0, stream>>>(xb, sA, wp2, bm[2], pxb, psb, N);
  k_scatmfma<<<gEm, blk, 0, stream>>>(ehA, wp2, pxb, psb, rowp, colp, revp, ehB, E);
  k_gnmsg<<<gNw, blk, 0, stream>>>(ehB, revp, offs, pxb, (u16*)nullptr, N);
  k_nodef<2><<<gNm, blk, 0, stream>>>(xb, pxb, wp2, bn[2], xa, N);

  k_pool<<<gBw, blk, 0, stream>>>(xa, goff, pooledh, B);
  k_xtconv<<<(B*128 + 255)/256, blk, 0, stream>>>(xt, ab1, B);
  {
    int waves = ((B + 15)/16) * (128/64);
    k_gemm<<<(waves + 3)/4, blk, 0, stream>>>(pooledh, 64, wxdP, bxd, ab1, 256, B, 128>>4, 64>>5, 1, 1);
  }
  {
    int waves = ((B + 15)/16) * (1024/64);
    k_gemm<<<(waves + 3)/4, blk, 0, stream>>>(ab1, 256, w1P, b1, h1h, 1024, B, 1024>>4, 256>>5, 1, 1);
  }
  {
    int waves = ((B + 15)/16) * (256/64);
    k_gemm<<<(waves + 3)/4, blk, 0, stream>>>(h1h, 1024, w2P, b2, h2f_, 256, B, 256>>4, 1024>>5, 1, 0);
  }
  k_out<<<gBw, blk, 0, stream>>>(h2f_, Wo, bo, (float*)d_out, B);
}